// Round 2
// baseline (5689.883 us; speedup 1.0000x reference)
//
#include <hip/hip_runtime.h>
#include <hip/hip_bf16.h>

// Round 2: inputs/outputs are FLOAT32 (per reference dtypes + npz sizes).
// Internal GEMMs convert f32->bf16 during LDS staging and use bf16 MFMA.

#define NN 100000
#define EG 800000
#define EE 262144

typedef __attribute__((ext_vector_type(8))) short short8;
typedef __attribute__((ext_vector_type(4))) float f32x4;

__device__ __forceinline__ unsigned short f2bf(float f) {
  union { float f; unsigned u; } v; v.f = f;
  return (unsigned short)((v.u + 0x7FFFu + ((v.u >> 16) & 1u)) >> 16);
}
__device__ __forceinline__ unsigned pack2bf(float a, float b) {
  return (unsigned)f2bf(a) | ((unsigned)f2bf(b) << 16);
}

// temp scalar: dtype unknown (int32 / f32). Decode heuristically.
__device__ __forceinline__ float decode_scalar(const void* p) {
  unsigned u = *(const unsigned*)p;
  float f = __uint_as_float(u);
  float af = fabsf(f);
  if (af >= 1e-6f && af <= 1e6f) return f;            // plausible f32
  if (u < 1024u) return (float)u;                     // small int
  return 1.0f;
}

// ---------------- degrees + norms ----------------
__global__ __launch_bounds__(256) void k_deg(const int* __restrict__ src,
                                             const int* __restrict__ dst,
                                             int* __restrict__ degO,
                                             int* __restrict__ degI) {
  for (int i = blockIdx.x * 256 + threadIdx.x; i < EG; i += gridDim.x * 256) {
    atomicAdd(&degO[src[i]], 1);
    atomicAdd(&degI[dst[i]], 1);
  }
}

__global__ __launch_bounds__(256) void k_norm(const int* __restrict__ degO,
                                              const int* __restrict__ degI,
                                              float* __restrict__ normO,
                                              float* __restrict__ normI) {
  int i = blockIdx.x * 256 + threadIdx.x;
  if (i < NN) {
    int dO = degO[i]; if (dO < 1) dO = 1;
    int dI = degI[i]; if (dI < 1) dI = 1;
    normO[i] = rsqrtf((float)dO);
    normI[i] = rsqrtf((float)dI);
  }
}

// ---------------- scatter-add aggregation (f32 atomics) ----------------
// layer 1: 128 features, one wave per edge, 2 feats/lane
__global__ __launch_bounds__(256) void k_scatter128(
    const float* __restrict__ x, const int* __restrict__ src,
    const int* __restrict__ dst, const float* __restrict__ normO,
    float* __restrict__ agg) {
  int wid = (blockIdx.x * 256 + threadIdx.x) >> 6;
  int lane = threadIdx.x & 63;
  int nw = (gridDim.x * 256) >> 6;
  for (int e = wid; e < EG; e += nw) {
    int s = src[e], d = dst[e];
    float ns = normO[s];
    float2 v = *(const float2*)(x + ((size_t)s << 7) + (lane << 1));
    float* ap = agg + ((size_t)d << 7) + (lane << 1);
    unsafeAtomicAdd(ap + 0, v.x * ns);
    unsafeAtomicAdd(ap + 1, v.y * ns);
  }
}

// layer 2: 256 features, 4 feats/lane
__global__ __launch_bounds__(256) void k_scatter256(
    const float* __restrict__ hsrc, const int* __restrict__ src,
    const int* __restrict__ dst, const float* __restrict__ normO,
    float* __restrict__ agg) {
  int wid = (blockIdx.x * 256 + threadIdx.x) >> 6;
  int lane = threadIdx.x & 63;
  int nw = (gridDim.x * 256) >> 6;
  for (int e = wid; e < EG; e += nw) {
    int s = src[e], d = dst[e];
    float ns = normO[s];
    float4 v = *(const float4*)(hsrc + ((size_t)s << 8) + (lane << 2));
    float* ap = agg + ((size_t)d << 8) + (lane << 2);
    unsafeAtomicAdd(ap + 0, v.x * ns);
    unsafeAtomicAdd(ap + 1, v.y * ns);
    unsafeAtomicAdd(ap + 2, v.z * ns);
    unsafeAtomicAdd(ap + 3, v.w * ns);
  }
}

// ---------------- edge gather: npemb = h[a] + h[b] ----------------
__global__ __launch_bounds__(256) void k_edge_gather(
    const float* __restrict__ h, const int* __restrict__ ea,
    const int* __restrict__ eb, float* __restrict__ outp) {
  int wid = (blockIdx.x * 256 + threadIdx.x) >> 6;
  int lane = threadIdx.x & 63;
  int nw = (gridDim.x * 256) >> 6;
  for (int e = wid; e < EE; e += nw) {
    int a = ea[e], b = eb[e];
    float4 va = *(const float4*)(h + ((size_t)a << 8) + (lane << 2));
    float4 vb = *(const float4*)(h + ((size_t)b << 8) + (lane << 2));
    float4 r;
    r.x = va.x + vb.x; r.y = va.y + vb.y; r.z = va.z + vb.z; r.w = va.w + vb.w;
    *(float4*)(outp + ((size_t)e << 8) + (lane << 2)) = r;
  }
}

// ---------------- tiled MFMA GEMM: C = act(A @ W + bias) ----------------
// A: [M,K] f32 (AMODE 1: scaled per-row by rowscale). W: [K,Ntot] f32. C: f32.
// Block tile 128x128, BK=32, 4 waves in 2x2, each wave 64x64 (4x4 frags of 16x16x32 bf16).
template <int K, int AMODE, bool RELU>
__global__ __launch_bounds__(256) void k_gemm(
    const float* __restrict__ A, const float* __restrict__ rowscale,
    const float* __restrict__ W, const float* __restrict__ bias,
    float* __restrict__ C, int M, int Ntot, int ldc) {
  __shared__ __align__(16) short At[128 * 40];
  __shared__ __align__(16) short Bt[128 * 40];
  const int t = threadIdx.x;
  const int row0 = blockIdx.x * 128;
  const int col0 = blockIdx.y * 128;
  const int lane = t & 63;
  const int wave = t >> 6;
  const int wr = (wave >> 1) << 6;
  const int wc = (wave & 1) << 6;
  const int lrow = lane & 15;
  const int lhi = lane >> 4;

  f32x4 acc[4][4];
#pragma unroll
  for (int m = 0; m < 4; ++m)
#pragma unroll
    for (int n = 0; n < 4; ++n) acc[m][n] = (f32x4){0.f, 0.f, 0.f, 0.f};

  for (int k0 = 0; k0 < K; k0 += 32) {
    if (k0) __syncthreads();
    // ---- stage A tile 128x32: f32 -> bf16 ----
#pragma unroll
    for (int it = 0; it < 2; ++it) {
      int idx = t + it * 256;
      int r = idx >> 2;
      int c8 = (idx & 3) << 3;
      int grow = row0 + r;
      int4 tv = {0, 0, 0, 0};
      if (grow < M) {
        const float* ar = A + (size_t)grow * K + k0 + c8;
        float s = (AMODE == 1) ? rowscale[grow] : 1.0f;
        float4 f0 = *(const float4*)ar;
        float4 f1 = *(const float4*)(ar + 4);
        tv.x = (int)pack2bf(f0.x * s, f0.y * s);
        tv.y = (int)pack2bf(f0.z * s, f0.w * s);
        tv.z = (int)pack2bf(f1.x * s, f1.y * s);
        tv.w = (int)pack2bf(f1.z * s, f1.w * s);
      }
      *(int4*)&At[r * 40 + c8] = tv;
    }
    // ---- stage B^T tile: Bt[c][kk] = W[k0+kk][col0+c], coalesced f32 reads ----
    {
      int c = t & 127;
      int kh = (t >> 7) << 4;  // 0 or 16
      const float* wp = W + (size_t)(k0 + kh) * Ntot + col0 + c;
      unsigned ww[8];
#pragma unroll
      for (int i = 0; i < 8; ++i) {
        float lo = wp[(size_t)(2 * i) * Ntot];
        float hi = wp[(size_t)(2 * i + 1) * Ntot];
        ww[i] = pack2bf(lo, hi);
      }
      *(int4*)&Bt[c * 40 + kh] = make_int4((int)ww[0], (int)ww[1], (int)ww[2], (int)ww[3]);
      *(int4*)&Bt[c * 40 + kh + 8] = make_int4((int)ww[4], (int)ww[5], (int)ww[6], (int)ww[7]);
    }
    __syncthreads();
    // ---- fragments + MFMA ----
    short8 a[4], b[4];
#pragma unroll
    for (int m = 0; m < 4; ++m)
      a[m] = *(const short8*)&At[(wr + m * 16 + lrow) * 40 + lhi * 8];
#pragma unroll
    for (int n = 0; n < 4; ++n)
      b[n] = *(const short8*)&Bt[(wc + n * 16 + lrow) * 40 + lhi * 8];
#pragma unroll
    for (int m = 0; m < 4; ++m)
#pragma unroll
      for (int n = 0; n < 4; ++n)
        acc[m][n] = __builtin_amdgcn_mfma_f32_16x16x32_bf16(a[m], b[n], acc[m][n], 0, 0, 0);
  }
  // ---- epilogue: C/D layout col=lane&15, row=(lane>>4)*4+r ----
#pragma unroll
  for (int n = 0; n < 4; ++n) {
    int col = col0 + wc + n * 16 + lrow;
    float bv = bias[col];
#pragma unroll
    for (int m = 0; m < 4; ++m) {
#pragma unroll
      for (int r = 0; r < 4; ++r) {
        int grow = row0 + wr + m * 16 + lhi * 4 + r;
        if (grow < M) {
          float vv = acc[m][n][r] + bv;
          if (RELU) vv = fmaxf(vv, 0.f);
          C[(size_t)grow * ldc + col] = vv;
        }
      }
    }
  }
}

// ---------------- branch elementwise: q, Z, M, A (all f32) ----------------
__global__ __launch_bounds__(256) void k_branch_ew(
    const float* __restrict__ npemb, const float* __restrict__ gauss,
    const float* __restrict__ unif, const void* __restrict__ temp_p,
    const float* __restrict__ Wq, const float* __restrict__ bq,
    const float* __restrict__ Wc, const float* __restrict__ bc,
    const float* __restrict__ mean_o, const float* __restrict__ logstd_o,
    float* __restrict__ q_o, float* __restrict__ A_o,
    float* __restrict__ M_o) {
  __shared__ float WqS[1024];  // [256][4]
  __shared__ float WcS[256];   // [64][4]
  int t = threadIdx.x;
  for (int i = t; i < 1024; i += 256) WqS[i] = Wq[i];
  if (t < 256) WcS[t] = Wc[t];
  __syncthreads();
  float invt = 1.0f / decode_scalar(temp_p);
  float bq0 = bq[0], bq1 = bq[1], bq2 = bq[2], bq3 = bq[3];
  float bc0 = bc[0], bc1 = bc[1], bc2 = bc[2], bc3 = bc[3];
  int wid = (blockIdx.x * 256 + t) >> 6;
  int lane = t & 63;
  int nw = (gridDim.x * 256) >> 6;
  for (int e = wid; e < EE; e += nw) {
    // ---- q = npemb @ Wq + bq (wave dot over K=256, 4 elems/lane) ----
    float4 av = *(const float4*)(npemb + (size_t)e * 256 + lane * 4);
    const float* wq = &WqS[lane * 16];
    float p0 = av.x * wq[0] + av.y * wq[4] + av.z * wq[8] + av.w * wq[12];
    float p1 = av.x * wq[1] + av.y * wq[5] + av.z * wq[9] + av.w * wq[13];
    float p2 = av.x * wq[2] + av.y * wq[6] + av.z * wq[10] + av.w * wq[14];
    float p3 = av.x * wq[3] + av.y * wq[7] + av.z * wq[11] + av.w * wq[15];
#pragma unroll
    for (int off = 32; off >= 1; off >>= 1) {
      p0 += __shfl_xor(p0, off);
      p1 += __shfl_xor(p1, off);
      p2 += __shfl_xor(p2, off);
      p3 += __shfl_xor(p3, off);
    }
    float q0 = p0 + bq0, q1 = p1 + bq1, q2 = p2 + bq2, q3 = p3 + bq3;
    if (lane == 0) {
      *(float4*)(q_o + (size_t)e * 4) = make_float4(q0, q1, q2, q3);
    }
    // ---- Z = softmax((q + gumbel)/temp) ----
    float qv[4] = {q0, q1, q2, q3};
    float z[4];
    float mx = -1e30f;
    float4 uv = *(const float4*)(unif + (size_t)e * 4);
    float uu[4] = {uv.x, uv.y, uv.z, uv.w};
#pragma unroll
    for (int c = 0; c < 4; ++c) {
      float g = -__logf(-__logf(uu[c] + 1e-7f) + 1e-7f);
      z[c] = (qv[c] + g) * invt;
      mx = fmaxf(mx, z[c]);
    }
    float zs = 0.f;
#pragma unroll
    for (int c = 0; c < 4; ++c) { z[c] = __expf(z[c] - mx); zs += z[c]; }
    float rzs = 1.0f / zs;
    // ---- M[d] = sum_c Z[c] * (gauss*exp(logstd)+mean)[c*64+d], lane = d ----
    float macc = 0.f;
#pragma unroll
    for (int c = 0; c < 4; ++c) {
      size_t k = (size_t)e * 256 + c * 64 + lane;
      float nl = gauss[k] * __expf(logstd_o[k]) + mean_o[k];
      macc += z[c] * rzs * nl;
    }
    M_o[(size_t)e * 64 + lane] = macc;
    // ---- A = softmax(M @ Wc + bc) ----
    const float* wcp = &WcS[lane * 4];
    float s0 = macc * wcp[0], s1 = macc * wcp[1], s2 = macc * wcp[2], s3 = macc * wcp[3];
#pragma unroll
    for (int off = 32; off >= 1; off >>= 1) {
      s0 += __shfl_xor(s0, off);
      s1 += __shfl_xor(s1, off);
      s2 += __shfl_xor(s2, off);
      s3 += __shfl_xor(s3, off);
    }
    s0 += bc0; s1 += bc1; s2 += bc2; s3 += bc3;
    float am = fmaxf(fmaxf(s0, s1), fmaxf(s2, s3));
    float e0 = __expf(s0 - am), e1 = __expf(s1 - am), e2 = __expf(s2 - am), e3 = __expf(s3 - am);
    float es = e0 + e1 + e2 + e3;
    float res = 1.0f / es;
    if (lane == 0) {
      *(float4*)(A_o + (size_t)e * 4) = make_float4(e0 * res, e1 * res, e2 * res, e3 * res);
    }
  }
}

extern "C" void kernel_launch(void* const* d_in, const int* in_sizes, int n_in,
                              void* d_out, int out_size, void* d_ws, size_t ws_size,
                              hipStream_t stream) {
  const float* x = (const float*)d_in[0];
  const int* src = (const int*)d_in[1];
  const int* dst = (const int*)d_in[2];
  const int* pos_src = (const int*)d_in[3];
  const int* pos_dst = (const int*)d_in[4];
  const int* neg_src = (const int*)d_in[5];
  const int* neg_dst = (const int*)d_in[6];
  const float* gauss_pos = (const float*)d_in[7];
  const float* gauss_neg = (const float*)d_in[8];
  const float* unif_pos = (const float*)d_in[9];
  const float* unif_neg = (const float*)d_in[10];
  const void* temp_p = d_in[11];
  const float* W1 = (const float*)d_in[12];
  const float* b1 = (const float*)d_in[13];
  const float* W2 = (const float*)d_in[14];
  const float* b2 = (const float*)d_in[15];
  const float* Wm = (const float*)d_in[16];
  const float* bm = (const float*)d_in[17];
  const float* Wl = (const float*)d_in[18];
  const float* bl = (const float*)d_in[19];
  const float* Wq = (const float*)d_in[20];
  const float* bq = (const float*)d_in[21];
  const float* Wd1 = (const float*)d_in[22];
  const float* bd1 = (const float*)d_in[23];
  const float* WdX = (const float*)d_in[24];
  const float* bdX = (const float*)d_in[25];
  const float* Wc = (const float*)d_in[26];
  const float* bc = (const float*)d_in[27];

  // workspace layout (bytes)
  char* w = (char*)d_ws;
  int* degO = (int*)w;                                   // 401,408
  int* degI = (int*)(w + 401408);                        // 401,408
  float* agg1 = (float*)(w + 802816);                    // [NN,128] f32, 51.2MB
  float* agg2 = (float*)(w + 52002816);                  // [NN,256] f32, 102.4MB
  float* normO = (float*)(w + 154402816);                // 401,408
  float* normI = (float*)(w + 154804224);                // 401,408
  float* h1 = (float*)(w + 155205632);                   // [NN,256] f32, 102.4MB
  float* h = (float*)(w + 257605632);                    // [NN,256] f32, 102.4MB
  float* npemb = (float*)(w + 360005632);                // [EE,256] f32, 268.4MB
  float* Mws = (float*)agg2;                             // alias: agg2 dead after encoder
  float* X1 = npemb;                                     // alias: npemb dead after branch_ew
  // total ws use: 628,441,088 B

  float* out = (float*)d_out;
  float* posA = out;
  float* negA = out + 1048576ull;
  float* posX = out + 2097152ull;
  float* negX = out + 35651584ull;
  float* pos_mean = out + 69206016ull;
  float* neg_mean = out + 136314880ull;
  float* pos_logstd = out + 203423744ull;
  float* neg_logstd = out + 270532608ull;
  float* posq = out + 337641472ull;
  float* negq = out + 338690048ull;

  // zero deg + agg1 + agg2 (contiguous from 0)
  hipMemsetAsync(d_ws, 0, 154402816, stream);

  k_deg<<<2048, 256, 0, stream>>>(src, dst, degO, degI);
  k_norm<<<392, 256, 0, stream>>>(degO, degI, normO, normI);

  // layer 1: agg1 = segsum(x*normO), h1 = relu((agg1*normI) @ W1 + b1)
  k_scatter128<<<2048, 256, 0, stream>>>(x, src, dst, normO, agg1);
  k_gemm<128, 1, true><<<dim3(782, 2), 256, 0, stream>>>(agg1, normI, W1, b1, h1, NN, 256, 256);
  // layer 2: agg2 = segsum(h1*normO), h = (agg2*normI) @ W2 + b2
  k_scatter256<<<2048, 256, 0, stream>>>(h1, src, dst, normO, agg2);
  k_gemm<256, 1, false><<<dim3(782, 2), 256, 0, stream>>>(agg2, normI, W2, b2, h, NN, 256, 256);

  for (int b = 0; b < 2; ++b) {
    const int* es = b ? neg_src : pos_src;
    const int* ed = b ? neg_dst : pos_dst;
    const float* gs = b ? gauss_neg : gauss_pos;
    const float* uf = b ? unif_neg : unif_pos;
    float* o_mean = b ? neg_mean : pos_mean;
    float* o_ls = b ? neg_logstd : pos_logstd;
    float* o_q = b ? negq : posq;
    float* o_A = b ? negA : posA;
    float* o_X = b ? negX : posX;

    k_edge_gather<<<2048, 256, 0, stream>>>(h, es, ed, npemb);
    k_gemm<256, 0, false><<<dim3(2048, 2), 256, 0, stream>>>(npemb, nullptr, Wm, bm, o_mean, EE, 256, 256);
    k_gemm<256, 0, false><<<dim3(2048, 2), 256, 0, stream>>>(npemb, nullptr, Wl, bl, o_ls, EE, 256, 256);
    k_branch_ew<<<2048, 256, 0, stream>>>(npemb, gs, uf, temp_p, Wq, bq, Wc, bc,
                                          o_mean, o_ls, o_q, o_A, Mws);
    k_gemm<64, 0, true><<<dim3(2048, 2), 256, 0, stream>>>(Mws, nullptr, Wd1, bd1, X1, EE, 256, 256);
    k_gemm<256, 0, true><<<dim3(2048, 1), 256, 0, stream>>>(X1, nullptr, WdX, bdX, o_X, EE, 128, 128);
  }
}

// Round 3
// 2442.552 us; speedup vs baseline: 2.3295x; 2.3295x over previous
//
#include <hip/hip_runtime.h>
#include <hip/hip_bf16.h>

// Round 3: CSR gather replaces scatter atomics; bf16 internal activations;
// BN=256 GEMM tiles (A read once). I/O remains f32.

#define NN 100000
#define EG 800000
#define EE 262144

typedef __attribute__((ext_vector_type(8))) short short8;
typedef __attribute__((ext_vector_type(4))) float f32x4;

__device__ __forceinline__ float bf2f(unsigned u16) {
  union { unsigned u; float f; } v; v.u = u16 << 16; return v.f;
}
__device__ __forceinline__ unsigned short f2bf(float f) {
  union { float f; unsigned u; } v; v.f = f;
  return (unsigned short)((v.u + 0x7FFFu + ((v.u >> 16) & 1u)) >> 16);
}
__device__ __forceinline__ unsigned pack2bf(float a, float b) {
  return (unsigned)f2bf(a) | ((unsigned)f2bf(b) << 16);
}

__device__ __forceinline__ float decode_scalar(const void* p) {
  unsigned u = *(const unsigned*)p;
  float f = __uint_as_float(u);
  float af = fabsf(f);
  if (af >= 1e-6f && af <= 1e6f) return f;  // plausible f32
  if (u < 1024u) return (float)u;           // small int
  return 1.0f;
}

// ---------------- degrees + norms ----------------
__global__ __launch_bounds__(256) void k_deg(const int* __restrict__ src,
                                             const int* __restrict__ dst,
                                             int* __restrict__ degO,
                                             int* __restrict__ degI) {
  for (int i = blockIdx.x * 256 + threadIdx.x; i < EG; i += gridDim.x * 256) {
    atomicAdd(&degO[src[i]], 1);
    atomicAdd(&degI[dst[i]], 1);
  }
}

__global__ __launch_bounds__(256) void k_norm(const int* __restrict__ degO,
                                              const int* __restrict__ degI,
                                              float* __restrict__ normO,
                                              float* __restrict__ normI) {
  int i = blockIdx.x * 256 + threadIdx.x;
  if (i < NN) {
    int dO = degO[i]; if (dO < 1) dO = 1;
    int dI = degI[i]; if (dI < 1) dI = 1;
    normO[i] = rsqrtf((float)dO);
    normI[i] = rsqrtf((float)dI);
  }
}

// ---------------- exclusive scan of degI -> rowptr, cursor (1 block, 1024 thr) ----------------
__global__ __launch_bounds__(1024) void k_scan(const int* __restrict__ degI,
                                               int* __restrict__ rowptr,
                                               int* __restrict__ cursor) {
  __shared__ int wsum[16];
  __shared__ int carry_s;
  __shared__ int tot_s;
  int t = threadIdx.x, lane = t & 63, wv = t >> 6;
  if (t == 0) carry_s = 0;
  __syncthreads();
  for (int base = 0; base < NN; base += 1024) {
    int c0 = carry_s;
    int i = base + t;
    int v = (i < NN) ? degI[i] : 0;
    int incl = v;
#pragma unroll
    for (int off = 1; off < 64; off <<= 1) {
      int u = __shfl_up(incl, off);
      if (lane >= off) incl += u;
    }
    if (lane == 63) wsum[wv] = incl;
    __syncthreads();
    if (wv == 0 && lane < 16) {
      int s = wsum[lane];
      int si = s;
#pragma unroll
      for (int off = 1; off < 16; off <<= 1) {
        int u = __shfl_up(si, off);
        if (lane >= off) si += u;
      }
      wsum[lane] = si - s;  // exclusive wave offset
      if (lane == 15) tot_s = si;
    }
    __syncthreads();
    int excl = c0 + wsum[wv] + incl - v;
    if (i < NN) { rowptr[i] = excl; cursor[i] = excl; }
    __syncthreads();
    if (t == 0) carry_s = c0 + tot_s;
    __syncthreads();
  }
  if (threadIdx.x == 0) rowptr[NN] = carry_s;
}

// ---------------- fill CSR buckets ----------------
__global__ __launch_bounds__(256) void k_fill(const int* __restrict__ src,
                                              const int* __restrict__ dst,
                                              int* __restrict__ cursor,
                                              int* __restrict__ csr) {
  for (int e = blockIdx.x * 256 + threadIdx.x; e < EG; e += gridDim.x * 256) {
    int d = dst[e];
    int pos = atomicAdd(&cursor[d], 1);
    csr[pos] = src[e];
  }
}

// ---------------- gather layer 1: agg1 = normI[n]*sum(normO[s]*x[s]) -> bf16 ----------------
__global__ __launch_bounds__(256) void k_gather1(
    const float* __restrict__ x, const int* __restrict__ rowptr,
    const int* __restrict__ csr, const float* __restrict__ normO,
    const float* __restrict__ normI, unsigned short* __restrict__ agg) {
  int wid = (blockIdx.x * 256 + threadIdx.x) >> 6;
  int lane = threadIdx.x & 63;
  int nw = (gridDim.x * 256) >> 6;
  for (int n = wid; n < NN; n += nw) {
    int beg = rowptr[n], end = rowptr[n + 1];
    float a0 = 0.f, a1 = 0.f;
    int i = beg;
    for (; i + 1 < end; i += 2) {
      int s0 = csr[i], s1 = csr[i + 1];
      float ns0 = normO[s0], ns1 = normO[s1];
      float2 v0 = *(const float2*)(x + ((size_t)s0 << 7) + (lane << 1));
      float2 v1 = *(const float2*)(x + ((size_t)s1 << 7) + (lane << 1));
      a0 += ns0 * v0.x + ns1 * v1.x;
      a1 += ns0 * v0.y + ns1 * v1.y;
    }
    if (i < end) {
      int s0 = csr[i];
      float ns0 = normO[s0];
      float2 v0 = *(const float2*)(x + ((size_t)s0 << 7) + (lane << 1));
      a0 += ns0 * v0.x; a1 += ns0 * v0.y;
    }
    float ni = normI[n];
    *(unsigned*)(agg + ((size_t)n << 7) + (lane << 1)) = pack2bf(a0 * ni, a1 * ni);
  }
}

// ---------------- gather layer 2: h1s already normO-prescaled bf16 ----------------
__global__ __launch_bounds__(256) void k_gather2(
    const unsigned short* __restrict__ h1s, const int* __restrict__ rowptr,
    const int* __restrict__ csr, const float* __restrict__ normI,
    unsigned short* __restrict__ agg) {
  int wid = (blockIdx.x * 256 + threadIdx.x) >> 6;
  int lane = threadIdx.x & 63;
  int nw = (gridDim.x * 256) >> 6;
  for (int n = wid; n < NN; n += nw) {
    int beg = rowptr[n], end = rowptr[n + 1];
    float a0 = 0.f, a1 = 0.f, a2 = 0.f, a3 = 0.f;
    int i = beg;
    for (; i + 1 < end; i += 2) {
      int s0 = csr[i], s1 = csr[i + 1];
      uint2 v0 = *(const uint2*)(h1s + ((size_t)s0 << 8) + (lane << 2));
      uint2 v1 = *(const uint2*)(h1s + ((size_t)s1 << 8) + (lane << 2));
      a0 += bf2f(v0.x & 0xFFFFu) + bf2f(v1.x & 0xFFFFu);
      a1 += bf2f(v0.x >> 16) + bf2f(v1.x >> 16);
      a2 += bf2f(v0.y & 0xFFFFu) + bf2f(v1.y & 0xFFFFu);
      a3 += bf2f(v0.y >> 16) + bf2f(v1.y >> 16);
    }
    if (i < end) {
      int s0 = csr[i];
      uint2 v0 = *(const uint2*)(h1s + ((size_t)s0 << 8) + (lane << 2));
      a0 += bf2f(v0.x & 0xFFFFu);
      a1 += bf2f(v0.x >> 16);
      a2 += bf2f(v0.y & 0xFFFFu);
      a3 += bf2f(v0.y >> 16);
    }
    float ni = normI[n];
    *(uint2*)(agg + ((size_t)n << 8) + (lane << 2)) =
        make_uint2(pack2bf(a0 * ni, a1 * ni), pack2bf(a2 * ni, a3 * ni));
  }
}

// ---------------- edge gather: npemb = h[a] + h[b] (bf16 in/out) ----------------
__global__ __launch_bounds__(256) void k_edge_gather(
    const unsigned short* __restrict__ h, const int* __restrict__ ea,
    const int* __restrict__ eb, unsigned short* __restrict__ outp) {
  int wid = (blockIdx.x * 256 + threadIdx.x) >> 6;
  int lane = threadIdx.x & 63;
  int nw = (gridDim.x * 256) >> 6;
  for (int e = wid; e < EE; e += nw) {
    int a = ea[e], b = eb[e];
    uint2 va = *(const uint2*)(h + ((size_t)a << 8) + (lane << 2));
    uint2 vb = *(const uint2*)(h + ((size_t)b << 8) + (lane << 2));
    unsigned r0 = pack2bf(bf2f(va.x & 0xFFFFu) + bf2f(vb.x & 0xFFFFu),
                          bf2f(va.x >> 16) + bf2f(vb.x >> 16));
    unsigned r1 = pack2bf(bf2f(va.y & 0xFFFFu) + bf2f(vb.y & 0xFFFFu),
                          bf2f(va.y >> 16) + bf2f(vb.y >> 16));
    *(uint2*)(outp + ((size_t)e << 8) + (lane << 2)) = make_uint2(r0, r1);
  }
}

// ---------------- tiled MFMA GEMM: C = act(A @ W + bias) [* oscale] ----------------
// A: [M,K] bf16. W: [K,Ntot] f32 (converted to bf16 on staging). C: f32 or bf16.
// Block tile 128 x BN, BK=32, 4 waves 2x2; wave = 64 x BN/2.
template <int K, int BN, bool RELU, bool OSCALE, bool OBF16>
__global__ __launch_bounds__(256) void k_gemm(
    const unsigned short* __restrict__ A, const float* __restrict__ oscale,
    const float* __restrict__ W, const float* __restrict__ bias,
    void* __restrict__ Cv, int M, int Ntot, int ldc) {
  constexpr int NFR = BN / 32;  // 16-col fragments per wave
  __shared__ __align__(16) short At[128 * 40];
  __shared__ __align__(16) short Bt[BN * 40];
  const int t = threadIdx.x;
  const int row0 = blockIdx.x * 128;
  const int col0 = blockIdx.y * BN;
  const int lane = t & 63;
  const int wave = t >> 6;
  const int wr = (wave >> 1) << 6;
  const int wc = (wave & 1) * (BN / 2);
  const int lrow = lane & 15;
  const int lhi = lane >> 4;

  f32x4 acc[4][NFR];
#pragma unroll
  for (int m = 0; m < 4; ++m)
#pragma unroll
    for (int n = 0; n < NFR; ++n) acc[m][n] = (f32x4){0.f, 0.f, 0.f, 0.f};

  for (int k0 = 0; k0 < K; k0 += 32) {
    if (k0) __syncthreads();
    // ---- stage A tile 128x32 bf16 ----
#pragma unroll
    for (int it = 0; it < 2; ++it) {
      int idx = t + it * 256;
      int r = idx >> 2;
      int c8 = (idx & 3) << 3;
      int grow = row0 + r;
      int4 tv = {0, 0, 0, 0};
      if (grow < M) tv = *(const int4*)(A + (size_t)grow * K + k0 + c8);
      *(int4*)&At[r * 40 + c8] = tv;
    }
    // ---- stage B^T tile: Bt[c][kk] = W[k0+kk][col0+c] ----
    if constexpr (BN == 256) {
      int c = t;
#pragma unroll
      for (int kh = 0; kh < 32; kh += 16) {
        const float* wp = W + (size_t)(k0 + kh) * Ntot + col0 + c;
        unsigned ww[8];
#pragma unroll
        for (int i = 0; i < 8; ++i)
          ww[i] = pack2bf(wp[(size_t)(2 * i) * Ntot], wp[(size_t)(2 * i + 1) * Ntot]);
        *(int4*)&Bt[c * 40 + kh] = make_int4((int)ww[0], (int)ww[1], (int)ww[2], (int)ww[3]);
        *(int4*)&Bt[c * 40 + kh + 8] = make_int4((int)ww[4], (int)ww[5], (int)ww[6], (int)ww[7]);
      }
    } else {
      int c = t & 127;
      int kh = (t >> 7) << 4;
      const float* wp = W + (size_t)(k0 + kh) * Ntot + col0 + c;
      unsigned ww[8];
#pragma unroll
      for (int i = 0; i < 8; ++i)
        ww[i] = pack2bf(wp[(size_t)(2 * i) * Ntot], wp[(size_t)(2 * i + 1) * Ntot]);
      *(int4*)&Bt[c * 40 + kh] = make_int4((int)ww[0], (int)ww[1], (int)ww[2], (int)ww[3]);
      *(int4*)&Bt[c * 40 + kh + 8] = make_int4((int)ww[4], (int)ww[5], (int)ww[6], (int)ww[7]);
    }
    __syncthreads();
    // ---- fragments + MFMA ----
    short8 a[4], b[NFR];
#pragma unroll
    for (int m = 0; m < 4; ++m)
      a[m] = *(const short8*)&At[(wr + m * 16 + lrow) * 40 + lhi * 8];
#pragma unroll
    for (int n = 0; n < NFR; ++n)
      b[n] = *(const short8*)&Bt[(wc + n * 16 + lrow) * 40 + lhi * 8];
#pragma unroll
    for (int m = 0; m < 4; ++m)
#pragma unroll
      for (int n = 0; n < NFR; ++n)
        acc[m][n] = __builtin_amdgcn_mfma_f32_16x16x32_bf16(a[m], b[n], acc[m][n], 0, 0, 0);
  }
  // ---- epilogue ----
#pragma unroll
  for (int n = 0; n < NFR; ++n) {
    int col = col0 + wc + n * 16 + lrow;
    float bv = bias[col];
#pragma unroll
    for (int m = 0; m < 4; ++m) {
#pragma unroll
      for (int r = 0; r < 4; ++r) {
        int grow = row0 + wr + m * 16 + lhi * 4 + r;
        if (grow < M) {
          float vv = acc[m][n][r] + bv;
          if (RELU) vv = fmaxf(vv, 0.f);
          if (OSCALE) vv *= oscale[grow];
          if (OBF16)
            ((unsigned short*)Cv)[(size_t)grow * ldc + col] = f2bf(vv);
          else
            ((float*)Cv)[(size_t)grow * ldc + col] = vv;
        }
      }
    }
  }
}

// ---------------- branch elementwise: q, Z, M, A ----------------
__global__ __launch_bounds__(256) void k_branch_ew(
    const unsigned short* __restrict__ npemb, const float* __restrict__ gauss,
    const float* __restrict__ unif, const void* __restrict__ temp_p,
    const float* __restrict__ Wq, const float* __restrict__ bq,
    const float* __restrict__ Wc, const float* __restrict__ bc,
    const float* __restrict__ mean_o, const float* __restrict__ logstd_o,
    float* __restrict__ q_o, float* __restrict__ A_o,
    unsigned short* __restrict__ M_o) {
  __shared__ float WqS[1024];  // [256][4]
  __shared__ float WcS[256];   // [64][4]
  int t = threadIdx.x;
  for (int i = t; i < 1024; i += 256) WqS[i] = Wq[i];
  if (t < 256) WcS[t] = Wc[t];
  __syncthreads();
  float invt = 1.0f / decode_scalar(temp_p);
  float bq0 = bq[0], bq1 = bq[1], bq2 = bq[2], bq3 = bq[3];
  float bc0 = bc[0], bc1 = bc[1], bc2 = bc[2], bc3 = bc[3];
  int wid = (blockIdx.x * 256 + t) >> 6;
  int lane = t & 63;
  int nw = (gridDim.x * 256) >> 6;
  for (int e = wid; e < EE; e += nw) {
    // ---- q = npemb @ Wq + bq ----
    uint2 av = *(const uint2*)(npemb + (size_t)e * 256 + lane * 4);
    float a0 = bf2f(av.x & 0xFFFFu), a1 = bf2f(av.x >> 16);
    float a2 = bf2f(av.y & 0xFFFFu), a3 = bf2f(av.y >> 16);
    const float* wq = &WqS[lane * 16];
    float p0 = a0 * wq[0] + a1 * wq[4] + a2 * wq[8] + a3 * wq[12];
    float p1 = a0 * wq[1] + a1 * wq[5] + a2 * wq[9] + a3 * wq[13];
    float p2 = a0 * wq[2] + a1 * wq[6] + a2 * wq[10] + a3 * wq[14];
    float p3 = a0 * wq[3] + a1 * wq[7] + a2 * wq[11] + a3 * wq[15];
#pragma unroll
    for (int off = 32; off >= 1; off >>= 1) {
      p0 += __shfl_xor(p0, off);
      p1 += __shfl_xor(p1, off);
      p2 += __shfl_xor(p2, off);
      p3 += __shfl_xor(p3, off);
    }
    float q0 = p0 + bq0, q1 = p1 + bq1, q2 = p2 + bq2, q3 = p3 + bq3;
    if (lane == 0) *(float4*)(q_o + (size_t)e * 4) = make_float4(q0, q1, q2, q3);
    // ---- Z = softmax((q + gumbel)/temp) ----
    float qv[4] = {q0, q1, q2, q3};
    float z[4];
    float mx = -1e30f;
    float4 uv = *(const float4*)(unif + (size_t)e * 4);
    float uu[4] = {uv.x, uv.y, uv.z, uv.w};
#pragma unroll
    for (int c = 0; c < 4; ++c) {
      float g = -__logf(-__logf(uu[c] + 1e-7f) + 1e-7f);
      z[c] = (qv[c] + g) * invt;
      mx = fmaxf(mx, z[c]);
    }
    float zs = 0.f;
#pragma unroll
    for (int c = 0; c < 4; ++c) { z[c] = __expf(z[c] - mx); zs += z[c]; }
    float rzs = 1.0f / zs;
    // ---- M[d] = sum_c Z[c]*(gauss*exp(logstd)+mean), lane = d ----
    float macc = 0.f;
#pragma unroll
    for (int c = 0; c < 4; ++c) {
      size_t k = (size_t)e * 256 + c * 64 + lane;
      float nl = gauss[k] * __expf(logstd_o[k]) + mean_o[k];
      macc += z[c] * rzs * nl;
    }
    M_o[(size_t)e * 64 + lane] = f2bf(macc);
    // ---- A = softmax(M @ Wc + bc) ----
    const float* wcp = &WcS[lane * 4];
    float s0 = macc * wcp[0], s1 = macc * wcp[1], s2 = macc * wcp[2], s3 = macc * wcp[3];
#pragma unroll
    for (int off = 32; off >= 1; off >>= 1) {
      s0 += __shfl_xor(s0, off);
      s1 += __shfl_xor(s1, off);
      s2 += __shfl_xor(s2, off);
      s3 += __shfl_xor(s3, off);
    }
    s0 += bc0; s1 += bc1; s2 += bc2; s3 += bc3;
    float am = fmaxf(fmaxf(s0, s1), fmaxf(s2, s3));
    float e0 = __expf(s0 - am), e1 = __expf(s1 - am), e2 = __expf(s2 - am), e3 = __expf(s3 - am);
    float res = 1.0f / (e0 + e1 + e2 + e3);
    if (lane == 0)
      *(float4*)(A_o + (size_t)e * 4) = make_float4(e0 * res, e1 * res, e2 * res, e3 * res);
  }
}

extern "C" void kernel_launch(void* const* d_in, const int* in_sizes, int n_in,
                              void* d_out, int out_size, void* d_ws, size_t ws_size,
                              hipStream_t stream) {
  const float* x = (const float*)d_in[0];
  const int* src = (const int*)d_in[1];
  const int* dst = (const int*)d_in[2];
  const int* pos_src = (const int*)d_in[3];
  const int* pos_dst = (const int*)d_in[4];
  const int* neg_src = (const int*)d_in[5];
  const int* neg_dst = (const int*)d_in[6];
  const float* gauss_pos = (const float*)d_in[7];
  const float* gauss_neg = (const float*)d_in[8];
  const float* unif_pos = (const float*)d_in[9];
  const float* unif_neg = (const float*)d_in[10];
  const void* temp_p = d_in[11];
  const float* W1 = (const float*)d_in[12];
  const float* b1 = (const float*)d_in[13];
  const float* W2 = (const float*)d_in[14];
  const float* b2 = (const float*)d_in[15];
  const float* Wm = (const float*)d_in[16];
  const float* bm = (const float*)d_in[17];
  const float* Wl = (const float*)d_in[18];
  const float* bl = (const float*)d_in[19];
  const float* Wq = (const float*)d_in[20];
  const float* bq = (const float*)d_in[21];
  const float* Wd1 = (const float*)d_in[22];
  const float* bd1 = (const float*)d_in[23];
  const float* WdX = (const float*)d_in[24];
  const float* bdX = (const float*)d_in[25];
  const float* Wc = (const float*)d_in[26];
  const float* bc = (const float*)d_in[27];

  // workspace layout (bytes)
  char* w = (char*)d_ws;
  int* degO = (int*)w;                                    // 401408
  int* degI = (int*)(w + 401408);                         // 401408
  int* rowptr = (int*)(w + 802816);                       // 401408 (NN+1)
  int* cursor = (int*)(w + 1204224);                      // 401408
  float* normO = (float*)(w + 1605632);                   // 401408
  float* normI = (float*)(w + 2007040);                   // 401408
  int* csr = (int*)(w + 2408448);                         // 3201024
  unsigned short* agg1 = (unsigned short*)(w + 5609472);  // [NN,128] bf16 25.6MB
  unsigned short* h1s = (unsigned short*)(w + 31209472);  // [NN,256] bf16 51.2MB
  unsigned short* agg2 = (unsigned short*)(w + 82409472); // [NN,256] bf16 51.2MB
  unsigned short* h = (unsigned short*)(w + 133609472);   // [NN,256] bf16 51.2MB
  unsigned short* npemb = (unsigned short*)(w + 184809472); // [EE,256] bf16 134.2MB
  unsigned short* Mws = (unsigned short*)(w + 319027200);   // [EE,64] bf16 33.6MB
  unsigned short* X1 = (unsigned short*)(w + 352581632);    // [EE,256] bf16 134.2MB
  // total: 486,799,360 B (< round-2's 628MB, fits)

  float* out = (float*)d_out;
  float* posA = out;
  float* negA = out + 1048576ull;
  float* posX = out + 2097152ull;
  float* negX = out + 35651584ull;
  float* pos_mean = out + 69206016ull;
  float* neg_mean = out + 136314880ull;
  float* pos_logstd = out + 203423744ull;
  float* neg_logstd = out + 270532608ull;
  float* posq = out + 337641472ull;
  float* negq = out + 338690048ull;

  // zero degree arrays only (802816 B)
  hipMemsetAsync(d_ws, 0, 802816, stream);

  k_deg<<<1024, 256, 0, stream>>>(src, dst, degO, degI);
  k_norm<<<392, 256, 0, stream>>>(degO, degI, normO, normI);
  k_scan<<<1, 1024, 0, stream>>>(degI, rowptr, cursor);
  k_fill<<<1024, 256, 0, stream>>>(src, dst, cursor, csr);

  // layer 1
  k_gather1<<<2048, 256, 0, stream>>>(x, rowptr, csr, normO, normI, agg1);
  k_gemm<128, 256, true, true, true><<<dim3(782, 1), 256, 0, stream>>>(
      agg1, normO, W1, b1, h1s, NN, 256, 256);
  // layer 2
  k_gather2<<<2048, 256, 0, stream>>>(h1s, rowptr, csr, normI, agg2);
  k_gemm<256, 256, false, false, true><<<dim3(782, 1), 256, 0, stream>>>(
      agg2, nullptr, W2, b2, h, NN, 256, 256);

  for (int b = 0; b < 2; ++b) {
    const int* es = b ? neg_src : pos_src;
    const int* ed = b ? neg_dst : pos_dst;
    const float* gs = b ? gauss_neg : gauss_pos;
    const float* uf = b ? unif_neg : unif_pos;
    float* o_mean = b ? neg_mean : pos_mean;
    float* o_ls = b ? neg_logstd : pos_logstd;
    float* o_q = b ? negq : posq;
    float* o_A = b ? negA : posA;
    float* o_X = b ? negX : posX;

    k_edge_gather<<<2048, 256, 0, stream>>>(h, es, ed, npemb);
    k_gemm<256, 256, false, false, false><<<dim3(2048, 1), 256, 0, stream>>>(
        npemb, nullptr, Wm, bm, o_mean, EE, 256, 256);
    k_gemm<256, 256, false, false, false><<<dim3(2048, 1), 256, 0, stream>>>(
        npemb, nullptr, Wl, bl, o_ls, EE, 256, 256);
    k_branch_ew<<<2048, 256, 0, stream>>>(npemb, gs, uf, temp_p, Wq, bq, Wc, bc,
                                          o_mean, o_ls, o_q, o_A, Mws);
    k_gemm<64, 256, true, false, true><<<dim3(2048, 1), 256, 0, stream>>>(
        Mws, nullptr, Wd1, bd1, X1, EE, 256, 256);
    k_gemm<256, 128, true, false, false><<<dim3(2048, 1), 256, 0, stream>>>(
        X1, nullptr, WdX, bdX, o_X, EE, 128, 128);
  }
}

// Round 4
// 2158.245 us; speedup vs baseline: 2.6363x; 1.1317x over previous
//
#include <hip/hip_runtime.h>
#include <hip/hip_bf16.h>

// Round 4: fused branch head (gather+dual GEMM+softmax head), fused decoder,
// bf16 pre-transposed weights, dual-edge vectorized CSR gathers.

#define NN 100000
#define EG 800000
#define EE 262144

typedef __attribute__((ext_vector_type(8))) short short8;
typedef __attribute__((ext_vector_type(4))) float f32x4;

__device__ __forceinline__ float bf2f(unsigned u16) {
  union { unsigned u; float f; } v; v.u = u16 << 16; return v.f;
}
__device__ __forceinline__ unsigned short f2bf(float f) {
  union { float f; unsigned u; } v; v.f = f;
  return (unsigned short)((v.u + 0x7FFFu + ((v.u >> 16) & 1u)) >> 16);
}
__device__ __forceinline__ unsigned pack2bf(float a, float b) {
  return (unsigned)f2bf(a) | ((unsigned)f2bf(b) << 16);
}

__device__ __forceinline__ float decode_scalar(const void* p) {
  unsigned u = *(const unsigned*)p;
  float f = __uint_as_float(u);
  float af = fabsf(f);
  if (af >= 1e-6f && af <= 1e6f) return f;  // plausible f32
  if (u < 1024u) return (float)u;           // small int
  return 1.0f;
}

// ---------------- degrees + norms ----------------
__global__ __launch_bounds__(256) void k_deg(const int* __restrict__ src,
                                             const int* __restrict__ dst,
                                             int* __restrict__ degO,
                                             int* __restrict__ degI) {
  for (int i = blockIdx.x * 256 + threadIdx.x; i < EG; i += gridDim.x * 256) {
    atomicAdd(&degO[src[i]], 1);
    atomicAdd(&degI[dst[i]], 1);
  }
}

__global__ __launch_bounds__(256) void k_norm(const int* __restrict__ degO,
                                              const int* __restrict__ degI,
                                              float* __restrict__ normO,
                                              float* __restrict__ normI) {
  int i = blockIdx.x * 256 + threadIdx.x;
  if (i < NN) {
    int dO = degO[i]; if (dO < 1) dO = 1;
    int dI = degI[i]; if (dI < 1) dI = 1;
    normO[i] = rsqrtf((float)dO);
    normI[i] = rsqrtf((float)dI);
  }
}

// ---------------- exclusive scan of degI -> rowptr, cursor ----------------
__global__ __launch_bounds__(1024) void k_scan(const int* __restrict__ degI,
                                               int* __restrict__ rowptr,
                                               int* __restrict__ cursor) {
  __shared__ int wsum[16];
  __shared__ int carry_s;
  __shared__ int tot_s;
  int t = threadIdx.x, lane = t & 63, wv = t >> 6;
  if (t == 0) carry_s = 0;
  __syncthreads();
  for (int base = 0; base < NN; base += 1024) {
    int c0 = carry_s;
    int i = base + t;
    int v = (i < NN) ? degI[i] : 0;
    int incl = v;
#pragma unroll
    for (int off = 1; off < 64; off <<= 1) {
      int u = __shfl_up(incl, off);
      if (lane >= off) incl += u;
    }
    if (lane == 63) wsum[wv] = incl;
    __syncthreads();
    if (wv == 0 && lane < 16) {
      int s = wsum[lane];
      int si = s;
#pragma unroll
      for (int off = 1; off < 16; off <<= 1) {
        int u = __shfl_up(si, off);
        if (lane >= off) si += u;
      }
      wsum[lane] = si - s;
      if (lane == 15) tot_s = si;
    }
    __syncthreads();
    int excl = c0 + wsum[wv] + incl - v;
    if (i < NN) { rowptr[i] = excl; cursor[i] = excl; }
    __syncthreads();
    if (t == 0) carry_s = c0 + tot_s;
    __syncthreads();
  }
  if (threadIdx.x == 0) rowptr[NN] = carry_s;
}

// ---------------- fill CSR buckets ----------------
__global__ __launch_bounds__(256) void k_fill(const int* __restrict__ src,
                                              const int* __restrict__ dst,
                                              int* __restrict__ cursor,
                                              int* __restrict__ csr) {
  for (int e = blockIdx.x * 256 + threadIdx.x; e < EG; e += gridDim.x * 256) {
    int d = dst[e];
    int pos = atomicAdd(&cursor[d], 1);
    csr[pos] = src[e];
  }
}

// ---------------- weight transpose f32[K][N] -> bf16[N][K] ----------------
__global__ __launch_bounds__(256) void k_transpose(const float* __restrict__ in,
                                                   unsigned short* __restrict__ out,
                                                   int K, int Nmask, int logN, int total) {
  for (int idx = blockIdx.x * 256 + threadIdx.x; idx < total; idx += gridDim.x * 256) {
    int n = idx & Nmask;
    int k = idx >> logN;
    out[(size_t)n * K + k] = f2bf(in[idx]);
  }
}

// ---------------- gather layer 1 (x f32 [NN,128]) ----------------
__global__ __launch_bounds__(256) void k_gather1(
    const float* __restrict__ x, const int* __restrict__ rowptr,
    const int* __restrict__ csr, const float* __restrict__ normO,
    const float* __restrict__ normI, unsigned short* __restrict__ agg) {
  int wid = (blockIdx.x * 256 + threadIdx.x) >> 6;
  int lane = threadIdx.x & 63;
  int half = lane >> 5, fl = lane & 31;
  int nw = (gridDim.x * 256) >> 6;
  for (int n = wid; n < NN; n += nw) {
    int beg = rowptr[n], end = rowptr[n + 1];
    float a0 = 0.f, a1 = 0.f, a2 = 0.f, a3 = 0.f;
    for (int i = beg + half; i < end; i += 2) {
      int s = csr[i];
      float ns = normO[s];
      float4 v = *(const float4*)(x + ((size_t)s << 7) + (fl << 2));
      a0 += ns * v.x; a1 += ns * v.y; a2 += ns * v.z; a3 += ns * v.w;
    }
    a0 += __shfl_xor(a0, 32); a1 += __shfl_xor(a1, 32);
    a2 += __shfl_xor(a2, 32); a3 += __shfl_xor(a3, 32);
    if (lane < 32) {
      float ni = normI[n];
      *(uint2*)(agg + ((size_t)n << 7) + (fl << 2)) =
          make_uint2(pack2bf(a0 * ni, a1 * ni), pack2bf(a2 * ni, a3 * ni));
    }
  }
}

// ---------------- gather layer 2 (h1s bf16 [NN,256], normO pre-baked) ----------------
__global__ __launch_bounds__(256) void k_gather2(
    const unsigned short* __restrict__ h1s, const int* __restrict__ rowptr,
    const int* __restrict__ csr, const float* __restrict__ normI,
    unsigned short* __restrict__ agg) {
  int wid = (blockIdx.x * 256 + threadIdx.x) >> 6;
  int lane = threadIdx.x & 63;
  int half = lane >> 5, fl = lane & 31;
  int nw = (gridDim.x * 256) >> 6;
  for (int n = wid; n < NN; n += nw) {
    int beg = rowptr[n], end = rowptr[n + 1];
    float a0 = 0.f, a1 = 0.f, a2 = 0.f, a3 = 0.f, a4 = 0.f, a5 = 0.f, a6 = 0.f, a7 = 0.f;
    for (int i = beg + half; i < end; i += 2) {
      int s = csr[i];
      uint4 v = *(const uint4*)(h1s + ((size_t)s << 8) + (fl << 3));
      a0 += bf2f(v.x & 0xFFFFu); a1 += bf2f(v.x >> 16);
      a2 += bf2f(v.y & 0xFFFFu); a3 += bf2f(v.y >> 16);
      a4 += bf2f(v.z & 0xFFFFu); a5 += bf2f(v.z >> 16);
      a6 += bf2f(v.w & 0xFFFFu); a7 += bf2f(v.w >> 16);
    }
    a0 += __shfl_xor(a0, 32); a1 += __shfl_xor(a1, 32);
    a2 += __shfl_xor(a2, 32); a3 += __shfl_xor(a3, 32);
    a4 += __shfl_xor(a4, 32); a5 += __shfl_xor(a5, 32);
    a6 += __shfl_xor(a6, 32); a7 += __shfl_xor(a7, 32);
    if (lane < 32) {
      float ni = normI[n];
      uint4 o;
      o.x = pack2bf(a0 * ni, a1 * ni);
      o.y = pack2bf(a2 * ni, a3 * ni);
      o.z = pack2bf(a4 * ni, a5 * ni);
      o.w = pack2bf(a6 * ni, a7 * ni);
      *(uint4*)(agg + ((size_t)n << 8) + (fl << 3)) = o;
    }
  }
}

// ---------------- encoder GEMM: C_bf16 = act(A_bf16 @ W + b) [* oscale] ----------------
// A [M,K] bf16, WT [256][K] bf16 (pre-transposed), C [M,256] bf16.
template <int K, bool RELU, bool OSCALE>
__global__ __launch_bounds__(256) void k_gemm(
    const unsigned short* __restrict__ A, const float* __restrict__ oscale,
    const unsigned short* __restrict__ WT, const float* __restrict__ bias,
    unsigned short* __restrict__ C, int M) {
  __shared__ __align__(16) short At[128 * 40];
  __shared__ __align__(16) short Bt[256 * 40];
  const int t = threadIdx.x;
  const int row0 = blockIdx.x * 128;
  const int lane = t & 63, wave = t >> 6;
  const int wr = (wave >> 1) << 6;
  const int wcc = (wave & 1) << 7;
  const int lrow = lane & 15, lhi = lane >> 4;

  f32x4 acc[4][8];
#pragma unroll
  for (int m = 0; m < 4; ++m)
#pragma unroll
    for (int n = 0; n < 8; ++n) acc[m][n] = (f32x4){0.f, 0.f, 0.f, 0.f};

  for (int k0 = 0; k0 < K; k0 += 32) {
    if (k0) __syncthreads();
#pragma unroll
    for (int it = 0; it < 2; ++it) {
      int idx = t + it * 256;
      int r = idx >> 2, c8 = (idx & 3) << 3;
      int grow = row0 + r;
      int4 tv = {0, 0, 0, 0};
      if (grow < M) tv = *(const int4*)(A + (size_t)grow * K + k0 + c8);
      *(int4*)&At[r * 40 + c8] = tv;
    }
    {
      const unsigned short* wt = WT + (size_t)t * K + k0;
      *(int4*)&Bt[t * 40 + 0] = *(const int4*)(wt);
      *(int4*)&Bt[t * 40 + 8] = *(const int4*)(wt + 8);
      *(int4*)&Bt[t * 40 + 16] = *(const int4*)(wt + 16);
      *(int4*)&Bt[t * 40 + 24] = *(const int4*)(wt + 24);
    }
    __syncthreads();
    short8 a[4], b[8];
#pragma unroll
    for (int m = 0; m < 4; ++m)
      a[m] = *(const short8*)&At[(wr + m * 16 + lrow) * 40 + lhi * 8];
#pragma unroll
    for (int n = 0; n < 8; ++n)
      b[n] = *(const short8*)&Bt[(wcc + n * 16 + lrow) * 40 + lhi * 8];
#pragma unroll
    for (int m = 0; m < 4; ++m)
#pragma unroll
      for (int n = 0; n < 8; ++n)
        acc[m][n] = __builtin_amdgcn_mfma_f32_16x16x32_bf16(a[m], b[n], acc[m][n], 0, 0, 0);
  }
#pragma unroll
  for (int n = 0; n < 8; ++n) {
    int col = wcc + n * 16 + lrow;
    float bv = bias[col];
#pragma unroll
    for (int m = 0; m < 4; ++m) {
#pragma unroll
      for (int r = 0; r < 4; ++r) {
        int grow = row0 + wr + m * 16 + lhi * 4 + r;
        if (grow < M) {
          float vv = acc[m][n][r] + bv;
          if (RELU) vv = fmaxf(vv, 0.f);
          if (OSCALE) vv *= oscale[grow];
          C[(size_t)grow * 256 + col] = f2bf(vv);
        }
      }
    }
  }
}

// ---------------- fused branch: mean/logstd GEMMs + q + Z + M + A ----------------
// 64 edges/block; A-tile gathered as h[ea]+h[eb]; dual MFMA accumulators.
__global__ __launch_bounds__(256, 2) void k_branch_fused(
    const unsigned short* __restrict__ h, const int* __restrict__ ea,
    const int* __restrict__ eb, const float* __restrict__ gauss,
    const float* __restrict__ unif, const void* __restrict__ temp_p,
    const unsigned short* __restrict__ WmT, const float* __restrict__ bm,
    const unsigned short* __restrict__ WlT, const float* __restrict__ bl,
    const float* __restrict__ Wq, const float* __restrict__ bq,
    const float* __restrict__ Wc, const float* __restrict__ bc,
    float* __restrict__ o_mean, float* __restrict__ o_ls,
    float* __restrict__ q_o, float* __restrict__ A_o,
    unsigned short* __restrict__ M_o) {
  __shared__ __align__(16) char U[66560];   // union: staging | Nl[64][260] f32
  short* At = (short*)U;                    // [64][40]
  short* Btm = (short*)(U + 5120);          // [256][40]
  short* Btl = (short*)(U + 25600);         // [256][40]
  float* Nl = (float*)U;
  __shared__ float WqS[1024];               // [256][4]
  __shared__ float WcS[256];                // [64][4]
  __shared__ float bmS[256], blS[256];
  __shared__ float zS[256];                 // [64][4]
  __shared__ int eaS[64], ebS[64];

  const int t = threadIdx.x;
  const int e0 = blockIdx.x << 6;
  const int lane = t & 63;
  const int wave = t >> 6;
  const int lrow = lane & 15;
  const int lhi = lane >> 4;
  const int wc = wave << 6;

  for (int i = t; i < 1024; i += 256) WqS[i] = Wq[i];
  WcS[t] = Wc[t];
  bmS[t] = bm[t];
  blS[t] = bl[t];
  if (t < 64) eaS[t] = ea[e0 + t];
  else if (t < 128) ebS[t - 64] = eb[e0 + t - 64];
  __syncthreads();

  f32x4 am[4][4], al[4][4];
#pragma unroll
  for (int m = 0; m < 4; ++m)
#pragma unroll
    for (int n = 0; n < 4; ++n) {
      am[m][n] = (f32x4){0.f, 0.f, 0.f, 0.f};
      al[m][n] = (f32x4){0.f, 0.f, 0.f, 0.f};
    }
  float qpart = 0.f;
  const int qe = t >> 2, qc = t & 3;
  const int ar = t >> 2, ac8 = (t & 3) << 3;

  for (int k0 = 0; k0 < 256; k0 += 32) {
    if (k0) __syncthreads();
    // A-stage: gather h[a]+h[b] directly (npemb never materialized)
    {
      const unsigned short* pa = h + ((size_t)eaS[ar] << 8) + k0 + ac8;
      const unsigned short* pb = h + ((size_t)ebS[ar] << 8) + k0 + ac8;
      uint4 va = *(const uint4*)pa;
      uint4 vb = *(const uint4*)pb;
      unsigned w0 = pack2bf(bf2f(va.x & 0xFFFFu) + bf2f(vb.x & 0xFFFFu),
                            bf2f(va.x >> 16) + bf2f(vb.x >> 16));
      unsigned w1 = pack2bf(bf2f(va.y & 0xFFFFu) + bf2f(vb.y & 0xFFFFu),
                            bf2f(va.y >> 16) + bf2f(vb.y >> 16));
      unsigned w2 = pack2bf(bf2f(va.z & 0xFFFFu) + bf2f(vb.z & 0xFFFFu),
                            bf2f(va.z >> 16) + bf2f(vb.z >> 16));
      unsigned w3 = pack2bf(bf2f(va.w & 0xFFFFu) + bf2f(vb.w & 0xFFFFu),
                            bf2f(va.w >> 16) + bf2f(vb.w >> 16));
      *(int4*)&At[ar * 40 + ac8] = make_int4((int)w0, (int)w1, (int)w2, (int)w3);
    }
    // B-stage: both weight matrices from bf16 [N][K] layout
    {
      const unsigned short* wm = WmT + ((size_t)t << 8) + k0;
      const unsigned short* wl = WlT + ((size_t)t << 8) + k0;
      *(int4*)&Btm[t * 40 + 0] = *(const int4*)(wm);
      *(int4*)&Btm[t * 40 + 8] = *(const int4*)(wm + 8);
      *(int4*)&Btm[t * 40 + 16] = *(const int4*)(wm + 16);
      *(int4*)&Btm[t * 40 + 24] = *(const int4*)(wm + 24);
      *(int4*)&Btl[t * 40 + 0] = *(const int4*)(wl);
      *(int4*)&Btl[t * 40 + 8] = *(const int4*)(wl + 8);
      *(int4*)&Btl[t * 40 + 16] = *(const int4*)(wl + 16);
      *(int4*)&Btl[t * 40 + 24] = *(const int4*)(wl + 24);
    }
    __syncthreads();
    short8 a[4], bmf[4], blf[4];
#pragma unroll
    for (int m = 0; m < 4; ++m)
      a[m] = *(const short8*)&At[(m * 16 + lrow) * 40 + lhi * 8];
#pragma unroll
    for (int n = 0; n < 4; ++n) {
      bmf[n] = *(const short8*)&Btm[(wc + n * 16 + lrow) * 40 + lhi * 8];
      blf[n] = *(const short8*)&Btl[(wc + n * 16 + lrow) * 40 + lhi * 8];
    }
#pragma unroll
    for (int m = 0; m < 4; ++m)
#pragma unroll
      for (int n = 0; n < 4; ++n) {
        am[m][n] = __builtin_amdgcn_mfma_f32_16x16x32_bf16(a[m], bmf[n], am[m][n], 0, 0, 0);
        al[m][n] = __builtin_amdgcn_mfma_f32_16x16x32_bf16(a[m], blf[n], al[m][n], 0, 0, 0);
      }
    // q partial: thread owns (edge qe, cat qc)
    {
      const short* rp = &At[qe * 40];
#pragma unroll
      for (int j = 0; j < 4; ++j) {
        short8 v = *(const short8*)(rp + j * 8);
#pragma unroll
        for (int u = 0; u < 8; ++u)
          qpart += bf2f((unsigned short)v[u]) * WqS[((k0 + j * 8 + u) << 2) + qc];
      }
    }
  }
  __syncthreads();  // staging dead; Nl aliases it

  // epilogue 1: mean / logstd / Nlat
#pragma unroll
  for (int n = 0; n < 4; ++n) {
    int col = wc + n * 16 + lrow;
    float bmv = bmS[col], blv = blS[col];
#pragma unroll
    for (int m = 0; m < 4; ++m) {
#pragma unroll
      for (int r = 0; r < 4; ++r) {
        int row = m * 16 + lhi * 4 + r;
        size_t gi = (((size_t)(e0 + row)) << 8) + col;
        float mv = am[m][n][r] + bmv;
        float lv = al[m][n][r] + blv;
        o_mean[gi] = mv;
        o_ls[gi] = lv;
        Nl[row * 260 + col] = gauss[gi] * __expf(lv) + mv;
      }
    }
  }

  // q / Z (thread = (edge, cat))
  float invt = 1.0f / decode_scalar(temp_p);
  float qv = qpart + bq[qc];
  q_o[((size_t)e0 << 2) + t] = qv;
  float uu = unif[((size_t)e0 << 2) + t];
  float g = -__logf(-__logf(uu + 1e-7f) + 1e-7f);
  float z = (qv + g) * invt;
  float mx = fmaxf(z, __shfl_xor(z, 1));
  mx = fmaxf(mx, __shfl_xor(mx, 2));
  float ez = __expf(z - mx);
  float sz = ez + __shfl_xor(ez, 1);
  sz += __shfl_xor(sz, 2);
  zS[t] = ez / sz;
  __syncthreads();

  // M + A: wave handles 16 edges, lane = d
  float bc0 = bc[0], bc1 = bc[1], bc2 = bc[2], bc3 = bc[3];
  const float* wcp = &WcS[lane * 4];
  float wc0 = wcp[0], wc1v = wcp[1], wc2v = wcp[2], wc3v = wcp[3];
  for (int el = 0; el < 16; ++el) {
    int e = (wave << 4) + el;
    float z0 = zS[e * 4 + 0], z1 = zS[e * 4 + 1], z2 = zS[e * 4 + 2], z3 = zS[e * 4 + 3];
    const float* np = &Nl[e * 260 + lane];
    float mval = z0 * np[0] + z1 * np[64] + z2 * np[128] + z3 * np[192];
    M_o[((size_t)(e0 + e) << 6) + lane] = f2bf(mval);
    float s0 = mval * wc0, s1 = mval * wc1v, s2 = mval * wc2v, s3 = mval * wc3v;
#pragma unroll
    for (int off = 32; off >= 1; off >>= 1) {
      s0 += __shfl_xor(s0, off);
      s1 += __shfl_xor(s1, off);
      s2 += __shfl_xor(s2, off);
      s3 += __shfl_xor(s3, off);
    }
    s0 += bc0; s1 += bc1; s2 += bc2; s3 += bc3;
    float amx = fmaxf(fmaxf(s0, s1), fmaxf(s2, s3));
    float e0f = __expf(s0 - amx), e1f = __expf(s1 - amx);
    float e2f = __expf(s2 - amx), e3f = __expf(s3 - amx);
    float res = 1.0f / (e0f + e1f + e2f + e3f);
    if (lane == 0)
      *(float4*)(A_o + ((size_t)(e0 + e) << 2)) =
          make_float4(e0f * res, e1f * res, e2f * res, e3f * res);
  }
}

// ---------------- fused decoder: X = relu(relu(M@Wd1+bd1)@WdX+bdX) ----------------
__global__ __launch_bounds__(256, 2) void k_dec(
    const unsigned short* __restrict__ Mw, const unsigned short* __restrict__ Wd1T,
    const float* __restrict__ bd1, const unsigned short* __restrict__ WdXT,
    const float* __restrict__ bdX, float* __restrict__ Xo) {
  __shared__ __align__(16) char U2[25600];  // union: (Mt+Bt1) | Bt2
  short* Mt = (short*)U2;                    // [64][40]
  short* Bt1 = (short*)(U2 + 5120);          // [256][40]
  short* Bt2 = (short*)U2;                   // [128][40]
  __shared__ __align__(16) short X1[64 * 264];
  const int t = threadIdx.x, lane = t & 63, wave = t >> 6;
  const int lrow = lane & 15, lhi = lane >> 4;
  const int e0 = blockIdx.x << 6;

  // ---- stage 1: X1 = relu(M @ Wd1 + bd1)  (64x256, K=64) ----
  f32x4 acc1[4][4];
#pragma unroll
  for (int m = 0; m < 4; ++m)
#pragma unroll
    for (int n = 0; n < 4; ++n) acc1[m][n] = (f32x4){0.f, 0.f, 0.f, 0.f};
  const int wc1 = wave << 6;
  for (int k0 = 0; k0 < 64; k0 += 32) {
    if (k0) __syncthreads();
    {
      int r = t >> 2, c8 = (t & 3) << 3;
      *(int4*)&Mt[r * 40 + c8] = *(const int4*)(Mw + ((size_t)(e0 + r) << 6) + k0 + c8);
    }
    {
      const unsigned short* wt = Wd1T + ((size_t)t << 6) + k0;
      *(int4*)&Bt1[t * 40 + 0] = *(const int4*)(wt);
      *(int4*)&Bt1[t * 40 + 8] = *(const int4*)(wt + 8);
      *(int4*)&Bt1[t * 40 + 16] = *(const int4*)(wt + 16);
      *(int4*)&Bt1[t * 40 + 24] = *(const int4*)(wt + 24);
    }
    __syncthreads();
    short8 a[4], b[4];
#pragma unroll
    for (int m = 0; m < 4; ++m)
      a[m] = *(const short8*)&Mt[(m * 16 + lrow) * 40 + lhi * 8];
#pragma unroll
    for (int n = 0; n < 4; ++n)
      b[n] = *(const short8*)&Bt1[(wc1 + n * 16 + lrow) * 40 + lhi * 8];
#pragma unroll
    for (int m = 0; m < 4; ++m)
#pragma unroll
      for (int n = 0; n < 4; ++n)
        acc1[m][n] = __builtin_amdgcn_mfma_f32_16x16x32_bf16(a[m], b[n], acc1[m][n], 0, 0, 0);
  }
  // X1 -> LDS (bf16, stride 264)
#pragma unroll
  for (int n = 0; n < 4; ++n) {
    int col = wc1 + n * 16 + lrow;
    float bv = bd1[col];
#pragma unroll
    for (int m = 0; m < 4; ++m) {
#pragma unroll
      for (int r = 0; r < 4; ++r) {
        int row = m * 16 + lhi * 4 + r;
        X1[row * 264 + col] = (short)f2bf(fmaxf(acc1[m][n][r] + bv, 0.f));
      }
    }
  }
  __syncthreads();

  // ---- stage 2: X = relu(X1 @ WdX + bdX)  (64x128, K=256) ----
  f32x4 acc2[4][2];
#pragma unroll
  for (int m = 0; m < 4; ++m)
#pragma unroll
    for (int n = 0; n < 2; ++n) acc2[m][n] = (f32x4){0.f, 0.f, 0.f, 0.f};
  const int wc2 = wave << 5;
  for (int k0 = 0; k0 < 256; k0 += 32) {
    if (k0) __syncthreads();
    {
      int c = t & 127, kh = (t >> 7) << 4;
      const unsigned short* wt = WdXT + ((size_t)c << 8) + k0 + kh;
      *(int4*)&Bt2[c * 40 + kh] = *(const int4*)(wt);
      *(int4*)&Bt2[c * 40 + kh + 8] = *(const int4*)(wt + 8);
    }
    __syncthreads();
    short8 a[4], b[2];
#pragma unroll
    for (int m = 0; m < 4; ++m)
      a[m] = *(const short8*)&X1[(m * 16 + lrow) * 264 + k0 + lhi * 8];
#pragma unroll
    for (int n = 0; n < 2; ++n)
      b[n] = *(const short8*)&Bt2[(wc2 + n * 16 + lrow) * 40 + lhi * 8];
#pragma unroll
    for (int m = 0; m < 4; ++m)
#pragma unroll
      for (int n = 0; n < 2; ++n)
        acc2[m][n] = __builtin_amdgcn_mfma_f32_16x16x32_bf16(a[m], b[n], acc2[m][n], 0, 0, 0);
  }
#pragma unroll
  for (int n = 0; n < 2; ++n) {
    int col = wc2 + n * 16 + lrow;
    float bv = bdX[col];
#pragma unroll
    for (int m = 0; m < 4; ++m) {
#pragma unroll
      for (int r = 0; r < 4; ++r) {
        int row = m * 16 + lhi * 4 + r;
        Xo[((size_t)(e0 + row) << 7) + col] = fmaxf(acc2[m][n][r] + bv, 0.f);
      }
    }
  }
}

extern "C" void kernel_launch(void* const* d_in, const int* in_sizes, int n_in,
                              void* d_out, int out_size, void* d_ws, size_t ws_size,
                              hipStream_t stream) {
  const float* x = (const float*)d_in[0];
  const int* src = (const int*)d_in[1];
  const int* dst = (const int*)d_in[2];
  const int* pos_src = (const int*)d_in[3];
  const int* pos_dst = (const int*)d_in[4];
  const int* neg_src = (const int*)d_in[5];
  const int* neg_dst = (const int*)d_in[6];
  const float* gauss_pos = (const float*)d_in[7];
  const float* gauss_neg = (const float*)d_in[8];
  const float* unif_pos = (const float*)d_in[9];
  const float* unif_neg = (const float*)d_in[10];
  const void* temp_p = d_in[11];
  const float* W1 = (const float*)d_in[12];
  const float* b1 = (const float*)d_in[13];
  const float* W2 = (const float*)d_in[14];
  const float* b2 = (const float*)d_in[15];
  const float* Wm = (const float*)d_in[16];
  const float* bm = (const float*)d_in[17];
  const float* Wl = (const float*)d_in[18];
  const float* bl = (const float*)d_in[19];
  const float* Wq = (const float*)d_in[20];
  const float* bq = (const float*)d_in[21];
  const float* Wd1 = (const float*)d_in[22];
  const float* bd1 = (const float*)d_in[23];
  const float* WdX = (const float*)d_in[24];
  const float* bdX = (const float*)d_in[25];
  const float* Wc = (const float*)d_in[26];
  const float* bc = (const float*)d_in[27];

  char* w = (char*)d_ws;
  int* degO = (int*)w;                                       // 401408
  int* degI = (int*)(w + 401408);
  int* rowptr = (int*)(w + 802816);
  int* cursor = (int*)(w + 1204224);
  float* normO = (float*)(w + 1605632);
  float* normI = (float*)(w + 2007040);
  int* csr = (int*)(w + 2408448);                            // 3201024
  unsigned short* W1T = (unsigned short*)(w + 5609472);      // [256][128] 65536
  unsigned short* W2T = (unsigned short*)(w + 5675008);      // [256][256] 131072
  unsigned short* WmT = (unsigned short*)(w + 5806080);      // 131072
  unsigned short* WlT = (unsigned short*)(w + 5937152);      // 131072
  unsigned short* Wd1T = (unsigned short*)(w + 6068224);     // [256][64] 32768
  unsigned short* WdXT = (unsigned short*)(w + 6100992);     // [128][256] 65536
  unsigned short* agg1 = (unsigned short*)(w + 6166528);     // [NN,128] bf16 25.6MB
  unsigned short* h1s = (unsigned short*)(w + 31766528);     // [NN,256] bf16 51.2MB
  unsigned short* agg2 = (unsigned short*)(w + 82966528);    // [NN,256] bf16
  unsigned short* h = (unsigned short*)(w + 134166528);      // [NN,256] bf16
  unsigned short* Mws = (unsigned short*)(w + 185366528);    // [EE,64] bf16 33.5MB
  // total ~219 MB

  float* out = (float*)d_out;
  float* posA = out;
  float* negA = out + 1048576ull;
  float* posX = out + 2097152ull;
  float* negX = out + 35651584ull;
  float* pos_mean = out + 69206016ull;
  float* neg_mean = out + 136314880ull;
  float* pos_logstd = out + 203423744ull;
  float* neg_logstd = out + 270532608ull;
  float* posq = out + 337641472ull;
  float* negq = out + 338690048ull;

  hipMemsetAsync(d_ws, 0, 802816, stream);

  k_deg<<<1024, 256, 0, stream>>>(src, dst, degO, degI);
  k_norm<<<392, 256, 0, stream>>>(degO, degI, normO, normI);
  k_scan<<<1, 1024, 0, stream>>>(degI, rowptr, cursor);
  k_fill<<<1024, 256, 0, stream>>>(src, dst, cursor, csr);

  // weight transposes (f32 [K][N] -> bf16 [N][K])
  k_transpose<<<128, 256, 0, stream>>>(W1, W1T, 128, 255, 8, 32768);
  k_transpose<<<256, 256, 0, stream>>>(W2, W2T, 256, 255, 8, 65536);
  k_transpose<<<256, 256, 0, stream>>>(Wm, WmT, 256, 255, 8, 65536);
  k_transpose<<<256, 256, 0, stream>>>(Wl, WlT, 256, 255, 8, 65536);
  k_transpose<<<64, 256, 0, stream>>>(Wd1, Wd1T, 64, 255, 8, 16384);
  k_transpose<<<128, 256, 0, stream>>>(WdX, WdXT, 256, 127, 7, 32768);

  // encoder
  k_gather1<<<2048, 256, 0, stream>>>(x, rowptr, csr, normO, normI, agg1);
  k_gemm<128, true, true><<<782, 256, 0, stream>>>(agg1, normO, W1T, b1, h1s, NN);
  k_gather2<<<2048, 256, 0, stream>>>(h1s, rowptr, csr, normI, agg2);
  k_gemm<256, false, false><<<782, 256, 0, stream>>>(agg2, nullptr, W2T, b2, h, NN);

  for (int b = 0; b < 2; ++b) {
    const int* es = b ? neg_src : pos_src;
    const int* ed = b ? neg_dst : pos_dst;
    const float* gs = b ? gauss_neg : gauss_pos;
    const float* uf = b ? unif_neg : unif_pos;
    float* o_mean = b ? neg_mean : pos_mean;
    float* o_ls = b ? neg_logstd : pos_logstd;
    float* o_q = b ? negq : posq;
    float* o_A = b ? negA : posA;
    float* o_X = b ? negX : posX;

    k_branch_fused<<<4096, 256, 0, stream>>>(h, es, ed, gs, uf, temp_p,
                                             WmT, bm, WlT, bl, Wq, bq, Wc, bc,
                                             o_mean, o_ls, o_q, o_A, Mws);
    k_dec<<<4096, 256, 0, stream>>>(Mws, Wd1T, bd1, WdXT, bdX, o_X);
  }
}

// Round 5
// 1865.294 us; speedup vs baseline: 3.0504x; 1.1571x over previous
//
#include <hip/hip_runtime.h>
#include <hip/hip_bf16.h>

// Round 5: q via MFMA (kills 16-way LDS conflict storm), 128-edge branch blocks,
// restructured decoder (fewer barriers), parallel hierarchical scan.

#define NN 100000
#define EG 800000
#define EE 262144
#define NB 98  // ceil(NN/1024)

typedef __attribute__((ext_vector_type(8))) short short8;
typedef __attribute__((ext_vector_type(4))) float f32x4;

__device__ __forceinline__ float bf2f(unsigned u16) {
  union { unsigned u; float f; } v; v.u = u16 << 16; return v.f;
}
__device__ __forceinline__ unsigned short f2bf(float f) {
  union { float f; unsigned u; } v; v.f = f;
  return (unsigned short)((v.u + 0x7FFFu + ((v.u >> 16) & 1u)) >> 16);
}
__device__ __forceinline__ unsigned pack2bf(float a, float b) {
  return (unsigned)f2bf(a) | ((unsigned)f2bf(b) << 16);
}

__device__ __forceinline__ float decode_scalar(const void* p) {
  unsigned u = *(const unsigned*)p;
  float f = __uint_as_float(u);
  float af = fabsf(f);
  if (af >= 1e-6f && af <= 1e6f) return f;
  if (u < 1024u) return (float)u;
  return 1.0f;
}

// ---------------- degrees + norms ----------------
__global__ __launch_bounds__(256) void k_deg(const int* __restrict__ src,
                                             const int* __restrict__ dst,
                                             int* __restrict__ degO,
                                             int* __restrict__ degI) {
  for (int i = blockIdx.x * 256 + threadIdx.x; i < EG; i += gridDim.x * 256) {
    atomicAdd(&degO[src[i]], 1);
    atomicAdd(&degI[dst[i]], 1);
  }
}

__global__ __launch_bounds__(256) void k_norm(const int* __restrict__ degO,
                                              const int* __restrict__ degI,
                                              float* __restrict__ normO,
                                              float* __restrict__ normI) {
  int i = blockIdx.x * 256 + threadIdx.x;
  if (i < NN) {
    int dO = degO[i]; if (dO < 1) dO = 1;
    int dI = degI[i]; if (dI < 1) dI = 1;
    normO[i] = rsqrtf((float)dO);
    normI[i] = rsqrtf((float)dI);
  }
}

// ---------------- parallel scan: 3 phases ----------------
__global__ __launch_bounds__(1024) void k_scan1(const int* __restrict__ degI,
                                                int* __restrict__ rowptr,
                                                int* __restrict__ bsum) {
  __shared__ int wsum[16];
  int t = threadIdx.x, lane = t & 63, wv = t >> 6;
  int i = blockIdx.x * 1024 + t;
  int v = (i < NN) ? degI[i] : 0;
  int incl = v;
#pragma unroll
  for (int off = 1; off < 64; off <<= 1) {
    int u = __shfl_up(incl, off);
    if (lane >= off) incl += u;
  }
  if (lane == 63) wsum[wv] = incl;
  __syncthreads();
  if (wv == 0 && lane < 16) {
    int s = wsum[lane];
    int si = s;
#pragma unroll
    for (int off = 1; off < 16; off <<= 1) {
      int u = __shfl_up(si, off);
      if (lane >= off) si += u;
    }
    wsum[lane] = si - s;
    if (lane == 15) bsum[blockIdx.x] = si;
  }
  __syncthreads();
  int excl = wsum[wv] + incl - v;
  if (i < NN) rowptr[i] = excl;
}

__global__ __launch_bounds__(128) void k_scan2(int* __restrict__ bsum) {
  __shared__ int w0tot;
  int t = threadIdx.x, lane = t & 63, wv = t >> 6;
  int v = (t < NB) ? bsum[t] : 0;
  int incl = v;
#pragma unroll
  for (int off = 1; off < 64; off <<= 1) {
    int u = __shfl_up(incl, off);
    if (lane >= off) incl += u;
  }
  if (wv == 0 && lane == 63) w0tot = incl;
  __syncthreads();
  int excl = incl - v + (wv ? w0tot : 0);
  if (t < NB) bsum[t] = excl;
}

__global__ __launch_bounds__(1024) void k_scan3(const int* __restrict__ degI,
                                                int* __restrict__ rowptr,
                                                int* __restrict__ cursor,
                                                const int* __restrict__ bsum) {
  int i = blockIdx.x * 1024 + threadIdx.x;
  if (i < NN) {
    int vv = rowptr[i] + bsum[blockIdx.x];
    rowptr[i] = vv;
    cursor[i] = vv;
    if (i == NN - 1) rowptr[NN] = vv + degI[i];
  }
}

// ---------------- fill CSR buckets ----------------
__global__ __launch_bounds__(256) void k_fill(const int* __restrict__ src,
                                              const int* __restrict__ dst,
                                              int* __restrict__ cursor,
                                              int* __restrict__ csr) {
  for (int e = blockIdx.x * 256 + threadIdx.x; e < EG; e += gridDim.x * 256) {
    int d = dst[e];
    int pos = atomicAdd(&cursor[d], 1);
    csr[pos] = src[e];
  }
}

// ---------------- weight transpose f32[K][N] -> bf16[N][K] ----------------
__global__ __launch_bounds__(256) void k_transpose(const float* __restrict__ in,
                                                   unsigned short* __restrict__ out,
                                                   int K, int Nmask, int logN, int total) {
  for (int idx = blockIdx.x * 256 + threadIdx.x; idx < total; idx += gridDim.x * 256) {
    int n = idx & Nmask;
    int k = idx >> logN;
    out[(size_t)n * K + k] = f2bf(in[idx]);
  }
}

// Wq f32[256][4] -> bf16 [16 pad][256] (rows >=4 zero)
__global__ __launch_bounds__(256) void k_transpose_q(const float* __restrict__ Wq,
                                                     unsigned short* __restrict__ WqT) {
  int idx = blockIdx.x * 256 + threadIdx.x;
  if (idx < 4096) {
    int r = idx >> 8, k = idx & 255;
    WqT[idx] = (r < 4) ? f2bf(Wq[k * 4 + r]) : (unsigned short)0;
  }
}

// ---------------- gather layer 1 ----------------
__global__ __launch_bounds__(256) void k_gather1(
    const float* __restrict__ x, const int* __restrict__ rowptr,
    const int* __restrict__ csr, const float* __restrict__ normO,
    const float* __restrict__ normI, unsigned short* __restrict__ agg) {
  int wid = (blockIdx.x * 256 + threadIdx.x) >> 6;
  int lane = threadIdx.x & 63;
  int half = lane >> 5, fl = lane & 31;
  int nw = (gridDim.x * 256) >> 6;
  for (int n = wid; n < NN; n += nw) {
    int beg = rowptr[n], end = rowptr[n + 1];
    float a0 = 0.f, a1 = 0.f, a2 = 0.f, a3 = 0.f;
    for (int i = beg + half; i < end; i += 2) {
      int s = csr[i];
      float ns = normO[s];
      float4 v = *(const float4*)(x + ((size_t)s << 7) + (fl << 2));
      a0 += ns * v.x; a1 += ns * v.y; a2 += ns * v.z; a3 += ns * v.w;
    }
    a0 += __shfl_xor(a0, 32); a1 += __shfl_xor(a1, 32);
    a2 += __shfl_xor(a2, 32); a3 += __shfl_xor(a3, 32);
    if (lane < 32) {
      float ni = normI[n];
      *(uint2*)(agg + ((size_t)n << 7) + (fl << 2)) =
          make_uint2(pack2bf(a0 * ni, a1 * ni), pack2bf(a2 * ni, a3 * ni));
    }
  }
}

// ---------------- gather layer 2 ----------------
__global__ __launch_bounds__(256) void k_gather2(
    const unsigned short* __restrict__ h1s, const int* __restrict__ rowptr,
    const int* __restrict__ csr, const float* __restrict__ normI,
    unsigned short* __restrict__ agg) {
  int wid = (blockIdx.x * 256 + threadIdx.x) >> 6;
  int lane = threadIdx.x & 63;
  int half = lane >> 5, fl = lane & 31;
  int nw = (gridDim.x * 256) >> 6;
  for (int n = wid; n < NN; n += nw) {
    int beg = rowptr[n], end = rowptr[n + 1];
    float a0 = 0.f, a1 = 0.f, a2 = 0.f, a3 = 0.f, a4 = 0.f, a5 = 0.f, a6 = 0.f, a7 = 0.f;
    for (int i = beg + half; i < end; i += 2) {
      int s = csr[i];
      uint4 v = *(const uint4*)(h1s + ((size_t)s << 8) + (fl << 3));
      a0 += bf2f(v.x & 0xFFFFu); a1 += bf2f(v.x >> 16);
      a2 += bf2f(v.y & 0xFFFFu); a3 += bf2f(v.y >> 16);
      a4 += bf2f(v.z & 0xFFFFu); a5 += bf2f(v.z >> 16);
      a6 += bf2f(v.w & 0xFFFFu); a7 += bf2f(v.w >> 16);
    }
    a0 += __shfl_xor(a0, 32); a1 += __shfl_xor(a1, 32);
    a2 += __shfl_xor(a2, 32); a3 += __shfl_xor(a3, 32);
    a4 += __shfl_xor(a4, 32); a5 += __shfl_xor(a5, 32);
    a6 += __shfl_xor(a6, 32); a7 += __shfl_xor(a7, 32);
    if (lane < 32) {
      float ni = normI[n];
      uint4 o;
      o.x = pack2bf(a0 * ni, a1 * ni);
      o.y = pack2bf(a2 * ni, a3 * ni);
      o.z = pack2bf(a4 * ni, a5 * ni);
      o.w = pack2bf(a6 * ni, a7 * ni);
      *(uint4*)(agg + ((size_t)n << 8) + (fl << 3)) = o;
    }
  }
}

// ---------------- encoder GEMM (unchanged) ----------------
template <int K, bool RELU, bool OSCALE>
__global__ __launch_bounds__(256) void k_gemm(
    const unsigned short* __restrict__ A, const float* __restrict__ oscale,
    const unsigned short* __restrict__ WT, const float* __restrict__ bias,
    unsigned short* __restrict__ C, int M) {
  __shared__ __align__(16) short At[128 * 40];
  __shared__ __align__(16) short Bt[256 * 40];
  const int t = threadIdx.x;
  const int row0 = blockIdx.x * 128;
  const int lane = t & 63, wave = t >> 6;
  const int wr = (wave >> 1) << 6;
  const int wcc = (wave & 1) << 7;
  const int lrow = lane & 15, lhi = lane >> 4;

  f32x4 acc[4][8];
#pragma unroll
  for (int m = 0; m < 4; ++m)
#pragma unroll
    for (int n = 0; n < 8; ++n) acc[m][n] = (f32x4){0.f, 0.f, 0.f, 0.f};

  for (int k0 = 0; k0 < K; k0 += 32) {
    if (k0) __syncthreads();
#pragma unroll
    for (int it = 0; it < 2; ++it) {
      int idx = t + it * 256;
      int r = idx >> 2, c8 = (idx & 3) << 3;
      int grow = row0 + r;
      int4 tv = {0, 0, 0, 0};
      if (grow < M) tv = *(const int4*)(A + (size_t)grow * K + k0 + c8);
      *(int4*)&At[r * 40 + c8] = tv;
    }
    {
      const unsigned short* wt = WT + (size_t)t * K + k0;
      *(int4*)&Bt[t * 40 + 0] = *(const int4*)(wt);
      *(int4*)&Bt[t * 40 + 8] = *(const int4*)(wt + 8);
      *(int4*)&Bt[t * 40 + 16] = *(const int4*)(wt + 16);
      *(int4*)&Bt[t * 40 + 24] = *(const int4*)(wt + 24);
    }
    __syncthreads();
    short8 a[4], b[8];
#pragma unroll
    for (int m = 0; m < 4; ++m)
      a[m] = *(const short8*)&At[(wr + m * 16 + lrow) * 40 + lhi * 8];
#pragma unroll
    for (int n = 0; n < 8; ++n)
      b[n] = *(const short8*)&Bt[(wcc + n * 16 + lrow) * 40 + lhi * 8];
#pragma unroll
    for (int m = 0; m < 4; ++m)
#pragma unroll
      for (int n = 0; n < 8; ++n)
        acc[m][n] = __builtin_amdgcn_mfma_f32_16x16x32_bf16(a[m], b[n], acc[m][n], 0, 0, 0);
  }
#pragma unroll
  for (int n = 0; n < 8; ++n) {
    int col = wcc + n * 16 + lrow;
    float bv = bias[col];
#pragma unroll
    for (int m = 0; m < 4; ++m) {
#pragma unroll
      for (int r = 0; r < 4; ++r) {
        int grow = row0 + wr + m * 16 + lhi * 4 + r;
        if (grow < M) {
          float vv = acc[m][n][r] + bv;
          if (RELU) vv = fmaxf(vv, 0.f);
          if (OSCALE) vv *= oscale[grow];
          C[(size_t)grow * 256 + col] = f2bf(vv);
        }
      }
    }
  }
}

// ---------------- fused branch v2: 128 edges, 512 threads, q via MFMA ----------------
__global__ __launch_bounds__(512, 2) void k_branch2(
    const unsigned short* __restrict__ h, const int* __restrict__ ea,
    const int* __restrict__ eb, const float* __restrict__ gauss,
    const float* __restrict__ unif, const void* __restrict__ temp_p,
    const unsigned short* __restrict__ WmT, const float* __restrict__ bm,
    const unsigned short* __restrict__ WlT, const float* __restrict__ bl,
    const unsigned short* __restrict__ WqT, const float* __restrict__ bq,
    const float* __restrict__ Wc, const float* __restrict__ bc,
    float* __restrict__ o_mean, float* __restrict__ o_ls,
    float* __restrict__ q_o, float* __restrict__ A_o,
    unsigned short* __restrict__ M_o) {
  __shared__ __align__(16) char U[66560];   // staging | Nl bf16 [128][260]
  short* At = (short*)U;                    // [128][40]
  short* Btm = (short*)(U + 10240);         // [256][40]
  short* Btl = (short*)(U + 30720);         // [256][40]
  short* Btq = (short*)(U + 51200);         // [16][40]
  unsigned short* Nl = (unsigned short*)U;
  __shared__ float zS[512];                 // [128][4]
  __shared__ float bmS[256], blS[256];
  __shared__ float WcT[4 * 68];             // transposed+padded Wc
  __shared__ float bqS[4], bcS[4];
  __shared__ int eaS[128], ebS[128];

  const int t = threadIdx.x;
  const int e0 = blockIdx.x << 7;
  const int lane = t & 63;
  const int wv = t >> 6;
  const int lrow = lane & 15, lhi = lane >> 4;
  const int wc = wv << 5;  // this wave's 32-col slice

  if (t < 256) {
    bmS[t] = bm[t]; blS[t] = bl[t];
    WcT[(t & 3) * 68 + (t >> 2)] = Wc[t];
  } else if (t < 384) {
    eaS[t - 256] = ea[e0 + t - 256];
  } else {
    ebS[t - 384] = eb[e0 + t - 384];
  }
  if (t < 4) { bqS[t] = bq[t]; bcS[t] = bc[t]; }
  __syncthreads();

  f32x4 am[8][2], al[8][2], aq;
#pragma unroll
  for (int m = 0; m < 8; ++m)
#pragma unroll
    for (int n = 0; n < 2; ++n) {
      am[m][n] = (f32x4){0.f, 0.f, 0.f, 0.f};
      al[m][n] = (f32x4){0.f, 0.f, 0.f, 0.f};
    }
  aq = (f32x4){0.f, 0.f, 0.f, 0.f};

  const int ar = t >> 2, ac8 = (t & 3) << 3;
  const int br = t & 255, bwhich = t >> 8;

  for (int k0 = 0; k0 < 256; k0 += 32) {
    if (k0) __syncthreads();
    // A: gather h[a]+h[b]
    {
      const unsigned short* pa = h + ((size_t)eaS[ar] << 8) + k0 + ac8;
      const unsigned short* pb = h + ((size_t)ebS[ar] << 8) + k0 + ac8;
      uint4 va = *(const uint4*)pa;
      uint4 vb = *(const uint4*)pb;
      unsigned w0 = pack2bf(bf2f(va.x & 0xFFFFu) + bf2f(vb.x & 0xFFFFu),
                            bf2f(va.x >> 16) + bf2f(vb.x >> 16));
      unsigned w1 = pack2bf(bf2f(va.y & 0xFFFFu) + bf2f(vb.y & 0xFFFFu),
                            bf2f(va.y >> 16) + bf2f(vb.y >> 16));
      unsigned w2 = pack2bf(bf2f(va.z & 0xFFFFu) + bf2f(vb.z & 0xFFFFu),
                            bf2f(va.z >> 16) + bf2f(vb.z >> 16));
      unsigned w3 = pack2bf(bf2f(va.w & 0xFFFFu) + bf2f(vb.w & 0xFFFFu),
                            bf2f(va.w >> 16) + bf2f(vb.w >> 16));
      *(int4*)&At[ar * 40 + ac8] = make_int4((int)w0, (int)w1, (int)w2, (int)w3);
    }
    // B: Btm (t<256) / Btl (t>=256)
    {
      const unsigned short* wsrc = (bwhich ? WlT : WmT) + ((size_t)br << 8) + k0;
      short* bdst = (bwhich ? Btl : Btm) + br * 40;
      *(int4*)&bdst[0] = *(const int4*)(wsrc);
      *(int4*)&bdst[8] = *(const int4*)(wsrc + 8);
      *(int4*)&bdst[16] = *(const int4*)(wsrc + 16);
      *(int4*)&bdst[24] = *(const int4*)(wsrc + 24);
    }
    if (t < 64) {
      int r = t >> 2, c8t = (t & 3) << 3;
      *(int4*)&Btq[r * 40 + c8t] = *(const int4*)(WqT + ((size_t)r << 8) + k0 + c8t);
    }
    __syncthreads();
    short8 a[8], bmf[2], blf[2], bqf;
#pragma unroll
    for (int m = 0; m < 8; ++m)
      a[m] = *(const short8*)&At[(m * 16 + lrow) * 40 + lhi * 8];
#pragma unroll
    for (int n = 0; n < 2; ++n) {
      bmf[n] = *(const short8*)&Btm[(wc + n * 16 + lrow) * 40 + lhi * 8];
      blf[n] = *(const short8*)&Btl[(wc + n * 16 + lrow) * 40 + lhi * 8];
    }
    bqf = *(const short8*)&Btq[lrow * 40 + lhi * 8];
#pragma unroll
    for (int m = 0; m < 8; ++m)
#pragma unroll
      for (int n = 0; n < 2; ++n) {
        am[m][n] = __builtin_amdgcn_mfma_f32_16x16x32_bf16(a[m], bmf[n], am[m][n], 0, 0, 0);
        al[m][n] = __builtin_amdgcn_mfma_f32_16x16x32_bf16(a[m], blf[n], al[m][n], 0, 0, 0);
      }
    aq = __builtin_amdgcn_mfma_f32_16x16x32_bf16(a[wv], bqf, aq, 0, 0, 0);
  }
  __syncthreads();  // staging dead -> Nl aliases

  // mean / logstd / Nl
#pragma unroll
  for (int n = 0; n < 2; ++n) {
    int col = wc + n * 16 + lrow;
    float bmv = bmS[col], blv = blS[col];
#pragma unroll
    for (int m = 0; m < 8; ++m) {
#pragma unroll
      for (int r = 0; r < 4; ++r) {
        int row = m * 16 + lhi * 4 + r;
        size_t gi = (((size_t)(e0 + row)) << 8) + col;
        float mv = am[m][n][r] + bmv;
        float lv = al[m][n][r] + blv;
        o_mean[gi] = mv;
        o_ls[gi] = lv;
        Nl[row * 260 + col] = f2bf(gauss[gi] * __expf(lv) + mv);
      }
    }
  }

  // q + Z (acc_q: col=lane&15 -> cat, row = wv*16 + lhi*4 + r)
  float invt = 1.0f / decode_scalar(temp_p);
  float qb = bqS[(lrow < 4) ? lrow : 0];
#pragma unroll
  for (int r = 0; r < 4; ++r) {
    int el = (wv << 4) + lhi * 4 + r;
    float q = aq[r] + qb;
    float uu = 0.5f;
    if (lrow < 4) {
      q_o[(((size_t)(e0 + el)) << 2) + lrow] = q;
      uu = unif[(((size_t)(e0 + el)) << 2) + lrow];
    }
    float g = -__logf(-__logf(uu + 1e-7f) + 1e-7f);
    float z = (q + g) * invt;
    float mx = fmaxf(z, __shfl_xor(z, 1));
    mx = fmaxf(mx, __shfl_xor(mx, 2));
    float ez = __expf(z - mx);
    float sz = ez + __shfl_xor(ez, 1);
    sz += __shfl_xor(sz, 2);
    if (lrow < 4) zS[el * 4 + lrow] = ez / sz;
  }
  __syncthreads();

  // M: wave -> 16 edges, lane = d; write M_o and stash M into Nl row head
#pragma unroll 1
  for (int el = 0; el < 16; ++el) {
    int e = (wv << 4) + el;
    float z0 = zS[e * 4 + 0], z1 = zS[e * 4 + 1], z2 = zS[e * 4 + 2], z3 = zS[e * 4 + 3];
    int base = e * 260;
    float mval = z0 * bf2f(Nl[base + lane]) + z1 * bf2f(Nl[base + 64 + lane]) +
                 z2 * bf2f(Nl[base + 128 + lane]) + z3 * bf2f(Nl[base + 192 + lane]);
    M_o[(((size_t)(e0 + e)) << 6) + lane] = f2bf(mval);
    Nl[base + lane] = f2bf(mval);
  }
  __syncthreads();

  // A: thread = (edge, cat); WcT transposed layout -> broadcast-free LDS
  {
    int e = t >> 2, cat = t & 3;
    const unsigned short* ms = &Nl[e * 260];
    const float* wct = &WcT[cat * 68];
    float s = 0.f;
#pragma unroll
    for (int d = 0; d < 64; ++d) s += bf2f(ms[d]) * wct[d];
    s += bcS[cat];
    float smx = fmaxf(s, __shfl_xor(s, 1));
    smx = fmaxf(smx, __shfl_xor(smx, 2));
    float es = __expf(s - smx);
    float ssum = es + __shfl_xor(es, 1);
    ssum += __shfl_xor(ssum, 2);
    A_o[(((size_t)(e0 + e)) << 2) + cat] = es / ssum;
  }
}

// ---------------- fused decoder v2: 128 edges, 512 threads ----------------
__global__ __launch_bounds__(512, 2) void k_dec2(
    const unsigned short* __restrict__ Mw, const unsigned short* __restrict__ Wd1T,
    const float* __restrict__ bd1, const unsigned short* __restrict__ WdXT,
    const float* __restrict__ bdX, float* __restrict__ Xo) {
  __shared__ __align__(16) char R[55296];  // Mt[128][72]+Bt1[256][72] | Bt2[128][72]
  short* Mt = (short*)R;
  short* Bt1 = (short*)(R + 18432);
  short* Bt2 = (short*)R;
  __shared__ __align__(16) short X1[128 * 264];
  const int t = threadIdx.x, lane = t & 63, wv = t >> 6;
  const int lrow = lane & 15, lhi = lane >> 4;
  const int e0 = blockIdx.x << 7;
  const int wr = (wv >> 2) << 6;

  // ---- stage 1: X1 = relu(M @ Wd1 + bd1), K=64 single shot ----
  {
    const int wc1 = (wv & 3) << 6;
    {
      int r = t >> 2, c8 = (t & 3) << 4;
      const unsigned short* mp = Mw + (((size_t)(e0 + r)) << 6) + c8;
      *(int4*)&Mt[r * 72 + c8] = *(const int4*)(mp);
      *(int4*)&Mt[r * 72 + c8 + 8] = *(const int4*)(mp + 8);
    }
    {
      int r1 = t >> 1, base = (t & 1) << 5;
      const unsigned short* wp = Wd1T + ((size_t)r1 << 6) + base;
#pragma unroll
      for (int j = 0; j < 4; ++j)
        *(int4*)&Bt1[r1 * 72 + base + j * 8] = *(const int4*)(wp + j * 8);
    }
    __syncthreads();
    f32x4 acc1[4][4];
#pragma unroll
    for (int m = 0; m < 4; ++m)
#pragma unroll
      for (int n = 0; n < 4; ++n) acc1[m][n] = (f32x4){0.f, 0.f, 0.f, 0.f};
    short8 a0[4], a1[4], b0[4], b1[4];
#pragma unroll
    for (int m = 0; m < 4; ++m) {
      a0[m] = *(const short8*)&Mt[(wr + m * 16 + lrow) * 72 + lhi * 8];
      a1[m] = *(const short8*)&Mt[(wr + m * 16 + lrow) * 72 + 32 + lhi * 8];
    }
#pragma unroll
    for (int n = 0; n < 4; ++n) {
      b0[n] = *(const short8*)&Bt1[(wc1 + n * 16 + lrow) * 72 + lhi * 8];
      b1[n] = *(const short8*)&Bt1[(wc1 + n * 16 + lrow) * 72 + 32 + lhi * 8];
    }
#pragma unroll
    for (int m = 0; m < 4; ++m)
#pragma unroll
      for (int n = 0; n < 4; ++n) {
        acc1[m][n] = __builtin_amdgcn_mfma_f32_16x16x32_bf16(a0[m], b0[n], acc1[m][n], 0, 0, 0);
        acc1[m][n] = __builtin_amdgcn_mfma_f32_16x16x32_bf16(a1[m], b1[n], acc1[m][n], 0, 0, 0);
      }
#pragma unroll
    for (int n = 0; n < 4; ++n) {
      int col = wc1 + n * 16 + lrow;
      float bv = bd1[col];
#pragma unroll
      for (int m = 0; m < 4; ++m)
#pragma unroll
        for (int r = 0; r < 4; ++r) {
          int row = wr + m * 16 + lhi * 4 + r;
          X1[row * 264 + col] = (short)f2bf(fmaxf(acc1[m][n][r] + bv, 0.f));
        }
    }
  }
  __syncthreads();

  // ---- stage 2: X = relu(X1 @ WdX + bdX), K=256 in 4 chunks of 64 ----
  f32x4 acc2[4][2];
#pragma unroll
  for (int m = 0; m < 4; ++m)
#pragma unroll
    for (int n = 0; n < 2; ++n) acc2[m][n] = (f32x4){0.f, 0.f, 0.f, 0.f};
  const int wc2 = (wv & 3) << 5;
  for (int k0 = 0; k0 < 256; k0 += 64) {
    if (k0) __syncthreads();
    {
      int r = t >> 2, c8 = (t & 3) << 4;
      const unsigned short* wp = WdXT + ((size_t)r << 8) + k0 + c8;
      *(int4*)&Bt2[r * 72 + c8] = *(const int4*)(wp);
      *(int4*)&Bt2[r * 72 + c8 + 8] = *(const int4*)(wp + 8);
    }
    __syncthreads();
    short8 a0[4], a1[4], b0[2], b1[2];
#pragma unroll
    for (int m = 0; m < 4; ++m) {
      a0[m] = *(const short8*)&X1[(wr + m * 16 + lrow) * 264 + k0 + lhi * 8];
      a1[m] = *(const short8*)&X1[(wr + m * 16 + lrow) * 264 + k0 + 32 + lhi * 8];
    }
#pragma unroll
    for (int n = 0; n < 2; ++n) {
      b0[n] = *(const short8*)&Bt2[(wc2 + n * 16 + lrow) * 72 + lhi * 8];
      b1[n] = *(const short8*)&Bt2[(wc2 + n * 16 + lrow) * 72 + 32 + lhi * 8];
    }
#pragma unroll
    for (int m = 0; m < 4; ++m)
#pragma unroll
      for (int n = 0; n < 2; ++n) {
        acc2[m][n] = __builtin_amdgcn_mfma_f32_16x16x32_bf16(a0[m], b0[n], acc2[m][n], 0, 0, 0);
        acc2[m][n] = __builtin_amdgcn_mfma_f32_16x16x32_bf16(a1[m], b1[n], acc2[m][n], 0, 0, 0);
      }
  }
#pragma unroll
  for (int n = 0; n < 2; ++n) {
    int col = wc2 + n * 16 + lrow;
    float bv = bdX[col];
#pragma unroll
    for (int m = 0; m < 4; ++m)
#pragma unroll
      for (int r = 0; r < 4; ++r) {
        int row = wr + m * 16 + lhi * 4 + r;
        Xo[(((size_t)(e0 + row)) << 7) + col] = fmaxf(acc2[m][n][r] + bv, 0.f);
      }
  }
}

extern "C" void kernel_launch(void* const* d_in, const int* in_sizes, int n_in,
                              void* d_out, int out_size, void* d_ws, size_t ws_size,
                              hipStream_t stream) {
  const float* x = (const float*)d_in[0];
  const int* src = (const int*)d_in[1];
  const int* dst = (const int*)d_in[2];
  const int* pos_src = (const int*)d_in[3];
  const int* pos_dst = (const int*)d_in[4];
  const int* neg_src = (const int*)d_in[5];
  const int* neg_dst = (const int*)d_in[6];
  const float* gauss_pos = (const float*)d_in[7];
  const float* gauss_neg = (const float*)d_in[8];
  const float* unif_pos = (const float*)d_in[9];
  const float* unif_neg = (const float*)d_in[10];
  const void* temp_p = d_in[11];
  const float* W1 = (const float*)d_in[12];
  const float* b1 = (const float*)d_in[13];
  const float* W2 = (const float*)d_in[14];
  const float* b2 = (const float*)d_in[15];
  const float* Wm = (const float*)d_in[16];
  const float* bm = (const float*)d_in[17];
  const float* Wl = (const float*)d_in[18];
  const float* bl = (const float*)d_in[19];
  const float* Wq = (const float*)d_in[20];
  const float* bq = (const float*)d_in[21];
  const float* Wd1 = (const float*)d_in[22];
  const float* bd1 = (const float*)d_in[23];
  const float* WdX = (const float*)d_in[24];
  const float* bdX = (const float*)d_in[25];
  const float* Wc = (const float*)d_in[26];
  const float* bc = (const float*)d_in[27];

  char* w = (char*)d_ws;
  int* degO = (int*)w;
  int* degI = (int*)(w + 401408);
  int* rowptr = (int*)(w + 802816);
  int* cursor = (int*)(w + 1204224);
  float* normO = (float*)(w + 1605632);
  float* normI = (float*)(w + 2007040);
  int* csr = (int*)(w + 2408448);
  unsigned short* W1T = (unsigned short*)(w + 5609472);
  unsigned short* W2T = (unsigned short*)(w + 5675008);
  unsigned short* WmT = (unsigned short*)(w + 5806080);
  unsigned short* WlT = (unsigned short*)(w + 5937152);
  unsigned short* Wd1T = (unsigned short*)(w + 6068224);
  unsigned short* WdXT = (unsigned short*)(w + 6100992);
  unsigned short* WqT = (unsigned short*)(w + 6166528);
  int* bsum = (int*)(w + 6174720);
  unsigned short* agg1 = (unsigned short*)(w + 6175232);
  unsigned short* h1s = (unsigned short*)(w + 31775232);
  unsigned short* agg2 = (unsigned short*)(w + 82975232);
  unsigned short* h = (unsigned short*)(w + 134175232);
  unsigned short* Mws = (unsigned short*)(w + 185375232);
  // end ~218.9 MB

  float* out = (float*)d_out;
  float* posA = out;
  float* negA = out + 1048576ull;
  float* posX = out + 2097152ull;
  float* negX = out + 35651584ull;
  float* pos_mean = out + 69206016ull;
  float* neg_mean = out + 136314880ull;
  float* pos_logstd = out + 203423744ull;
  float* neg_logstd = out + 270532608ull;
  float* posq = out + 337641472ull;
  float* negq = out + 338690048ull;

  hipMemsetAsync(d_ws, 0, 802816, stream);

  k_deg<<<1024, 256, 0, stream>>>(src, dst, degO, degI);
  k_norm<<<392, 256, 0, stream>>>(degO, degI, normO, normI);
  k_scan1<<<NB, 1024, 0, stream>>>(degI, rowptr, bsum);
  k_scan2<<<1, 128, 0, stream>>>(bsum);
  k_scan3<<<NB, 1024, 0, stream>>>(degI, rowptr, cursor, bsum);
  k_fill<<<1024, 256, 0, stream>>>(src, dst, cursor, csr);

  k_transpose<<<128, 256, 0, stream>>>(W1, W1T, 128, 255, 8, 32768);
  k_transpose<<<256, 256, 0, stream>>>(W2, W2T, 256, 255, 8, 65536);
  k_transpose<<<256, 256, 0, stream>>>(Wm, WmT, 256, 255, 8, 65536);
  k_transpose<<<256, 256, 0, stream>>>(Wl, WlT, 256, 255, 8, 65536);
  k_transpose<<<64, 256, 0, stream>>>(Wd1, Wd1T, 64, 255, 8, 16384);
  k_transpose<<<128, 256, 0, stream>>>(WdX, WdXT, 256, 127, 7, 32768);
  k_transpose_q<<<16, 256, 0, stream>>>(Wq, WqT);

  k_gather1<<<2048, 256, 0, stream>>>(x, rowptr, csr, normO, normI, agg1);
  k_gemm<128, true, true><<<782, 256, 0, stream>>>(agg1, normO, W1T, b1, h1s, NN);
  k_gather2<<<2048, 256, 0, stream>>>(h1s, rowptr, csr, normI, agg2);
  k_gemm<256, false, false><<<782, 256, 0, stream>>>(agg2, nullptr, W2T, b2, h, NN);

  for (int b = 0; b < 2; ++b) {
    const int* es = b ? neg_src : pos_src;
    const int* ed = b ? neg_dst : pos_dst;
    const float* gs = b ? gauss_neg : gauss_pos;
    const float* uf = b ? unif_neg : unif_pos;
    float* o_mean = b ? neg_mean : pos_mean;
    float* o_ls = b ? neg_logstd : pos_logstd;
    float* o_q = b ? negq : posq;
    float* o_A = b ? negA : posA;
    float* o_X = b ? negX : posX;

    k_branch2<<<2048, 512, 0, stream>>>(h, es, ed, gs, uf, temp_p,
                                        WmT, bm, WlT, bl, WqT, bq, Wc, bc,
                                        o_mean, o_ls, o_q, o_A, Mws);
    k_dec2<<<2048, 512, 0, stream>>>(Mws, Wd1T, bd1, WdXT, bdX, o_X);
  }
}

// Round 6
// 1574.625 us; speedup vs baseline: 3.6135x; 1.1846x over previous
//
#include <hip/hip_runtime.h>
#include <hip/hip_bf16.h>

// Round 6: column-pair permutation in all GEMM B-staging (float2/u32 packed I/O),
// M via LDS f32 atomics (no Nl buffer), swizzled stride-32 staging (3 blocks/CU),
// no runtime-indexed register arrays, 64-edge decoder blocks.

#define NN 100000
#define EG 800000
#define EE 262144
#define NB 98

typedef __attribute__((ext_vector_type(8))) short short8;
typedef __attribute__((ext_vector_type(4))) float f32x4;

__device__ __forceinline__ float bf2f(unsigned u16) {
  union { unsigned u; float f; } v; v.u = u16 << 16; return v.f;
}
__device__ __forceinline__ float lo2f(unsigned u) {
  union { unsigned u; float f; } v; v.u = u << 16; return v.f;
}
__device__ __forceinline__ float hi2f(unsigned u) {
  union { unsigned u; float f; } v; v.u = u & 0xFFFF0000u; return v.f;
}
__device__ __forceinline__ unsigned short f2bf(float f) {
  union { float f; unsigned u; } v; v.f = f;
  return (unsigned short)((v.u + 0x7FFFu + ((v.u >> 16) & 1u)) >> 16);
}
__device__ __forceinline__ unsigned pack2bf(float a, float b) {
  return (unsigned)f2bf(a) | ((unsigned)f2bf(b) << 16);
}
__device__ __forceinline__ int permc(int c) {
  return (c & ~31) | ((c & 15) << 1) | ((c >> 4) & 1);
}

__device__ __forceinline__ float decode_scalar(const void* p) {
  unsigned u = *(const unsigned*)p;
  float f = __uint_as_float(u);
  float af = fabsf(f);
  if (af >= 1e-6f && af <= 1e6f) return f;
  if (u < 1024u) return (float)u;
  return 1.0f;
}

// ---------------- degrees + norms ----------------
__global__ __launch_bounds__(256) void k_deg(const int* __restrict__ src,
                                             const int* __restrict__ dst,
                                             int* __restrict__ degO,
                                             int* __restrict__ degI) {
  for (int i = blockIdx.x * 256 + threadIdx.x; i < EG; i += gridDim.x * 256) {
    atomicAdd(&degO[src[i]], 1);
    atomicAdd(&degI[dst[i]], 1);
  }
}

__global__ __launch_bounds__(256) void k_norm(const int* __restrict__ degO,
                                              const int* __restrict__ degI,
                                              float* __restrict__ normO,
                                              float* __restrict__ normI) {
  int i = blockIdx.x * 256 + threadIdx.x;
  if (i < NN) {
    int dO = degO[i]; if (dO < 1) dO = 1;
    int dI = degI[i]; if (dI < 1) dI = 1;
    normO[i] = rsqrtf((float)dO);
    normI[i] = rsqrtf((float)dI);
  }
}

// ---------------- parallel scan ----------------
__global__ __launch_bounds__(1024) void k_scan1(const int* __restrict__ degI,
                                                int* __restrict__ rowptr,
                                                int* __restrict__ bsum) {
  __shared__ int wsum[16];
  int t = threadIdx.x, lane = t & 63, wv = t >> 6;
  int i = blockIdx.x * 1024 + t;
  int v = (i < NN) ? degI[i] : 0;
  int incl = v;
#pragma unroll
  for (int off = 1; off < 64; off <<= 1) {
    int u = __shfl_up(incl, off);
    if (lane >= off) incl += u;
  }
  if (lane == 63) wsum[wv] = incl;
  __syncthreads();
  if (wv == 0 && lane < 16) {
    int s = wsum[lane];
    int si = s;
#pragma unroll
    for (int off = 1; off < 16; off <<= 1) {
      int u = __shfl_up(si, off);
      if (lane >= off) si += u;
    }
    wsum[lane] = si - s;
    if (lane == 15) bsum[blockIdx.x] = si;
  }
  __syncthreads();
  int excl = wsum[wv] + incl - v;
  if (i < NN) rowptr[i] = excl;
}

__global__ __launch_bounds__(128) void k_scan2(int* __restrict__ bsum) {
  __shared__ int w0tot;
  int t = threadIdx.x, lane = t & 63, wv = t >> 6;
  int v = (t < NB) ? bsum[t] : 0;
  int incl = v;
#pragma unroll
  for (int off = 1; off < 64; off <<= 1) {
    int u = __shfl_up(incl, off);
    if (lane >= off) incl += u;
  }
  if (wv == 0 && lane == 63) w0tot = incl;
  __syncthreads();
  int excl = incl - v + (wv ? w0tot : 0);
  if (t < NB) bsum[t] = excl;
}

__global__ __launch_bounds__(1024) void k_scan3(const int* __restrict__ degI,
                                                int* __restrict__ rowptr,
                                                int* __restrict__ cursor,
                                                const int* __restrict__ bsum) {
  int i = blockIdx.x * 1024 + threadIdx.x;
  if (i < NN) {
    int vv = rowptr[i] + bsum[blockIdx.x];
    rowptr[i] = vv;
    cursor[i] = vv;
    if (i == NN - 1) rowptr[NN] = vv + degI[i];
  }
}

__global__ __launch_bounds__(256) void k_fill(const int* __restrict__ src,
                                              const int* __restrict__ dst,
                                              int* __restrict__ cursor,
                                              int* __restrict__ csr) {
  for (int e = blockIdx.x * 256 + threadIdx.x; e < EG; e += gridDim.x * 256) {
    int d = dst[e];
    int pos = atomicAdd(&cursor[d], 1);
    csr[pos] = src[e];
  }
}

// ---------------- weight transpose f32[K][N] -> bf16[N][K] ----------------
__global__ __launch_bounds__(256) void k_transpose(const float* __restrict__ in,
                                                   unsigned short* __restrict__ out,
                                                   int K, int Nmask, int logN, int total) {
  for (int idx = blockIdx.x * 256 + threadIdx.x; idx < total; idx += gridDim.x * 256) {
    int n = idx & Nmask;
    int k = idx >> logN;
    out[(size_t)n * K + k] = f2bf(in[idx]);
  }
}

__global__ __launch_bounds__(256) void k_transpose_q(const float* __restrict__ Wq,
                                                     unsigned short* __restrict__ WqT) {
  int idx = blockIdx.x * 256 + threadIdx.x;
  if (idx < 4096) {
    int r = idx >> 8, k = idx & 255;
    WqT[idx] = (r < 4) ? f2bf(Wq[k * 4 + r]) : (unsigned short)0;
  }
}

// ---------------- gather layer 1 ----------------
__global__ __launch_bounds__(256) void k_gather1(
    const float* __restrict__ x, const int* __restrict__ rowptr,
    const int* __restrict__ csr, const float* __restrict__ normO,
    const float* __restrict__ normI, unsigned short* __restrict__ agg) {
  int wid = (blockIdx.x * 256 + threadIdx.x) >> 6;
  int lane = threadIdx.x & 63;
  int half = lane >> 5, fl = lane & 31;
  int nw = (gridDim.x * 256) >> 6;
  for (int n = wid; n < NN; n += nw) {
    int beg = rowptr[n], end = rowptr[n + 1];
    float a0 = 0.f, a1 = 0.f, a2 = 0.f, a3 = 0.f;
    for (int i = beg + half; i < end; i += 2) {
      int s = csr[i];
      float ns = normO[s];
      float4 v = *(const float4*)(x + ((size_t)s << 7) + (fl << 2));
      a0 += ns * v.x; a1 += ns * v.y; a2 += ns * v.z; a3 += ns * v.w;
    }
    a0 += __shfl_xor(a0, 32); a1 += __shfl_xor(a1, 32);
    a2 += __shfl_xor(a2, 32); a3 += __shfl_xor(a3, 32);
    if (lane < 32) {
      float ni = normI[n];
      *(uint2*)(agg + ((size_t)n << 7) + (fl << 2)) =
          make_uint2(pack2bf(a0 * ni, a1 * ni), pack2bf(a2 * ni, a3 * ni));
    }
  }
}

// ---------------- gather layer 2 ----------------
__global__ __launch_bounds__(256) void k_gather2(
    const unsigned short* __restrict__ h1s, const int* __restrict__ rowptr,
    const int* __restrict__ csr, const float* __restrict__ normI,
    unsigned short* __restrict__ agg) {
  int wid = (blockIdx.x * 256 + threadIdx.x) >> 6;
  int lane = threadIdx.x & 63;
  int half = lane >> 5, fl = lane & 31;
  int nw = (gridDim.x * 256) >> 6;
  for (int n = wid; n < NN; n += nw) {
    int beg = rowptr[n], end = rowptr[n + 1];
    float a0 = 0.f, a1 = 0.f, a2 = 0.f, a3 = 0.f, a4 = 0.f, a5 = 0.f, a6 = 0.f, a7 = 0.f;
    for (int i = beg + half; i < end; i += 2) {
      int s = csr[i];
      uint4 v = *(const uint4*)(h1s + ((size_t)s << 8) + (fl << 3));
      a0 += lo2f(v.x); a1 += hi2f(v.x);
      a2 += lo2f(v.y); a3 += hi2f(v.y);
      a4 += lo2f(v.z); a5 += hi2f(v.z);
      a6 += lo2f(v.w); a7 += hi2f(v.w);
    }
    a0 += __shfl_xor(a0, 32); a1 += __shfl_xor(a1, 32);
    a2 += __shfl_xor(a2, 32); a3 += __shfl_xor(a3, 32);
    a4 += __shfl_xor(a4, 32); a5 += __shfl_xor(a5, 32);
    a6 += __shfl_xor(a6, 32); a7 += __shfl_xor(a7, 32);
    if (lane < 32) {
      float ni = normI[n];
      uint4 o;
      o.x = pack2bf(a0 * ni, a1 * ni);
      o.y = pack2bf(a2 * ni, a3 * ni);
      o.z = pack2bf(a4 * ni, a5 * ni);
      o.w = pack2bf(a6 * ni, a7 * ni);
      *(uint4*)(agg + ((size_t)n << 8) + (fl << 3)) = o;
    }
  }
}

// ---------------- encoder GEMM: perm'd B + packed u32 C stores ----------------
template <int K, bool RELU, bool OSCALE>
__global__ __launch_bounds__(256) void k_gemm(
    const unsigned short* __restrict__ A, const float* __restrict__ oscale,
    const unsigned short* __restrict__ WT, const float* __restrict__ bias,
    unsigned short* __restrict__ C, int M) {
  __shared__ __align__(16) short At[128 * 40];
  __shared__ __align__(16) short Bt[256 * 40];
  const int t = threadIdx.x;
  const int row0 = blockIdx.x * 128;
  const int lane = t & 63, wave = t >> 6;
  const int wr = (wave >> 1) << 6;
  const int wcc = (wave & 1) << 7;
  const int lrow = lane & 15, lhi = lane >> 4;

  f32x4 acc[4][8];
#pragma unroll
  for (int m = 0; m < 4; ++m)
#pragma unroll
    for (int n = 0; n < 8; ++n) acc[m][n] = (f32x4){0.f, 0.f, 0.f, 0.f};

  for (int k0 = 0; k0 < K; k0 += 32) {
    if (k0) __syncthreads();
#pragma unroll
    for (int it = 0; it < 2; ++it) {
      int idx = t + it * 256;
      int r = idx >> 2, c8 = (idx & 3) << 3;
      int grow = row0 + r;
      int4 tv = {0, 0, 0, 0};
      if (grow < M) tv = *(const int4*)(A + (size_t)grow * K + k0 + c8);
      *(int4*)&At[r * 40 + c8] = tv;
    }
    {
      const unsigned short* wt = WT + (size_t)permc(t) * K + k0;
      *(int4*)&Bt[t * 40 + 0] = *(const int4*)(wt);
      *(int4*)&Bt[t * 40 + 8] = *(const int4*)(wt + 8);
      *(int4*)&Bt[t * 40 + 16] = *(const int4*)(wt + 16);
      *(int4*)&Bt[t * 40 + 24] = *(const int4*)(wt + 24);
    }
    __syncthreads();
    short8 a[4], b[8];
#pragma unroll
    for (int m = 0; m < 4; ++m)
      a[m] = *(const short8*)&At[(wr + m * 16 + lrow) * 40 + lhi * 8];
#pragma unroll
    for (int n = 0; n < 8; ++n)
      b[n] = *(const short8*)&Bt[(wcc + n * 16 + lrow) * 40 + lhi * 8];
#pragma unroll
    for (int m = 0; m < 4; ++m)
#pragma unroll
      for (int n = 0; n < 8; ++n)
        acc[m][n] = __builtin_amdgcn_mfma_f32_16x16x32_bf16(a[m], b[n], acc[m][n], 0, 0, 0);
  }
#pragma unroll
  for (int np = 0; np < 4; ++np) {
    int tc = wcc + np * 32 + (lrow << 1);
    float bv0 = bias[tc], bv1 = bias[tc + 1];
#pragma unroll
    for (int m = 0; m < 4; ++m) {
#pragma unroll
      for (int r = 0; r < 4; ++r) {
        int grow = row0 + wr + m * 16 + lhi * 4 + r;
        if (grow < M) {
          float v0 = acc[m][2 * np][r] + bv0;
          float v1 = acc[m][2 * np + 1][r] + bv1;
          if (RELU) { v0 = fmaxf(v0, 0.f); v1 = fmaxf(v1, 0.f); }
          if (OSCALE) { float s = oscale[grow]; v0 *= s; v1 *= s; }
          *(unsigned*)&C[(size_t)grow * 256 + tc] = pack2bf(v0, v1);
        }
      }
    }
  }
}

// ---------------- fused branch v3 ----------------
__global__ __launch_bounds__(512) void k_branch2(
    const unsigned short* __restrict__ h, const int* __restrict__ ea,
    const int* __restrict__ eb, const float* __restrict__ gauss,
    const float* __restrict__ unif, const void* __restrict__ temp_p,
    const unsigned short* __restrict__ WmT, const float* __restrict__ bm,
    const unsigned short* __restrict__ WlT, const float* __restrict__ bl,
    const unsigned short* __restrict__ WqT, const float* __restrict__ bq,
    const float* __restrict__ Wc, const float* __restrict__ bc,
    float* __restrict__ o_mean, float* __restrict__ o_ls,
    float* __restrict__ q_o, float* __restrict__ A_o,
    unsigned* __restrict__ M_o32) {
  __shared__ __align__(16) char U[41984];  // staging | Mf f32[128][66]
  short* At = (short*)U;                   // [128][32] slot-swizzled
  short* Btm = (short*)(U + 8192);         // [256][32]
  short* Btl = (short*)(U + 24576);        // [256][32]
  short* Btq = (short*)(U + 40960);        // [16][32]
  float* Mf = (float*)U;                   // [128][66] (33792 B)
  __shared__ float zS[512];
  __shared__ float WcT[4 * 68];
  __shared__ float bmS[256], blS[256];
  __shared__ int eaS[128], ebS[128];

  const int t = threadIdx.x;
  const int e0 = blockIdx.x << 7;
  const int lane = t & 63;
  const int wv = t >> 6;
  const int lrow = lane & 15, lhi = lane >> 4;
  const int wc = wv << 5;

  if (t < 256) {
    bmS[t] = bm[t]; blS[t] = bl[t];
    WcT[(t & 3) * 68 + (t >> 2)] = Wc[t];
  } else if (t < 384) {
    eaS[t - 256] = ea[e0 + t - 256];
  } else {
    ebS[t - 384] = eb[e0 + t - 384];
  }
  __syncthreads();

  f32x4 am[8][2], al[8][2], aq;
#pragma unroll
  for (int m = 0; m < 8; ++m)
#pragma unroll
    for (int n = 0; n < 2; ++n) {
      am[m][n] = (f32x4){0.f, 0.f, 0.f, 0.f};
      al[m][n] = (f32x4){0.f, 0.f, 0.f, 0.f};
    }
  aq = (f32x4){0.f, 0.f, 0.f, 0.f};

  const int ar = t >> 2, as_ = t & 3;
  const int arsw = ((as_ ^ (ar & 3)) << 3);
  const int br = t & 255, bw = t >> 8;
  const int fsw = (lrow & 3);

  for (int k0 = 0; k0 < 256; k0 += 32) {
    if (k0) __syncthreads();
    // A: gather h[a]+h[b] into swizzled slot
    {
      const unsigned short* pa = h + ((size_t)eaS[ar] << 8) + k0 + (as_ << 3);
      const unsigned short* pb = h + ((size_t)ebS[ar] << 8) + k0 + (as_ << 3);
      uint4 va = *(const uint4*)pa;
      uint4 vb = *(const uint4*)pb;
      unsigned w0 = pack2bf(lo2f(va.x) + lo2f(vb.x), hi2f(va.x) + hi2f(vb.x));
      unsigned w1 = pack2bf(lo2f(va.y) + lo2f(vb.y), hi2f(va.y) + hi2f(vb.y));
      unsigned w2 = pack2bf(lo2f(va.z) + lo2f(vb.z), hi2f(va.z) + hi2f(vb.z));
      unsigned w3 = pack2bf(lo2f(va.w) + lo2f(vb.w), hi2f(va.w) + hi2f(vb.w));
      *(int4*)&At[ar * 32 + arsw] = make_int4((int)w0, (int)w1, (int)w2, (int)w3);
    }
    // B: perm'd staging, slot-swizzled
    {
      const unsigned short* wsrc = (bw ? WlT : WmT) + ((size_t)permc(br) << 8) + k0;
      short* bb = (bw ? Btl : Btm) + br * 32;
      int rs = br & 3;
      *(int4*)&bb[((0 ^ rs) << 3)] = *(const int4*)(wsrc);
      *(int4*)&bb[((1 ^ rs) << 3)] = *(const int4*)(wsrc + 8);
      *(int4*)&bb[((2 ^ rs) << 3)] = *(const int4*)(wsrc + 16);
      *(int4*)&bb[((3 ^ rs) << 3)] = *(const int4*)(wsrc + 24);
    }
    if (t < 64) {
      int r = t >> 2, s = t & 3;
      *(int4*)&Btq[r * 32 + ((s ^ (r & 3)) << 3)] =
          *(const int4*)(WqT + ((size_t)r << 8) + k0 + (s << 3));
    }
    __syncthreads();
    short8 a[8], bmf[2], blf[2], bqf, aqa;
#pragma unroll
    for (int m = 0; m < 8; ++m)
      a[m] = *(const short8*)&At[(m * 16 + lrow) * 32 + ((lhi ^ fsw) << 3)];
#pragma unroll
    for (int n = 0; n < 2; ++n) {
      bmf[n] = *(const short8*)&Btm[(wc + n * 16 + lrow) * 32 + ((lhi ^ fsw) << 3)];
      blf[n] = *(const short8*)&Btl[(wc + n * 16 + lrow) * 32 + ((lhi ^ fsw) << 3)];
    }
    bqf = *(const short8*)&Btq[lrow * 32 + ((lhi ^ fsw) << 3)];
    aqa = *(const short8*)&At[((wv << 4) + lrow) * 32 + ((lhi ^ fsw) << 3)];
#pragma unroll
    for (int m = 0; m < 8; ++m)
#pragma unroll
      for (int n = 0; n < 2; ++n) {
        am[m][n] = __builtin_amdgcn_mfma_f32_16x16x32_bf16(a[m], bmf[n], am[m][n], 0, 0, 0);
        al[m][n] = __builtin_amdgcn_mfma_f32_16x16x32_bf16(a[m], blf[n], al[m][n], 0, 0, 0);
      }
    aq = __builtin_amdgcn_mfma_f32_16x16x32_bf16(aqa, bqf, aq, 0, 0, 0);
  }
  __syncthreads();

  // Z phase + zero Mf (staging now dead)
  float invt = 1.0f / decode_scalar(temp_p);
  float qb = (lrow < 4) ? bq[lrow] : 0.f;
#pragma unroll
  for (int r = 0; r < 4; ++r) {
    int el = (wv << 4) + lhi * 4 + r;
    float q = aq[r] + qb;
    float uu = 0.5f;
    if (lrow < 4) {
      q_o[(((size_t)(e0 + el)) << 2) + lrow] = q;
      uu = unif[(((size_t)(e0 + el)) << 2) + lrow];
    }
    float g = -__logf(-__logf(uu + 1e-7f) + 1e-7f);
    float z = (q + g) * invt;
    float mx = fmaxf(z, __shfl_xor(z, 1));
    mx = fmaxf(mx, __shfl_xor(mx, 2));
    float ez = __expf(z - mx);
    float sz = ez + __shfl_xor(ez, 1);
    sz += __shfl_xor(sz, 2);
    if (lrow < 4) zS[el * 4 + lrow] = ez / sz;
  }
  for (int i = t; i < 128 * 66; i += 512) Mf[i] = 0.f;
  __syncthreads();

  // mean/ls epilogue: float2 stores, f32 LDS atomic M accumulation
  const int cidx = wv >> 1;
  const int dd = ((wv & 1) << 5) + (lrow << 1);
  const int tc = wc + (lrow << 1);
  float bm0 = bmS[tc], bm1 = bmS[tc + 1];
  float bl0 = blS[tc], bl1 = blS[tc + 1];
#pragma unroll
  for (int m = 0; m < 8; ++m) {
#pragma unroll
    for (int r = 0; r < 4; ++r) {
      int row = m * 16 + lhi * 4 + r;
      size_t gi = (((size_t)(e0 + row)) << 8) + tc;
      float mv0 = am[m][0][r] + bm0, mv1 = am[m][1][r] + bm1;
      float lv0 = al[m][0][r] + bl0, lv1 = al[m][1][r] + bl1;
      *(float2*)(o_mean + gi) = make_float2(mv0, mv1);
      *(float2*)(o_ls + gi) = make_float2(lv0, lv1);
      float2 g2 = *(const float2*)(gauss + gi);
      float zc = zS[(row << 2) + cidx];
      float nl0 = g2.x * __expf(lv0) + mv0;
      float nl1 = g2.y * __expf(lv1) + mv1;
      atomicAdd(&Mf[row * 66 + dd], zc * nl0);
      atomicAdd(&Mf[row * 66 + dd + 1], zc * nl1);
    }
  }
  __syncthreads();

  // A phase: thread = (edge, cat)
  {
    int e = t >> 2, cat = t & 3;
    const float* mrow = &Mf[e * 66];
    const float* wct = &WcT[cat * 68];
    float s = 0.f;
#pragma unroll
    for (int dp = 0; dp < 32; ++dp) {
      float2 m2 = *(const float2*)(mrow + 2 * dp);
      s += m2.x * wct[2 * dp] + m2.y * wct[2 * dp + 1];
    }
    s += bc[cat];
    float smx = fmaxf(s, __shfl_xor(s, 1));
    smx = fmaxf(smx, __shfl_xor(smx, 2));
    float es = __expf(s - smx);
    float ssum = es + __shfl_xor(es, 1);
    ssum += __shfl_xor(ssum, 2);
    A_o[(((size_t)e0) << 2) + t] = es / ssum;
  }
  // M write (packed u32, coalesced)
#pragma unroll
  for (int j = 0; j < 8; ++j) {
    int idx = j * 512 + t;
    int row = idx >> 5, dp = idx & 31;
    float2 m2 = *(const float2*)(&Mf[row * 66 + 2 * dp]);
    M_o32[((size_t)(e0 + row)) * 32 + dp] = pack2bf(m2.x, m2.y);
  }
}

// ---------------- fused decoder v3: 64 edges, 512 threads ----------------
__global__ __launch_bounds__(512) void k_dec2(
    const unsigned short* __restrict__ Mw, const unsigned short* __restrict__ Wd1T,
    const float* __restrict__ bd1, const unsigned short* __restrict__ WdXT,
    const float* __restrict__ bdX, float* __restrict__ Xo) {
  __shared__ __align__(16) char R[65280];
  short* Mt = (short*)R;             // [64][72] = 9216
  short* Bt1 = (short*)(R + 9216);   // [256][72] = 36864
  short* X1 = (short*)R;             // [64][264] = 33792, aliases stage-1 tiles
  short* Bt2 = (short*)(R + 46848);  // [128][72] = 18432
  const int t = threadIdx.x, lane = t & 63, wv = t >> 6;
  const int lrow = lane & 15, lhi = lane >> 4;
  const int e0 = blockIdx.x << 6;

  // stage 1: X1 = relu(M @ Wd1 + bd1), 64x256, K=64
  {
    int r = t >> 3, c8 = (t & 7) << 3;
    *(int4*)&Mt[r * 72 + c8] = *(const int4*)(Mw + (((size_t)(e0 + r)) << 6) + c8);
  }
  {
    int r1 = t >> 1, base = (t & 1) << 5;
    const unsigned short* wp = Wd1T + ((size_t)permc(r1) << 6) + base;
#pragma unroll
    for (int j = 0; j < 4; ++j)
      *(int4*)&Bt1[r1 * 72 + base + j * 8] = *(const int4*)(wp + j * 8);
  }
  __syncthreads();
  f32x4 acc1[4][2];
#pragma unroll
  for (int m = 0; m < 4; ++m)
#pragma unroll
    for (int n = 0; n < 2; ++n) acc1[m][n] = (f32x4){0.f, 0.f, 0.f, 0.f};
  const int wc1 = wv << 5;
  {
    short8 a0[4], a1[4], b0[2], b1[2];
#pragma unroll
    for (int m = 0; m < 4; ++m) {
      a0[m] = *(const short8*)&Mt[(m * 16 + lrow) * 72 + lhi * 8];
      a1[m] = *(const short8*)&Mt[(m * 16 + lrow) * 72 + 32 + lhi * 8];
    }
#pragma unroll
    for (int n = 0; n < 2; ++n) {
      b0[n] = *(const short8*)&Bt1[(wc1 + n * 16 + lrow) * 72 + lhi * 8];
      b1[n] = *(const short8*)&Bt1[(wc1 + n * 16 + lrow) * 72 + 32 + lhi * 8];
    }
#pragma unroll
    for (int m = 0; m < 4; ++m)
#pragma unroll
      for (int n = 0; n < 2; ++n) {
        acc1[m][n] = __builtin_amdgcn_mfma_f32_16x16x32_bf16(a0[m], b0[n], acc1[m][n], 0, 0, 0);
        acc1[m][n] = __builtin_amdgcn_mfma_f32_16x16x32_bf16(a1[m], b1[n], acc1[m][n], 0, 0, 0);
      }
  }
  __syncthreads();  // all tile reads done; X1 may overwrite
  {
    int tc = wc1 + (lrow << 1);
    float bdv0 = bd1[tc], bdv1 = bd1[tc + 1];
#pragma unroll
    for (int m = 0; m < 4; ++m)
#pragma unroll
      for (int r = 0; r < 4; ++r) {
        int row = m * 16 + lhi * 4 + r;
        float v0 = fmaxf(acc1[m][0][r] + bdv0, 0.f);
        float v1 = fmaxf(acc1[m][1][r] + bdv1, 0.f);
        *(unsigned*)&X1[row * 264 + tc] = pack2bf(v0, v1);
      }
  }

  // stage 2: X = relu(X1 @ WdX + bdX), 64x128, K=256 in 4 chunks
  f32x4 acc2[2][2];
#pragma unroll
  for (int m = 0; m < 2; ++m)
#pragma unroll
    for (int n = 0; n < 2; ++n) acc2[m][n] = (f32x4){0.f, 0.f, 0.f, 0.f};
  const int wr2 = (wv >> 2) << 5, wc2 = (wv & 3) << 5;
  for (int k0 = 0; k0 < 256; k0 += 64) {
    __syncthreads();
    {
      int r = t >> 2, base = (t & 3) << 4;
      const unsigned short* wp = WdXT + ((size_t)permc(r) << 8) + k0 + base;
      *(int4*)&Bt2[r * 72 + base] = *(const int4*)(wp);
      *(int4*)&Bt2[r * 72 + base + 8] = *(const int4*)(wp + 8);
    }
    __syncthreads();
    short8 c0[2], c1[2], d0[2], d1[2];
#pragma unroll
    for (int m = 0; m < 2; ++m) {
      c0[m] = *(const short8*)&X1[(wr2 + m * 16 + lrow) * 264 + k0 + lhi * 8];
      c1[m] = *(const short8*)&X1[(wr2 + m * 16 + lrow) * 264 + k0 + 32 + lhi * 8];
    }
#pragma unroll
    for (int n = 0; n < 2; ++n) {
      d0[n] = *(const short8*)&Bt2[(wc2 + n * 16 + lrow) * 72 + lhi * 8];
      d1[n] = *(const short8*)&Bt2[(wc2 + n * 16 + lrow) * 72 + 32 + lhi * 8];
    }
#pragma unroll
    for (int m = 0; m < 2; ++m)
#pragma unroll
      for (int n = 0; n < 2; ++n) {
        acc2[m][n] = __builtin_amdgcn_mfma_f32_16x16x32_bf16(c0[m], d0[n], acc2[m][n], 0, 0, 0);
        acc2[m][n] = __builtin_amdgcn_mfma_f32_16x16x32_bf16(c1[m], d1[n], acc2[m][n], 0, 0, 0);
      }
  }
  {
    int tc2 = wc2 + (lrow << 1);
    float bx0 = bdX[tc2], bx1 = bdX[tc2 + 1];
#pragma unroll
    for (int m = 0; m < 2; ++m)
#pragma unroll
      for (int r = 0; r < 4; ++r) {
        int row = wr2 + m * 16 + lhi * 4 + r;
        float v0 = fmaxf(acc2[m][0][r] + bx0, 0.f);
        float v1 = fmaxf(acc2[m][1][r] + bx1, 0.f);
        *(float2*)(Xo + (((size_t)(e0 + row)) << 7) + tc2) = make_float2(v0, v1);
      }
  }
}

extern "C" void kernel_launch(void* const* d_in, const int* in_sizes, int n_in,
                              void* d_out, int out_size, void* d_ws, size_t ws_size,
                              hipStream_t stream) {
  const float* x = (const float*)d_in[0];
  const int* src = (const int*)d_in[1];
  const int* dst = (const int*)d_in[2];
  const int* pos_src = (const int*)d_in[3];
  const int* pos_dst = (const int*)d_in[4];
  const int* neg_src = (const int*)d_in[5];
  const int* neg_dst = (const int*)d_in[6];
  const float* gauss_pos = (const float*)d_in[7];
  const float* gauss_neg = (const float*)d_in[8];
  const float* unif_pos = (const float*)d_in[9];
  const float* unif_neg = (const float*)d_in[10];
  const void* temp_p = d_in[11];
  const float* W1 = (const float*)d_in[12];
  const float* b1 = (const float*)d_in[13];
  const float* W2 = (const float*)d_in[14];
  const float* b2 = (const float*)d_in[15];
  const float* Wm = (const float*)d_in[16];
  const float* bm = (const float*)d_in[17];
  const float* Wl = (const float*)d_in[18];
  const float* bl = (const float*)d_in[19];
  const float* Wq = (const float*)d_in[20];
  const float* bq = (const float*)d_in[21];
  const float* Wd1 = (const float*)d_in[22];
  const float* bd1 = (const float*)d_in[23];
  const float* WdX = (const float*)d_in[24];
  const float* bdX = (const float*)d_in[25];
  const float* Wc = (const float*)d_in[26];
  const float* bc = (const float*)d_in[27];

  char* w = (char*)d_ws;
  int* degO = (int*)w;
  int* degI = (int*)(w + 401408);
  int* rowptr = (int*)(w + 802816);
  int* cursor = (int*)(w + 1204224);
  float* normO = (float*)(w + 1605632);
  float* normI = (float*)(w + 2007040);
  int* csr = (int*)(w + 2408448);
  unsigned short* W1T = (unsigned short*)(w + 5609472);
  unsigned short* W2T = (unsigned short*)(w + 5675008);
  unsigned short* WmT = (unsigned short*)(w + 5806080);
  unsigned short* WlT = (unsigned short*)(w + 5937152);
  unsigned short* Wd1T = (unsigned short*)(w + 6068224);
  unsigned short* WdXT = (unsigned short*)(w + 6100992);
  unsigned short* WqT = (unsigned short*)(w + 6166528);
  int* bsum = (int*)(w + 6174720);
  unsigned short* agg1 = (unsigned short*)(w + 6175232);
  unsigned short* h1s = (unsigned short*)(w + 31775232);
  unsigned short* agg2 = (unsigned short*)(w + 82975232);
  unsigned short* h = (unsigned short*)(w + 134175232);
  unsigned short* Mws = (unsigned short*)(w + 185375232);

  float* out = (float*)d_out;
  float* posA = out;
  float* negA = out + 1048576ull;
  float* posX = out + 2097152ull;
  float* negX = out + 35651584ull;
  float* pos_mean = out + 69206016ull;
  float* neg_mean = out + 136314880ull;
  float* pos_logstd = out + 203423744ull;
  float* neg_logstd = out + 270532608ull;
  float* posq = out + 337641472ull;
  float* negq = out + 338690048ull;

  hipMemsetAsync(d_ws, 0, 802816, stream);

  k_deg<<<1024, 256, 0, stream>>>(src, dst, degO, degI);
  k_norm<<<392, 256, 0, stream>>>(degO, degI, normO, normI);
  k_scan1<<<NB, 1024, 0, stream>>>(degI, rowptr, bsum);
  k_scan2<<<1, 128, 0, stream>>>(bsum);
  k_scan3<<<NB, 1024, 0, stream>>>(degI, rowptr, cursor, bsum);
  k_fill<<<1024, 256, 0, stream>>>(src, dst, cursor, csr);

  k_transpose<<<128, 256, 0, stream>>>(W1, W1T, 128, 255, 8, 32768);
  k_transpose<<<256, 256, 0, stream>>>(W2, W2T, 256, 255, 8, 65536);
  k_transpose<<<256, 256, 0, stream>>>(Wm, WmT, 256, 255, 8, 65536);
  k_transpose<<<256, 256, 0, stream>>>(Wl, WlT, 256, 255, 8, 65536);
  k_transpose<<<64, 256, 0, stream>>>(Wd1, Wd1T, 64, 255, 8, 16384);
  k_transpose<<<128, 256, 0, stream>>>(WdX, WdXT, 256, 127, 7, 32768);
  k_transpose_q<<<16, 256, 0, stream>>>(Wq, WqT);

  k_gather1<<<2048, 256, 0, stream>>>(x, rowptr, csr, normO, normI, agg1);
  k_gemm<128, true, true><<<782, 256, 0, stream>>>(agg1, normO, W1T, b1, h1s, NN);
  k_gather2<<<2048, 256, 0, stream>>>(h1s, rowptr, csr, normI, agg2);
  k_gemm<256, false, false><<<782, 256, 0, stream>>>(agg2, nullptr, W2T, b2, h, NN);

  for (int b = 0; b < 2; ++b) {
    const int* es = b ? neg_src : pos_src;
    const int* ed = b ? neg_dst : pos_dst;
    const float* gs = b ? gauss_neg : gauss_pos;
    const float* uf = b ? unif_neg : unif_pos;
    float* o_mean = b ? neg_mean : pos_mean;
    float* o_ls = b ? neg_logstd : pos_logstd;
    float* o_q = b ? negq : posq;
    float* o_A = b ? negA : posA;
    float* o_X = b ? negX : posX;

    k_branch2<<<2048, 512, 0, stream>>>(h, es, ed, gs, uf, temp_p,
                                        WmT, bm, WlT, bl, WqT, bq, Wc, bc,
                                        o_mean, o_ls, o_q, o_A, (unsigned*)Mws);
    k_dec2<<<4096, 512, 0, stream>>>(Mws, Wd1T, bd1, WdXT, bdX, o_X);
  }
}

// Round 7
// 1490.722 us; speedup vs baseline: 3.8169x; 1.0563x over previous
//
#include <hip/hip_runtime.h>
#include <hip/hip_bf16.h>

// Round 7: T14 async gather-prefetch in branch2, NT loads/stores for stream-once
// data (gauss/mean/logstd/X/q/A), decoder weight prefetch, merged transposes,
// norm folded into scan3.

#define NN 100000
#define EG 800000
#define EE 262144
#define NB 98

typedef __attribute__((ext_vector_type(8))) short short8;
typedef __attribute__((ext_vector_type(4))) float f32x4;
typedef __attribute__((ext_vector_type(2))) float f32x2;

__device__ __forceinline__ float lo2f(unsigned u) {
  union { unsigned u; float f; } v; v.u = u << 16; return v.f;
}
__device__ __forceinline__ float hi2f(unsigned u) {
  union { unsigned u; float f; } v; v.u = u & 0xFFFF0000u; return v.f;
}
__device__ __forceinline__ unsigned short f2bf(float f) {
  union { float f; unsigned u; } v; v.f = f;
  return (unsigned short)((v.u + 0x7FFFu + ((v.u >> 16) & 1u)) >> 16);
}
__device__ __forceinline__ unsigned pack2bf(float a, float b) {
  return (unsigned)f2bf(a) | ((unsigned)f2bf(b) << 16);
}
__device__ __forceinline__ int permc(int c) {
  return (c & ~31) | ((c & 15) << 1) | ((c >> 4) & 1);
}

__device__ __forceinline__ float decode_scalar(const void* p) {
  unsigned u = *(const unsigned*)p;
  float f = __uint_as_float(u);
  float af = fabsf(f);
  if (af >= 1e-6f && af <= 1e6f) return f;
  if (u < 1024u) return (float)u;
  return 1.0f;
}

// ---------------- degrees ----------------
__global__ __launch_bounds__(256) void k_deg(const int* __restrict__ src,
                                             const int* __restrict__ dst,
                                             int* __restrict__ degO,
                                             int* __restrict__ degI) {
  for (int i = blockIdx.x * 256 + threadIdx.x; i < EG; i += gridDim.x * 256) {
    atomicAdd(&degO[src[i]], 1);
    atomicAdd(&degI[dst[i]], 1);
  }
}

// ---------------- parallel scan ----------------
__global__ __launch_bounds__(1024) void k_scan1(const int* __restrict__ degI,
                                                int* __restrict__ rowptr,
                                                int* __restrict__ bsum) {
  __shared__ int wsum[16];
  int t = threadIdx.x, lane = t & 63, wv = t >> 6;
  int i = blockIdx.x * 1024 + t;
  int v = (i < NN) ? degI[i] : 0;
  int incl = v;
#pragma unroll
  for (int off = 1; off < 64; off <<= 1) {
    int u = __shfl_up(incl, off);
    if (lane >= off) incl += u;
  }
  if (lane == 63) wsum[wv] = incl;
  __syncthreads();
  if (wv == 0 && lane < 16) {
    int s = wsum[lane];
    int si = s;
#pragma unroll
    for (int off = 1; off < 16; off <<= 1) {
      int u = __shfl_up(si, off);
      if (lane >= off) si += u;
    }
    wsum[lane] = si - s;
    if (lane == 15) bsum[blockIdx.x] = si;
  }
  __syncthreads();
  int excl = wsum[wv] + incl - v;
  if (i < NN) rowptr[i] = excl;
}

__global__ __launch_bounds__(128) void k_scan2(int* __restrict__ bsum) {
  __shared__ int w0tot;
  int t = threadIdx.x, lane = t & 63, wv = t >> 6;
  int v = (t < NB) ? bsum[t] : 0;
  int incl = v;
#pragma unroll
  for (int off = 1; off < 64; off <<= 1) {
    int u = __shfl_up(incl, off);
    if (lane >= off) incl += u;
  }
  if (wv == 0 && lane == 63) w0tot = incl;
  __syncthreads();
  int excl = incl - v + (wv ? w0tot : 0);
  if (t < NB) bsum[t] = excl;
}

// scan phase 3 + norm computation (folded)
__global__ __launch_bounds__(1024) void k_scan3(const int* __restrict__ degI,
                                                const int* __restrict__ degO,
                                                int* __restrict__ rowptr,
                                                int* __restrict__ cursor,
                                                const int* __restrict__ bsum,
                                                float* __restrict__ normO,
                                                float* __restrict__ normI) {
  int i = blockIdx.x * 1024 + threadIdx.x;
  if (i < NN) {
    int vv = rowptr[i] + bsum[blockIdx.x];
    rowptr[i] = vv;
    cursor[i] = vv;
    if (i == NN - 1) rowptr[NN] = vv + degI[i];
    int dO = degO[i]; if (dO < 1) dO = 1;
    int dI = degI[i]; if (dI < 1) dI = 1;
    normO[i] = rsqrtf((float)dO);
    normI[i] = rsqrtf((float)dI);
  }
}

__global__ __launch_bounds__(256) void k_fill(const int* __restrict__ src,
                                              const int* __restrict__ dst,
                                              int* __restrict__ cursor,
                                              int* __restrict__ csr) {
  for (int e = blockIdx.x * 256 + threadIdx.x; e < EG; e += gridDim.x * 256) {
    int d = dst[e];
    int pos = atomicAdd(&cursor[d], 1);
    csr[pos] = src[e];
  }
}

// ---------------- merged weight transposes (all 7 in one launch) ----------------
__global__ __launch_bounds__(256) void k_transpose_all(
    const float* __restrict__ W1, const float* __restrict__ W2,
    const float* __restrict__ Wm, const float* __restrict__ Wl,
    const float* __restrict__ Wd1, const float* __restrict__ WdX,
    const float* __restrict__ Wq,
    unsigned short* __restrict__ W1T, unsigned short* __restrict__ W2T,
    unsigned short* __restrict__ WmT, unsigned short* __restrict__ WlT,
    unsigned short* __restrict__ Wd1T, unsigned short* __restrict__ WdXT,
    unsigned short* __restrict__ WqT) {
  int idx = blockIdx.x * 256 + threadIdx.x;
  if (idx < 32768) {                       // W1 [128][256] -> [256][128]
    int n = idx & 255, k = idx >> 8;
    W1T[n * 128 + k] = f2bf(W1[idx]);
  } else if (idx < 98304) {                // W2 [256][256] -> [256][256]
    int i = idx - 32768;
    int n = i & 255, k = i >> 8;
    W2T[n * 256 + k] = f2bf(W2[i]);
  } else if (idx < 163840) {               // Wm
    int i = idx - 98304;
    int n = i & 255, k = i >> 8;
    WmT[n * 256 + k] = f2bf(Wm[i]);
  } else if (idx < 229376) {               // Wl
    int i = idx - 163840;
    int n = i & 255, k = i >> 8;
    WlT[n * 256 + k] = f2bf(Wl[i]);
  } else if (idx < 245760) {               // Wd1 [64][256] -> [256][64]
    int i = idx - 229376;
    int n = i & 255, k = i >> 8;
    Wd1T[n * 64 + k] = f2bf(Wd1[i]);
  } else if (idx < 278528) {               // WdX [256][128] -> [128][256]
    int i = idx - 245760;
    int n = i & 127, k = i >> 7;
    WdXT[n * 256 + k] = f2bf(WdX[i]);
  } else if (idx < 282624) {               // Wq [256][4] -> [16 pad][256]
    int i = idx - 278528;
    int r = i >> 8, k = i & 255;
    WqT[i] = (r < 4) ? f2bf(Wq[k * 4 + r]) : (unsigned short)0;
  }
}

// ---------------- gather layer 1 ----------------
__global__ __launch_bounds__(256) void k_gather1(
    const float* __restrict__ x, const int* __restrict__ rowptr,
    const int* __restrict__ csr, const float* __restrict__ normO,
    const float* __restrict__ normI, unsigned short* __restrict__ agg) {
  int wid = (blockIdx.x * 256 + threadIdx.x) >> 6;
  int lane = threadIdx.x & 63;
  int half = lane >> 5, fl = lane & 31;
  int nw = (gridDim.x * 256) >> 6;
  for (int n = wid; n < NN; n += nw) {
    int beg = rowptr[n], end = rowptr[n + 1];
    float a0 = 0.f, a1 = 0.f, a2 = 0.f, a3 = 0.f;
    for (int i = beg + half; i < end; i += 2) {
      int s = csr[i];
      float ns = normO[s];
      float4 v = *(const float4*)(x + ((size_t)s << 7) + (fl << 2));
      a0 += ns * v.x; a1 += ns * v.y; a2 += ns * v.z; a3 += ns * v.w;
    }
    a0 += __shfl_xor(a0, 32); a1 += __shfl_xor(a1, 32);
    a2 += __shfl_xor(a2, 32); a3 += __shfl_xor(a3, 32);
    if (lane < 32) {
      float ni = normI[n];
      *(uint2*)(agg + ((size_t)n << 7) + (fl << 2)) =
          make_uint2(pack2bf(a0 * ni, a1 * ni), pack2bf(a2 * ni, a3 * ni));
    }
  }
}

// ---------------- gather layer 2 ----------------
__global__ __launch_bounds__(256) void k_gather2(
    const unsigned short* __restrict__ h1s, const int* __restrict__ rowptr,
    const int* __restrict__ csr, const float* __restrict__ normI,
    unsigned short* __restrict__ agg) {
  int wid = (blockIdx.x * 256 + threadIdx.x) >> 6;
  int lane = threadIdx.x & 63;
  int half = lane >> 5, fl = lane & 31;
  int nw = (gridDim.x * 256) >> 6;
  for (int n = wid; n < NN; n += nw) {
    int beg = rowptr[n], end = rowptr[n + 1];
    float a0 = 0.f, a1 = 0.f, a2 = 0.f, a3 = 0.f, a4 = 0.f, a5 = 0.f, a6 = 0.f, a7 = 0.f;
    for (int i = beg + half; i < end; i += 2) {
      int s = csr[i];
      uint4 v = *(const uint4*)(h1s + ((size_t)s << 8) + (fl << 3));
      a0 += lo2f(v.x); a1 += hi2f(v.x);
      a2 += lo2f(v.y); a3 += hi2f(v.y);
      a4 += lo2f(v.z); a5 += hi2f(v.z);
      a6 += lo2f(v.w); a7 += hi2f(v.w);
    }
    a0 += __shfl_xor(a0, 32); a1 += __shfl_xor(a1, 32);
    a2 += __shfl_xor(a2, 32); a3 += __shfl_xor(a3, 32);
    a4 += __shfl_xor(a4, 32); a5 += __shfl_xor(a5, 32);
    a6 += __shfl_xor(a6, 32); a7 += __shfl_xor(a7, 32);
    if (lane < 32) {
      float ni = normI[n];
      uint4 o;
      o.x = pack2bf(a0 * ni, a1 * ni);
      o.y = pack2bf(a2 * ni, a3 * ni);
      o.z = pack2bf(a4 * ni, a5 * ni);
      o.w = pack2bf(a6 * ni, a7 * ni);
      *(uint4*)(agg + ((size_t)n << 8) + (fl << 3)) = o;
    }
  }
}

// ---------------- encoder GEMM ----------------
template <int K, bool RELU, bool OSCALE>
__global__ __launch_bounds__(256) void k_gemm(
    const unsigned short* __restrict__ A, const float* __restrict__ oscale,
    const unsigned short* __restrict__ WT, const float* __restrict__ bias,
    unsigned short* __restrict__ C, int M) {
  __shared__ __align__(16) short At[128 * 40];
  __shared__ __align__(16) short Bt[256 * 40];
  const int t = threadIdx.x;
  const int row0 = blockIdx.x * 128;
  const int lane = t & 63, wave = t >> 6;
  const int wr = (wave >> 1) << 6;
  const int wcc = (wave & 1) << 7;
  const int lrow = lane & 15, lhi = lane >> 4;

  f32x4 acc[4][8];
#pragma unroll
  for (int m = 0; m < 4; ++m)
#pragma unroll
    for (int n = 0; n < 8; ++n) acc[m][n] = (f32x4){0.f, 0.f, 0.f, 0.f};

  for (int k0 = 0; k0 < K; k0 += 32) {
    if (k0) __syncthreads();
#pragma unroll
    for (int it = 0; it < 2; ++it) {
      int idx = t + it * 256;
      int r = idx >> 2, c8 = (idx & 3) << 3;
      int grow = row0 + r;
      int4 tv = {0, 0, 0, 0};
      if (grow < M) tv = *(const int4*)(A + (size_t)grow * K + k0 + c8);
      *(int4*)&At[r * 40 + c8] = tv;
    }
    {
      const unsigned short* wt = WT + (size_t)permc(t) * K + k0;
      *(int4*)&Bt[t * 40 + 0] = *(const int4*)(wt);
      *(int4*)&Bt[t * 40 + 8] = *(const int4*)(wt + 8);
      *(int4*)&Bt[t * 40 + 16] = *(const int4*)(wt + 16);
      *(int4*)&Bt[t * 40 + 24] = *(const int4*)(wt + 24);
    }
    __syncthreads();
    short8 a[4], b[8];
#pragma unroll
    for (int m = 0; m < 4; ++m)
      a[m] = *(const short8*)&At[(wr + m * 16 + lrow) * 40 + lhi * 8];
#pragma unroll
    for (int n = 0; n < 8; ++n)
      b[n] = *(const short8*)&Bt[(wcc + n * 16 + lrow) * 40 + lhi * 8];
#pragma unroll
    for (int m = 0; m < 4; ++m)
#pragma unroll
      for (int n = 0; n < 8; ++n)
        acc[m][n] = __builtin_amdgcn_mfma_f32_16x16x32_bf16(a[m], b[n], acc[m][n], 0, 0, 0);
  }
#pragma unroll
  for (int np = 0; np < 4; ++np) {
    int tc = wcc + np * 32 + (lrow << 1);
    float bv0 = bias[tc], bv1 = bias[tc + 1];
#pragma unroll
    for (int m = 0; m < 4; ++m) {
#pragma unroll
      for (int r = 0; r < 4; ++r) {
        int grow = row0 + wr + m * 16 + lhi * 4 + r;
        if (grow < M) {
          float v0 = acc[m][2 * np][r] + bv0;
          float v1 = acc[m][2 * np + 1][r] + bv1;
          if (RELU) { v0 = fmaxf(v0, 0.f); v1 = fmaxf(v1, 0.f); }
          if (OSCALE) { float s = oscale[grow]; v0 *= s; v1 *= s; }
          *(unsigned*)&C[(size_t)grow * 256 + tc] = pack2bf(v0, v1);
        }
      }
    }
  }
}

// ---------------- fused branch v4: async gather prefetch + NT I/O ----------------
__global__ __launch_bounds__(512) void k_branch2(
    const unsigned short* __restrict__ h, const int* __restrict__ ea,
    const int* __restrict__ eb, const float* __restrict__ gauss,
    const float* __restrict__ unif, const void* __restrict__ temp_p,
    const unsigned short* __restrict__ WmT, const float* __restrict__ bm,
    const unsigned short* __restrict__ WlT, const float* __restrict__ bl,
    const unsigned short* __restrict__ WqT, const float* __restrict__ bq,
    const float* __restrict__ Wc, const float* __restrict__ bc,
    float* __restrict__ o_mean, float* __restrict__ o_ls,
    float* __restrict__ q_o, float* __restrict__ A_o,
    unsigned* __restrict__ M_o32) {
  __shared__ __align__(16) char U[41984];  // staging | Mf f32[128][66]
  short* At = (short*)U;                   // [128][32] slot-swizzled
  short* Btm = (short*)(U + 8192);         // [256][32]
  short* Btl = (short*)(U + 24576);        // [256][32]
  short* Btq = (short*)(U + 40960);        // [16][32]
  float* Mf = (float*)U;                   // [128][66]
  __shared__ float zS[512];
  __shared__ float qS[512];
  __shared__ float WcT[4 * 68];
  __shared__ float bmS[256], blS[256];
  __shared__ int eaS[128], ebS[128];

  const int t = threadIdx.x;
  const int e0 = blockIdx.x << 7;
  const int lane = t & 63;
  const int wv = t >> 6;
  const int lrow = lane & 15, lhi = lane >> 4;
  const int wc = wv << 5;

  if (t < 256) {
    bmS[t] = bm[t]; blS[t] = bl[t];
    WcT[(t & 3) * 68 + (t >> 2)] = Wc[t];
  } else if (t < 384) {
    eaS[t - 256] = ea[e0 + t - 256];
  } else {
    ebS[t - 384] = eb[e0 + t - 384];
  }
  __syncthreads();

  f32x4 am[8][2], al[8][2], aq;
#pragma unroll
  for (int m = 0; m < 8; ++m)
#pragma unroll
    for (int n = 0; n < 2; ++n) {
      am[m][n] = (f32x4){0.f, 0.f, 0.f, 0.f};
      al[m][n] = (f32x4){0.f, 0.f, 0.f, 0.f};
    }
  aq = (f32x4){0.f, 0.f, 0.f, 0.f};

  const int ar = t >> 2, as_ = t & 3;
  const int arsw = ((as_ ^ (ar & 3)) << 3);
  const int br = t & 255, bw = t >> 8;
  const int fsw = (lrow & 3);

  const unsigned short* pa_base = h + ((size_t)eaS[ar] << 8) + (as_ << 3);
  const unsigned short* pb_base = h + ((size_t)ebS[ar] << 8) + (as_ << 3);
  const unsigned short* wsrc_base = (bw ? WlT : WmT) + ((size_t)permc(br) << 8);
  short* bb = (bw ? Btl : Btm) + br * 32;
  const int rs = br & 3;

  // prologue gather
  uint4 va = *(const uint4*)pa_base;
  uint4 vb = *(const uint4*)pb_base;

  for (int k0 = 0; k0 < 256; k0 += 32) {
    unsigned w0 = pack2bf(lo2f(va.x) + lo2f(vb.x), hi2f(va.x) + hi2f(vb.x));
    unsigned w1 = pack2bf(lo2f(va.y) + lo2f(vb.y), hi2f(va.y) + hi2f(vb.y));
    unsigned w2 = pack2bf(lo2f(va.z) + lo2f(vb.z), hi2f(va.z) + hi2f(vb.z));
    unsigned w3 = pack2bf(lo2f(va.w) + lo2f(vb.w), hi2f(va.w) + hi2f(vb.w));
    // issue next iteration's gather loads (hidden under this iteration's MFMA)
    if (k0 < 224) {
      va = *(const uint4*)(pa_base + k0 + 32);
      vb = *(const uint4*)(pb_base + k0 + 32);
    }
    if (k0) __syncthreads();
    *(int4*)&At[ar * 32 + arsw] = make_int4((int)w0, (int)w1, (int)w2, (int)w3);
    {
      const unsigned short* wsrc = wsrc_base + k0;
      *(int4*)&bb[((0 ^ rs) << 3)] = *(const int4*)(wsrc);
      *(int4*)&bb[((1 ^ rs) << 3)] = *(const int4*)(wsrc + 8);
      *(int4*)&bb[((2 ^ rs) << 3)] = *(const int4*)(wsrc + 16);
      *(int4*)&bb[((3 ^ rs) << 3)] = *(const int4*)(wsrc + 24);
    }
    if (t < 64) {
      int r = t >> 2, s = t & 3;
      *(int4*)&Btq[r * 32 + ((s ^ (r & 3)) << 3)] =
          *(const int4*)(WqT + ((size_t)r << 8) + k0 + (s << 3));
    }
    __syncthreads();
    short8 a[8], bmf[2], blf[2], bqf, aqa;
#pragma unroll
    for (int m = 0; m < 8; ++m)
      a[m] = *(const short8*)&At[(m * 16 + lrow) * 32 + ((lhi ^ fsw) << 3)];
#pragma unroll
    for (int n = 0; n < 2; ++n) {
      bmf[n] = *(const short8*)&Btm[(wc + n * 16 + lrow) * 32 + ((lhi ^ fsw) << 3)];
      blf[n] = *(const short8*)&Btl[(wc + n * 16 + lrow) * 32 + ((lhi ^ fsw) << 3)];
    }
    bqf = *(const short8*)&Btq[lrow * 32 + ((lhi ^ fsw) << 3)];
    aqa = *(const short8*)&At[((wv << 4) + lrow) * 32 + ((lhi ^ fsw) << 3)];
#pragma unroll
    for (int m = 0; m < 8; ++m)
#pragma unroll
      for (int n = 0; n < 2; ++n) {
        am[m][n] = __builtin_amdgcn_mfma_f32_16x16x32_bf16(a[m], bmf[n], am[m][n], 0, 0, 0);
        al[m][n] = __builtin_amdgcn_mfma_f32_16x16x32_bf16(a[m], blf[n], al[m][n], 0, 0, 0);
      }
    aq = __builtin_amdgcn_mfma_f32_16x16x32_bf16(aqa, bqf, aq, 0, 0, 0);
  }
  __syncthreads();

  // Z phase + zero Mf (staging now dead)
  float invt = 1.0f / decode_scalar(temp_p);
  float qb = (lrow < 4) ? bq[lrow] : 0.f;
#pragma unroll
  for (int r = 0; r < 4; ++r) {
    int el = (wv << 4) + lhi * 4 + r;
    float q = aq[r] + qb;
    float uu = 0.5f;
    if (lrow < 4) uu = unif[(((size_t)(e0 + el)) << 2) + lrow];
    float g = -__logf(-__logf(uu + 1e-7f) + 1e-7f);
    float z = (q + g) * invt;
    float mx = fmaxf(z, __shfl_xor(z, 1));
    mx = fmaxf(mx, __shfl_xor(mx, 2));
    float ez = __expf(z - mx);
    float sz = ez + __shfl_xor(ez, 1);
    sz += __shfl_xor(sz, 2);
    if (lrow < 4) { zS[el * 4 + lrow] = ez / sz; qS[el * 4 + lrow] = q; }
  }
  for (int i = t; i < 128 * 66; i += 512) Mf[i] = 0.f;
  __syncthreads();

  // coalesced q store
  __builtin_nontemporal_store(qS[t], q_o + (((size_t)e0) << 2) + t);

  // mean/ls epilogue: NT float2 stores + f32 LDS atomic M accumulation
  const int cidx = wv >> 1;
  const int dd = ((wv & 1) << 5) + (lrow << 1);
  const int tc = wc + (lrow << 1);
  float bm0 = bmS[tc], bm1 = bmS[tc + 1];
  float bl0 = blS[tc], bl1 = blS[tc + 1];
#pragma unroll
  for (int m = 0; m < 8; ++m) {
#pragma unroll
    for (int r = 0; r < 4; ++r) {
      int row = m * 16 + lhi * 4 + r;
      size_t gi = (((size_t)(e0 + row)) << 8) + tc;
      float mv0 = am[m][0][r] + bm0, mv1 = am[m][1][r] + bm1;
      float lv0 = al[m][0][r] + bl0, lv1 = al[m][1][r] + bl1;
      __builtin_nontemporal_store((f32x2){mv0, mv1}, (f32x2*)(o_mean + gi));
      __builtin_nontemporal_store((f32x2){lv0, lv1}, (f32x2*)(o_ls + gi));
      f32x2 g2 = __builtin_nontemporal_load((const f32x2*)(gauss + gi));
      float zc = zS[(row << 2) + cidx];
      atomicAdd(&Mf[row * 66 + dd], zc * (g2.x * __expf(lv0) + mv0));
      atomicAdd(&Mf[row * 66 + dd + 1], zc * (g2.y * __expf(lv1) + mv1));
    }
  }
  __syncthreads();

  // A phase: thread = (edge, cat)
  {
    int e = t >> 2, cat = t & 3;
    const float* mrow = &Mf[e * 66];
    const float* wct = &WcT[cat * 68];
    float s = 0.f;
#pragma unroll
    for (int dp = 0; dp < 32; ++dp) {
      float2 m2 = *(const float2*)(mrow + 2 * dp);
      s += m2.x * wct[2 * dp] + m2.y * wct[2 * dp + 1];
    }
    s += bc[cat];
    float smx = fmaxf(s, __shfl_xor(s, 1));
    smx = fmaxf(smx, __shfl_xor(smx, 2));
    float es = __expf(s - smx);
    float ssum = es + __shfl_xor(es, 1);
    ssum += __shfl_xor(ssum, 2);
    __builtin_nontemporal_store(es / ssum, A_o + (((size_t)e0) << 2) + t);
  }
  // M write (packed u32, coalesced; re-read by decoder -> keep cached)
#pragma unroll
  for (int j = 0; j < 8; ++j) {
    int idx = j * 512 + t;
    int row = idx >> 5, dp = idx & 31;
    float2 m2 = *(const float2*)(&Mf[row * 66 + 2 * dp]);
    M_o32[((size_t)(e0 + row)) * 32 + dp] = pack2bf(m2.x, m2.y);
  }
}

// ---------------- fused decoder v4: weight prefetch + NT X store ----------------
__global__ __launch_bounds__(512) void k_dec2(
    const unsigned short* __restrict__ Mw, const unsigned short* __restrict__ Wd1T,
    const float* __restrict__ bd1, const unsigned short* __restrict__ WdXT,
    const float* __restrict__ bdX, float* __restrict__ Xo) {
  __shared__ __align__(16) char R[65280];
  short* Mt = (short*)R;             // [64][72]
  short* Bt1 = (short*)(R + 9216);   // [256][72]
  short* X1 = (short*)R;             // [64][264] aliases stage-1 tiles
  short* Bt2 = (short*)(R + 46848);  // [128][72] (no alias with Mt/Bt1/X1 live ranges)
  const int t = threadIdx.x, lane = t & 63, wv = t >> 6;
  const int lrow = lane & 15, lhi = lane >> 4;
  const int e0 = blockIdx.x << 6;

  // stage-2 weight prefetch base (issued during stage 1)
  const int r2 = t >> 2, base2 = (t & 3) << 4;
  const unsigned short* wpb = WdXT + ((size_t)permc(r2) << 8) + base2;

  // stage 1: X1 = relu(M @ Wd1 + bd1), 64x256, K=64
  {
    int r = t >> 3, c8 = (t & 7) << 3;
    *(int4*)&Mt[r * 72 + c8] = *(const int4*)(Mw + (((size_t)(e0 + r)) << 6) + c8);
  }
  {
    int r1 = t >> 1, base = (t & 1) << 5;
    const unsigned short* wp = Wd1T + ((size_t)permc(r1) << 6) + base;
#pragma unroll
    for (int j = 0; j < 4; ++j)
      *(int4*)&Bt1[r1 * 72 + base + j * 8] = *(const int4*)(wp + j * 8);
  }
  // prologue prefetch for stage-2 chunk 0 (hides L2 latency under stage 1)
  int4 pw0 = *(const int4*)(wpb);
  int4 pw1 = *(const int4*)(wpb + 8);
  __syncthreads();
  f32x4 acc1[4][2];
#pragma unroll
  for (int m = 0; m < 4; ++m)
#pragma unroll
    for (int n = 0; n < 2; ++n) acc1[m][n] = (f32x4){0.f, 0.f, 0.f, 0.f};
  const int wc1 = wv << 5;
  {
    short8 a0[4], a1[4], b0[2], b1[2];
#pragma unroll
    for (int m = 0; m < 4; ++m) {
      a0[m] = *(const short8*)&Mt[(m * 16 + lrow) * 72 + lhi * 8];
      a1[m] = *(const short8*)&Mt[(m * 16 + lrow) * 72 + 32 + lhi * 8];
    }
#pragma unroll
    for (int n = 0; n < 2; ++n) {
      b0[n] = *(const short8*)&Bt1[(wc1 + n * 16 + lrow) * 72 + lhi * 8];
      b1[n] = *(const short8*)&Bt1[(wc1 + n * 16 + lrow) * 72 + 32 + lhi * 8];
    }
#pragma unroll
    for (int m = 0; m < 4; ++m)
#pragma unroll
      for (int n = 0; n < 2; ++n) {
        acc1[m][n] = __builtin_amdgcn_mfma_f32_16x16x32_bf16(a0[m], b0[n], acc1[m][n], 0, 0, 0);
        acc1[m][n] = __builtin_amdgcn_mfma_f32_16x16x32_bf16(a1[m], b1[n], acc1[m][n], 0, 0, 0);
      }
  }
  __syncthreads();  // all tile reads done; X1 may overwrite
  {
    int tc = wc1 + (lrow << 1);
    float bdv0 = bd1[tc], bdv1 = bd1[tc + 1];
#pragma unroll
    for (int m = 0; m < 4; ++m)
#pragma unroll
      for (int r = 0; r < 4; ++r) {
        int row = m * 16 + lhi * 4 + r;
        float v0 = fmaxf(acc1[m][0][r] + bdv0, 0.f);
        float v1 = fmaxf(acc1[m][1][r] + bdv1, 0.f);
        *(unsigned*)&X1[row * 264 + tc] = pack2bf(v0, v1);
      }
  }

  // stage 2: X = relu(X1 @ WdX + bdX), 64x128, K=256 in 4 chunks, prefetched
  f32x4 acc2[2][2];
#pragma unroll
  for (int m = 0; m < 2; ++m)
#pragma unroll
    for (int n = 0; n < 2; ++n) acc2[m][n] = (f32x4){0.f, 0.f, 0.f, 0.f};
  const int wr2 = (wv >> 2) << 5, wc2 = (wv & 3) << 5;
  for (int k0 = 0; k0 < 256; k0 += 64) {
    __syncthreads();
    *(int4*)&Bt2[r2 * 72 + base2] = pw0;
    *(int4*)&Bt2[r2 * 72 + base2 + 8] = pw1;
    if (k0 < 192) {
      pw0 = *(const int4*)(wpb + k0 + 64);
      pw1 = *(const int4*)(wpb + k0 + 64 + 8);
    }
    __syncthreads();
    short8 c0[2], c1[2], d0[2], d1[2];
#pragma unroll
    for (int m = 0; m < 2; ++m) {
      c0[m] = *(const short8*)&X1[(wr2 + m * 16 + lrow) * 264 + k0 + lhi * 8];
      c1[m] = *(const short8*)&X1[(wr2 + m * 16 + lrow) * 264 + k0 + 32 + lhi * 8];
    }
#pragma unroll
    for (int n = 0; n < 2; ++n) {
      d0[n] = *(const short8*)&Bt2[(wc2 + n * 16 + lrow) * 72 + lhi * 8];
      d1[n] = *(const short8*)&Bt2[(wc2 + n * 16 + lrow) * 72 + 32 + lhi * 8];
    }
#pragma unroll
    for (int m = 0; m < 2; ++m)
#pragma unroll
      for (int n = 0; n < 2; ++n) {
        acc2[m][n] = __builtin_amdgcn_mfma_f32_16x16x32_bf16(c0[m], d0[n], acc2[m][n], 0, 0, 0);
        acc2[m][n] = __builtin_amdgcn_mfma_f32_16x16x32_bf16(c1[m], d1[n], acc2[m][n], 0, 0, 0);
      }
  }
  {
    int tc2 = wc2 + (lrow << 1);
    float bx0 = bdX[tc2], bx1 = bdX[tc2 + 1];
#pragma unroll
    for (int m = 0; m < 2; ++m)
#pragma unroll
      for (int r = 0; r < 4; ++r) {
        int row = wr2 + m * 16 + lhi * 4 + r;
        float v0 = fmaxf(acc2[m][0][r] + bx0, 0.f);
        float v1 = fmaxf(acc2[m][1][r] + bx1, 0.f);
        __builtin_nontemporal_store((f32x2){v0, v1},
                                    (f32x2*)(Xo + (((size_t)(e0 + row)) << 7) + tc2));
      }
  }
}

extern "C" void kernel_launch(void* const* d_in, const int* in_sizes, int n_in,
                              void* d_out, int out_size, void* d_ws, size_t ws_size,
                              hipStream_t stream) {
  const float* x = (const float*)d_in[0];
  const int* src = (const int*)d_in[1];
  const int* dst = (const int*)d_in[2];
  const int* pos_src = (const int*)d_in[3];
  const int* pos_dst = (const int*)d_in[4];
  const int* neg_src = (const int*)d_in[5];
  const int* neg_dst = (const int*)d_in[6];
  const float* gauss_pos = (const float*)d_in[7];
  const float* gauss_neg = (const float*)d_in[8];
  const float* unif_pos = (const float*)d_in[9];
  const float* unif_neg = (const float*)d_in[10];
  const void* temp_p = d_in[11];
  const float* W1 = (const float*)d_in[12];
  const float* b1 = (const float*)d_in[13];
  const float* W2 = (const float*)d_in[14];
  const float* b2 = (const float*)d_in[15];
  const float* Wm = (const float*)d_in[16];
  const float* bm = (const float*)d_in[17];
  const float* Wl = (const float*)d_in[18];
  const float* bl = (const float*)d_in[19];
  const float* Wq = (const float*)d_in[20];
  const float* bq = (const float*)d_in[21];
  const float* Wd1 = (const float*)d_in[22];
  const float* bd1 = (const float*)d_in[23];
  const float* WdX = (const float*)d_in[24];
  const float* bdX = (const float*)d_in[25];
  const float* Wc = (const float*)d_in[26];
  const float* bc = (const float*)d_in[27];

  char* w = (char*)d_ws;
  int* degO = (int*)w;
  int* degI = (int*)(w + 401408);
  int* rowptr = (int*)(w + 802816);
  int* cursor = (int*)(w + 1204224);
  float* normO = (float*)(w + 1605632);
  float* normI = (float*)(w + 2007040);
  int* csr = (int*)(w + 2408448);
  unsigned short* W1T = (unsigned short*)(w + 5609472);
  unsigned short* W2T = (unsigned short*)(w + 5675008);
  unsigned short* WmT = (unsigned short*)(w + 5806080);
  unsigned short* WlT = (unsigned short*)(w + 5937152);
  unsigned short* Wd1T = (unsigned short*)(w + 6068224);
  unsigned short* WdXT = (unsigned short*)(w + 6100992);
  unsigned short* WqT = (unsigned short*)(w + 6166528);
  int* bsum = (int*)(w + 6174720);
  unsigned short* agg1 = (unsigned short*)(w + 6175232);
  unsigned short* h1s = (unsigned short*)(w + 31775232);
  unsigned short* agg2 = (unsigned short*)(w + 82975232);
  unsigned short* h = (unsigned short*)(w + 134175232);
  unsigned short* Mws = (unsigned short*)(w + 185375232);

  float* out = (float*)d_out;
  float* posA = out;
  float* negA = out + 1048576ull;
  float* posX = out + 2097152ull;
  float* negX = out + 35651584ull;
  float* pos_mean = out + 69206016ull;
  float* neg_mean = out + 136314880ull;
  float* pos_logstd = out + 203423744ull;
  float* neg_logstd = out + 270532608ull;
  float* posq = out + 337641472ull;
  float* negq = out + 338690048ull;

  hipMemsetAsync(d_ws, 0, 802816, stream);

  k_deg<<<1024, 256, 0, stream>>>(src, dst, degO, degI);
  k_scan1<<<NB, 1024, 0, stream>>>(degI, rowptr, bsum);
  k_scan2<<<1, 128, 0, stream>>>(bsum);
  k_scan3<<<NB, 1024, 0, stream>>>(degI, degO, rowptr, cursor, bsum, normO, normI);
  k_fill<<<1024, 256, 0, stream>>>(src, dst, cursor, csr);
  k_transpose_all<<<1104, 256, 0, stream>>>(W1, W2, Wm, Wl, Wd1, WdX, Wq,
                                            W1T, W2T, WmT, WlT, Wd1T, WdXT, WqT);

  k_gather1<<<2048, 256, 0, stream>>>(x, rowptr, csr, normO, normI, agg1);
  k_gemm<128, true, true><<<782, 256, 0, stream>>>(agg1, normO, W1T, b1, h1s, NN);
  k_gather2<<<2048, 256, 0, stream>>>(h1s, rowptr, csr, normI, agg2);
  k_gemm<256, false, false><<<782, 256, 0, stream>>>(agg2, nullptr, W2T, b2, h, NN);

  for (int b = 0; b < 2; ++b) {
    const int* es = b ? neg_src : pos_src;
    const int* ed = b ? neg_dst : pos_dst;
    const float* gs = b ? gauss_neg : gauss_pos;
    const float* uf = b ? unif_neg : unif_pos;
    float* o_mean = b ? neg_mean : pos_mean;
    float* o_ls = b ? neg_logstd : pos_logstd;
    float* o_q = b ? negq : posq;
    float* o_A = b ? negA : posA;
    float* o_X = b ? negX : posX;

    k_branch2<<<2048, 512, 0, stream>>>(h, es, ed, gs, uf, temp_p,
                                        WmT, bm, WlT, bl, WqT, bq, Wc, bc,
                                        o_mean, o_ls, o_q, o_A, (unsigned*)Mws);
    k_dec2<<<4096, 512, 0, stream>>>(Mws, Wd1T, bd1, WdXT, bdX, o_X);
  }
}

// Round 8
// 1375.048 us; speedup vs baseline: 4.1380x; 1.0841x over previous
//
#include <hip/hip_runtime.h>
#include <hip/hip_bf16.h>

// Round 8: branch2 B-fragments loaded directly from global (L2-hot weights; no
// B LDS staging), 2x-unrolled CSR gathers, NT stream I/O retained.

#define NN 100000
#define EG 800000
#define EE 262144
#define NB 98

typedef __attribute__((ext_vector_type(8))) short short8;
typedef __attribute__((ext_vector_type(4))) float f32x4;
typedef __attribute__((ext_vector_type(2))) float f32x2;

__device__ __forceinline__ float lo2f(unsigned u) {
  union { unsigned u; float f; } v; v.u = u << 16; return v.f;
}
__device__ __forceinline__ float hi2f(unsigned u) {
  union { unsigned u; float f; } v; v.u = u & 0xFFFF0000u; return v.f;
}
__device__ __forceinline__ unsigned short f2bf(float f) {
  union { float f; unsigned u; } v; v.f = f;
  return (unsigned short)((v.u + 0x7FFFu + ((v.u >> 16) & 1u)) >> 16);
}
__device__ __forceinline__ unsigned pack2bf(float a, float b) {
  return (unsigned)f2bf(a) | ((unsigned)f2bf(b) << 16);
}
__device__ __forceinline__ int permc(int c) {
  return (c & ~31) | ((c & 15) << 1) | ((c >> 4) & 1);
}

__device__ __forceinline__ float decode_scalar(const void* p) {
  unsigned u = *(const unsigned*)p;
  float f = __uint_as_float(u);
  float af = fabsf(f);
  if (af >= 1e-6f && af <= 1e6f) return f;
  if (u < 1024u) return (float)u;
  return 1.0f;
}

// ---------------- degrees ----------------
__global__ __launch_bounds__(256) void k_deg(const int* __restrict__ src,
                                             const int* __restrict__ dst,
                                             int* __restrict__ degO,
                                             int* __restrict__ degI) {
  for (int i = blockIdx.x * 256 + threadIdx.x; i < EG; i += gridDim.x * 256) {
    atomicAdd(&degO[src[i]], 1);
    atomicAdd(&degI[dst[i]], 1);
  }
}

// ---------------- parallel scan ----------------
__global__ __launch_bounds__(1024) void k_scan1(const int* __restrict__ degI,
                                                int* __restrict__ rowptr,
                                                int* __restrict__ bsum) {
  __shared__ int wsum[16];
  int t = threadIdx.x, lane = t & 63, wv = t >> 6;
  int i = blockIdx.x * 1024 + t;
  int v = (i < NN) ? degI[i] : 0;
  int incl = v;
#pragma unroll
  for (int off = 1; off < 64; off <<= 1) {
    int u = __shfl_up(incl, off);
    if (lane >= off) incl += u;
  }
  if (lane == 63) wsum[wv] = incl;
  __syncthreads();
  if (wv == 0 && lane < 16) {
    int s = wsum[lane];
    int si = s;
#pragma unroll
    for (int off = 1; off < 16; off <<= 1) {
      int u = __shfl_up(si, off);
      if (lane >= off) si += u;
    }
    wsum[lane] = si - s;
    if (lane == 15) bsum[blockIdx.x] = si;
  }
  __syncthreads();
  int excl = wsum[wv] + incl - v;
  if (i < NN) rowptr[i] = excl;
}

__global__ __launch_bounds__(128) void k_scan2(int* __restrict__ bsum) {
  __shared__ int w0tot;
  int t = threadIdx.x, lane = t & 63, wv = t >> 6;
  int v = (t < NB) ? bsum[t] : 0;
  int incl = v;
#pragma unroll
  for (int off = 1; off < 64; off <<= 1) {
    int u = __shfl_up(incl, off);
    if (lane >= off) incl += u;
  }
  if (wv == 0 && lane == 63) w0tot = incl;
  __syncthreads();
  int excl = incl - v + (wv ? w0tot : 0);
  if (t < NB) bsum[t] = excl;
}

__global__ __launch_bounds__(1024) void k_scan3(const int* __restrict__ degI,
                                                const int* __restrict__ degO,
                                                int* __restrict__ rowptr,
                                                int* __restrict__ cursor,
                                                const int* __restrict__ bsum,
                                                float* __restrict__ normO,
                                                float* __restrict__ normI) {
  int i = blockIdx.x * 1024 + threadIdx.x;
  if (i < NN) {
    int vv = rowptr[i] + bsum[blockIdx.x];
    rowptr[i] = vv;
    cursor[i] = vv;
    if (i == NN - 1) rowptr[NN] = vv + degI[i];
    int dO = degO[i]; if (dO < 1) dO = 1;
    int dI = degI[i]; if (dI < 1) dI = 1;
    normO[i] = rsqrtf((float)dO);
    normI[i] = rsqrtf((float)dI);
  }
}

__global__ __launch_bounds__(256) void k_fill(const int* __restrict__ src,
                                              const int* __restrict__ dst,
                                              int* __restrict__ cursor,
                                              int* __restrict__ csr) {
  for (int e = blockIdx.x * 256 + threadIdx.x; e < EG; e += gridDim.x * 256) {
    int d = dst[e];
    int pos = atomicAdd(&cursor[d], 1);
    csr[pos] = src[e];
  }
}

// ---------------- merged weight transposes ----------------
__global__ __launch_bounds__(256) void k_transpose_all(
    const float* __restrict__ W1, const float* __restrict__ W2,
    const float* __restrict__ Wm, const float* __restrict__ Wl,
    const float* __restrict__ Wd1, const float* __restrict__ WdX,
    const float* __restrict__ Wq,
    unsigned short* __restrict__ W1T, unsigned short* __restrict__ W2T,
    unsigned short* __restrict__ WmT, unsigned short* __restrict__ WlT,
    unsigned short* __restrict__ Wd1T, unsigned short* __restrict__ WdXT,
    unsigned short* __restrict__ WqT) {
  int idx = blockIdx.x * 256 + threadIdx.x;
  if (idx < 32768) {
    int n = idx & 255, k = idx >> 8;
    W1T[n * 128 + k] = f2bf(W1[idx]);
  } else if (idx < 98304) {
    int i = idx - 32768;
    int n = i & 255, k = i >> 8;
    W2T[n * 256 + k] = f2bf(W2[i]);
  } else if (idx < 163840) {
    int i = idx - 98304;
    int n = i & 255, k = i >> 8;
    WmT[n * 256 + k] = f2bf(Wm[i]);
  } else if (idx < 229376) {
    int i = idx - 163840;
    int n = i & 255, k = i >> 8;
    WlT[n * 256 + k] = f2bf(Wl[i]);
  } else if (idx < 245760) {
    int i = idx - 229376;
    int n = i & 255, k = i >> 8;
    Wd1T[n * 64 + k] = f2bf(Wd1[i]);
  } else if (idx < 278528) {
    int i = idx - 245760;
    int n = i & 127, k = i >> 7;
    WdXT[n * 256 + k] = f2bf(WdX[i]);
  } else if (idx < 282624) {
    int i = idx - 278528;
    int r = i >> 8, k = i & 255;
    WqT[i] = (r < 4) ? f2bf(Wq[k * 4 + r]) : (unsigned short)0;
  }
}

// ---------------- gather layer 1 (2x unrolled) ----------------
__global__ __launch_bounds__(256) void k_gather1(
    const float* __restrict__ x, const int* __restrict__ rowptr,
    const int* __restrict__ csr, const float* __restrict__ normO,
    const float* __restrict__ normI, unsigned short* __restrict__ agg) {
  int wid = (blockIdx.x * 256 + threadIdx.x) >> 6;
  int lane = threadIdx.x & 63;
  int half = lane >> 5, fl = lane & 31;
  int nw = (gridDim.x * 256) >> 6;
  for (int n = wid; n < NN; n += nw) {
    int beg = rowptr[n], end = rowptr[n + 1];
    float a0 = 0.f, a1 = 0.f, a2 = 0.f, a3 = 0.f;
    float b0 = 0.f, b1 = 0.f, b2 = 0.f, b3 = 0.f;
    int i = beg + half;
    for (; i + 2 < end; i += 4) {
      int s0 = csr[i], s1 = csr[i + 2];
      float ns0 = normO[s0], ns1 = normO[s1];
      float4 v0 = *(const float4*)(x + ((size_t)s0 << 7) + (fl << 2));
      float4 v1 = *(const float4*)(x + ((size_t)s1 << 7) + (fl << 2));
      a0 += ns0 * v0.x; a1 += ns0 * v0.y; a2 += ns0 * v0.z; a3 += ns0 * v0.w;
      b0 += ns1 * v1.x; b1 += ns1 * v1.y; b2 += ns1 * v1.z; b3 += ns1 * v1.w;
    }
    for (; i < end; i += 2) {
      int s0 = csr[i];
      float ns0 = normO[s0];
      float4 v0 = *(const float4*)(x + ((size_t)s0 << 7) + (fl << 2));
      a0 += ns0 * v0.x; a1 += ns0 * v0.y; a2 += ns0 * v0.z; a3 += ns0 * v0.w;
    }
    a0 += b0; a1 += b1; a2 += b2; a3 += b3;
    a0 += __shfl_xor(a0, 32); a1 += __shfl_xor(a1, 32);
    a2 += __shfl_xor(a2, 32); a3 += __shfl_xor(a3, 32);
    if (lane < 32) {
      float ni = normI[n];
      *(uint2*)(agg + ((size_t)n << 7) + (fl << 2)) =
          make_uint2(pack2bf(a0 * ni, a1 * ni), pack2bf(a2 * ni, a3 * ni));
    }
  }
}

// ---------------- gather layer 2 (2x unrolled) ----------------
__global__ __launch_bounds__(256) void k_gather2(
    const unsigned short* __restrict__ h1s, const int* __restrict__ rowptr,
    const int* __restrict__ csr, const float* __restrict__ normI,
    unsigned short* __restrict__ agg) {
  int wid = (blockIdx.x * 256 + threadIdx.x) >> 6;
  int lane = threadIdx.x & 63;
  int half = lane >> 5, fl = lane & 31;
  int nw = (gridDim.x * 256) >> 6;
  for (int n = wid; n < NN; n += nw) {
    int beg = rowptr[n], end = rowptr[n + 1];
    float a0 = 0.f, a1 = 0.f, a2 = 0.f, a3 = 0.f, a4 = 0.f, a5 = 0.f, a6 = 0.f, a7 = 0.f;
    float c0 = 0.f, c1 = 0.f, c2 = 0.f, c3 = 0.f, c4 = 0.f, c5 = 0.f, c6 = 0.f, c7 = 0.f;
    int i = beg + half;
    for (; i + 2 < end; i += 4) {
      int s0 = csr[i], s1 = csr[i + 2];
      uint4 v = *(const uint4*)(h1s + ((size_t)s0 << 8) + (fl << 3));
      uint4 u = *(const uint4*)(h1s + ((size_t)s1 << 8) + (fl << 3));
      a0 += lo2f(v.x); a1 += hi2f(v.x);
      a2 += lo2f(v.y); a3 += hi2f(v.y);
      a4 += lo2f(v.z); a5 += hi2f(v.z);
      a6 += lo2f(v.w); a7 += hi2f(v.w);
      c0 += lo2f(u.x); c1 += hi2f(u.x);
      c2 += lo2f(u.y); c3 += hi2f(u.y);
      c4 += lo2f(u.z); c5 += hi2f(u.z);
      c6 += lo2f(u.w); c7 += hi2f(u.w);
    }
    for (; i < end; i += 2) {
      int s0 = csr[i];
      uint4 v = *(const uint4*)(h1s + ((size_t)s0 << 8) + (fl << 3));
      a0 += lo2f(v.x); a1 += hi2f(v.x);
      a2 += lo2f(v.y); a3 += hi2f(v.y);
      a4 += lo2f(v.z); a5 += hi2f(v.z);
      a6 += lo2f(v.w); a7 += hi2f(v.w);
    }
    a0 += c0; a1 += c1; a2 += c2; a3 += c3;
    a4 += c4; a5 += c5; a6 += c6; a7 += c7;
    a0 += __shfl_xor(a0, 32); a1 += __shfl_xor(a1, 32);
    a2 += __shfl_xor(a2, 32); a3 += __shfl_xor(a3, 32);
    a4 += __shfl_xor(a4, 32); a5 += __shfl_xor(a5, 32);
    a6 += __shfl_xor(a6, 32); a7 += __shfl_xor(a7, 32);
    if (lane < 32) {
      float ni = normI[n];
      uint4 o;
      o.x = pack2bf(a0 * ni, a1 * ni);
      o.y = pack2bf(a2 * ni, a3 * ni);
      o.z = pack2bf(a4 * ni, a5 * ni);
      o.w = pack2bf(a6 * ni, a7 * ni);
      *(uint4*)(agg + ((size_t)n << 8) + (fl << 3)) = o;
    }
  }
}

// ---------------- encoder GEMM ----------------
template <int K, bool RELU, bool OSCALE>
__global__ __launch_bounds__(256) void k_gemm(
    const unsigned short* __restrict__ A, const float* __restrict__ oscale,
    const unsigned short* __restrict__ WT, const float* __restrict__ bias,
    unsigned short* __restrict__ C, int M) {
  __shared__ __align__(16) short At[128 * 40];
  __shared__ __align__(16) short Bt[256 * 40];
  const int t = threadIdx.x;
  const int row0 = blockIdx.x * 128;
  const int lane = t & 63, wave = t >> 6;
  const int wr = (wave >> 1) << 6;
  const int wcc = (wave & 1) << 7;
  const int lrow = lane & 15, lhi = lane >> 4;

  f32x4 acc[4][8];
#pragma unroll
  for (int m = 0; m < 4; ++m)
#pragma unroll
    for (int n = 0; n < 8; ++n) acc[m][n] = (f32x4){0.f, 0.f, 0.f, 0.f};

  for (int k0 = 0; k0 < K; k0 += 32) {
    if (k0) __syncthreads();
#pragma unroll
    for (int it = 0; it < 2; ++it) {
      int idx = t + it * 256;
      int r = idx >> 2, c8 = (idx & 3) << 3;
      int grow = row0 + r;
      int4 tv = {0, 0, 0, 0};
      if (grow < M) tv = *(const int4*)(A + (size_t)grow * K + k0 + c8);
      *(int4*)&At[r * 40 + c8] = tv;
    }
    {
      const unsigned short* wt = WT + (size_t)permc(t) * K + k0;
      *(int4*)&Bt[t * 40 + 0] = *(const int4*)(wt);
      *(int4*)&Bt[t * 40 + 8] = *(const int4*)(wt + 8);
      *(int4*)&Bt[t * 40 + 16] = *(const int4*)(wt + 16);
      *(int4*)&Bt[t * 40 + 24] = *(const int4*)(wt + 24);
    }
    __syncthreads();
    short8 a[4], b[8];
#pragma unroll
    for (int m = 0; m < 4; ++m)
      a[m] = *(const short8*)&At[(wr + m * 16 + lrow) * 40 + lhi * 8];
#pragma unroll
    for (int n = 0; n < 8; ++n)
      b[n] = *(const short8*)&Bt[(wcc + n * 16 + lrow) * 40 + lhi * 8];
#pragma unroll
    for (int m = 0; m < 4; ++m)
#pragma unroll
      for (int n = 0; n < 8; ++n)
        acc[m][n] = __builtin_amdgcn_mfma_f32_16x16x32_bf16(a[m], b[n], acc[m][n], 0, 0, 0);
  }
#pragma unroll
  for (int np = 0; np < 4; ++np) {
    int tc = wcc + np * 32 + (lrow << 1);
    float bv0 = bias[tc], bv1 = bias[tc + 1];
#pragma unroll
    for (int m = 0; m < 4; ++m) {
#pragma unroll
      for (int r = 0; r < 4; ++r) {
        int grow = row0 + wr + m * 16 + lhi * 4 + r;
        if (grow < M) {
          float v0 = acc[m][2 * np][r] + bv0;
          float v1 = acc[m][2 * np + 1][r] + bv1;
          if (RELU) { v0 = fmaxf(v0, 0.f); v1 = fmaxf(v1, 0.f); }
          if (OSCALE) { float s = oscale[grow]; v0 *= s; v1 *= s; }
          *(unsigned*)&C[(size_t)grow * 256 + tc] = pack2bf(v0, v1);
        }
      }
    }
  }
}

// ---------------- fused branch v5: B direct from global, A-only LDS ----------------
__global__ __launch_bounds__(512) void k_branch2(
    const unsigned short* __restrict__ h, const int* __restrict__ ea,
    const int* __restrict__ eb, const float* __restrict__ gauss,
    const float* __restrict__ unif, const void* __restrict__ temp_p,
    const unsigned short* __restrict__ WmT, const float* __restrict__ bm,
    const unsigned short* __restrict__ WlT, const float* __restrict__ bl,
    const unsigned short* __restrict__ WqT, const float* __restrict__ bq,
    const float* __restrict__ Wc, const float* __restrict__ bc,
    float* __restrict__ o_mean, float* __restrict__ o_ls,
    float* __restrict__ q_o, float* __restrict__ A_o,
    unsigned* __restrict__ M_o32) {
  __shared__ __align__(16) char U[33792];  // At [128][32] swizzled | Mf f32[128][66]
  short* At = (short*)U;
  float* Mf = (float*)U;
  __shared__ float zS[512];
  __shared__ float qS[512];
  __shared__ float WcT[4 * 68];
  __shared__ float bmS[256], blS[256];
  __shared__ int eaS[128], ebS[128];

  const int t = threadIdx.x;
  const int e0 = blockIdx.x << 7;
  const int lane = t & 63;
  const int wv = t >> 6;
  const int lrow = lane & 15, lhi = lane >> 4;
  const int wc = wv << 5;

  if (t < 256) {
    bmS[t] = bm[t]; blS[t] = bl[t];
    WcT[(t & 3) * 68 + (t >> 2)] = Wc[t];
  } else if (t < 384) {
    eaS[t - 256] = ea[e0 + t - 256];
  } else {
    ebS[t - 384] = eb[e0 + t - 384];
  }
  __syncthreads();

  f32x4 am[8][2], al[8][2], aq;
#pragma unroll
  for (int m = 0; m < 8; ++m)
#pragma unroll
    for (int n = 0; n < 2; ++n) {
      am[m][n] = (f32x4){0.f, 0.f, 0.f, 0.f};
      al[m][n] = (f32x4){0.f, 0.f, 0.f, 0.f};
    }
  aq = (f32x4){0.f, 0.f, 0.f, 0.f};

  const int ar = t >> 2, as_ = t & 3;
  const int arsw = ((as_ ^ (ar & 3)) << 3);
  const int fsw = (lrow & 3);

  const unsigned short* pa_base = h + ((size_t)eaS[ar] << 8) + (as_ << 3);
  const unsigned short* pb_base = h + ((size_t)ebS[ar] << 8) + (as_ << 3);
  // per-lane B fragment base pointers (global, L2-hot), perm-consistent rows
  const size_t row0p = (size_t)permc(wc + lrow) << 8;
  const size_t row1p = (size_t)permc(wc + 16 + lrow) << 8;
  const unsigned short* bm0p = WmT + row0p + (lhi << 3);
  const unsigned short* bm1p = WmT + row1p + (lhi << 3);
  const unsigned short* bl0p = WlT + row0p + (lhi << 3);
  const unsigned short* bl1p = WlT + row1p + (lhi << 3);
  const unsigned short* bqp = WqT + ((size_t)lrow << 8) + (lhi << 3);

  // prologue gather
  uint4 va = *(const uint4*)pa_base;
  uint4 vb = *(const uint4*)pb_base;

  for (int k0 = 0; k0 < 256; k0 += 32) {
    unsigned w0 = pack2bf(lo2f(va.x) + lo2f(vb.x), hi2f(va.x) + hi2f(vb.x));
    unsigned w1 = pack2bf(lo2f(va.y) + lo2f(vb.y), hi2f(va.y) + hi2f(vb.y));
    unsigned w2 = pack2bf(lo2f(va.z) + lo2f(vb.z), hi2f(va.z) + hi2f(vb.z));
    unsigned w3 = pack2bf(lo2f(va.w) + lo2f(vb.w), hi2f(va.w) + hi2f(vb.w));
    if (k0 < 224) {  // next iteration's gather (hidden under MFMA)
      va = *(const uint4*)(pa_base + k0 + 32);
      vb = *(const uint4*)(pb_base + k0 + 32);
    }
    // B fragments direct from global; issued before barriers -> latency hidden
    short8 bmf0 = *(const short8*)(bm0p + k0);
    short8 bmf1 = *(const short8*)(bm1p + k0);
    short8 blf0 = *(const short8*)(bl0p + k0);
    short8 blf1 = *(const short8*)(bl1p + k0);
    short8 bqf = *(const short8*)(bqp + k0);
    if (k0) __syncthreads();
    *(int4*)&At[ar * 32 + arsw] = make_int4((int)w0, (int)w1, (int)w2, (int)w3);
    __syncthreads();
    short8 a[8], aqa;
#pragma unroll
    for (int m = 0; m < 8; ++m)
      a[m] = *(const short8*)&At[(m * 16 + lrow) * 32 + ((lhi ^ fsw) << 3)];
    aqa = *(const short8*)&At[((wv << 4) + lrow) * 32 + ((lhi ^ fsw) << 3)];
#pragma unroll
    for (int m = 0; m < 8; ++m) {
      am[m][0] = __builtin_amdgcn_mfma_f32_16x16x32_bf16(a[m], bmf0, am[m][0], 0, 0, 0);
      am[m][1] = __builtin_amdgcn_mfma_f32_16x16x32_bf16(a[m], bmf1, am[m][1], 0, 0, 0);
      al[m][0] = __builtin_amdgcn_mfma_f32_16x16x32_bf16(a[m], blf0, al[m][0], 0, 0, 0);
      al[m][1] = __builtin_amdgcn_mfma_f32_16x16x32_bf16(a[m], blf1, al[m][1], 0, 0, 0);
    }
    aq = __builtin_amdgcn_mfma_f32_16x16x32_bf16(aqa, bqf, aq, 0, 0, 0);
  }
  __syncthreads();

  // Z phase + zero Mf (staging dead)
  float invt = 1.0f / decode_scalar(temp_p);
  float qb = (lrow < 4) ? bq[lrow] : 0.f;
#pragma unroll
  for (int r = 0; r < 4; ++r) {
    int el = (wv << 4) + lhi * 4 + r;
    float q = aq[r] + qb;
    float uu = 0.5f;
    if (lrow < 4) uu = unif[(((size_t)(e0 + el)) << 2) + lrow];
    float g = -__logf(-__logf(uu + 1e-7f) + 1e-7f);
    float z = (q + g) * invt;
    float mx = fmaxf(z, __shfl_xor(z, 1));
    mx = fmaxf(mx, __shfl_xor(mx, 2));
    float ez = __expf(z - mx);
    float sz = ez + __shfl_xor(ez, 1);
    sz += __shfl_xor(sz, 2);
    if (lrow < 4) { zS[el * 4 + lrow] = ez / sz; qS[el * 4 + lrow] = q; }
  }
  for (int i = t; i < 128 * 66; i += 512) Mf[i] = 0.f;
  __syncthreads();

  __builtin_nontemporal_store(qS[t], q_o + (((size_t)e0) << 2) + t);

  const int cidx = wv >> 1;
  const int dd = ((wv & 1) << 5) + (lrow << 1);
  const int tc = wc + (lrow << 1);
  float bm0 = bmS[tc], bm1 = bmS[tc + 1];
  float bl0 = blS[tc], bl1 = blS[tc + 1];
#pragma unroll
  for (int m = 0; m < 8; ++m) {
#pragma unroll
    for (int r = 0; r < 4; ++r) {
      int row = m * 16 + lhi * 4 + r;
      size_t gi = (((size_t)(e0 + row)) << 8) + tc;
      float mv0 = am[m][0][r] + bm0, mv1 = am[m][1][r] + bm1;
      float lv0 = al[m][0][r] + bl0, lv1 = al[m][1][r] + bl1;
      __builtin_nontemporal_store((f32x2){mv0, mv1}, (f32x2*)(o_mean + gi));
      __builtin_nontemporal_store((f32x2){lv0, lv1}, (f32x2*)(o_ls + gi));
      f32x2 g2 = __builtin_nontemporal_load((const f32x2*)(gauss + gi));
      float zc = zS[(row << 2) + cidx];
      atomicAdd(&Mf[row * 66 + dd], zc * (g2.x * __expf(lv0) + mv0));
      atomicAdd(&Mf[row * 66 + dd + 1], zc * (g2.y * __expf(lv1) + mv1));
    }
  }
  __syncthreads();

  // A phase
  {
    int e = t >> 2, cat = t & 3;
    const float* mrow = &Mf[e * 66];
    const float* wct = &WcT[cat * 68];
    float s = 0.f;
#pragma unroll
    for (int dp = 0; dp < 32; ++dp) {
      float2 m2 = *(const float2*)(mrow + 2 * dp);
      s += m2.x * wct[2 * dp] + m2.y * wct[2 * dp + 1];
    }
    s += bc[cat];
    float smx = fmaxf(s, __shfl_xor(s, 1));
    smx = fmaxf(smx, __shfl_xor(smx, 2));
    float es = __expf(s - smx);
    float ssum = es + __shfl_xor(es, 1);
    ssum += __shfl_xor(ssum, 2);
    __builtin_nontemporal_store(es / ssum, A_o + (((size_t)e0) << 2) + t);
  }
  // M write (packed u32, coalesced; decoder re-reads -> keep cached)
#pragma unroll
  for (int j = 0; j < 8; ++j) {
    int idx = j * 512 + t;
    int row = idx >> 5, dp = idx & 31;
    float2 m2 = *(const float2*)(&Mf[row * 66 + 2 * dp]);
    M_o32[((size_t)(e0 + row)) * 32 + dp] = pack2bf(m2.x, m2.y);
  }
}

// ---------------- fused decoder (unchanged from r7) ----------------
__global__ __launch_bounds__(512) void k_dec2(
    const unsigned short* __restrict__ Mw, const unsigned short* __restrict__ Wd1T,
    const float* __restrict__ bd1, const unsigned short* __restrict__ WdXT,
    const float* __restrict__ bdX, float* __restrict__ Xo) {
  __shared__ __align__(16) char R[65280];
  short* Mt = (short*)R;
  short* Bt1 = (short*)(R + 9216);
  short* X1 = (short*)R;
  short* Bt2 = (short*)(R + 46848);
  const int t = threadIdx.x, lane = t & 63, wv = t >> 6;
  const int lrow = lane & 15, lhi = lane >> 4;
  const int e0 = blockIdx.x << 6;

  const int r2 = t >> 2, base2 = (t & 3) << 4;
  const unsigned short* wpb = WdXT + ((size_t)permc(r2) << 8) + base2;

  {
    int r = t >> 3, c8 = (t & 7) << 3;
    *(int4*)&Mt[r * 72 + c8] = *(const int4*)(Mw + (((size_t)(e0 + r)) << 6) + c8);
  }
  {
    int r1 = t >> 1, base = (t & 1) << 5;
    const unsigned short* wp = Wd1T + ((size_t)permc(r1) << 6) + base;
#pragma unroll
    for (int j = 0; j < 4; ++j)
      *(int4*)&Bt1[r1 * 72 + base + j * 8] = *(const int4*)(wp + j * 8);
  }
  int4 pw0 = *(const int4*)(wpb);
  int4 pw1 = *(const int4*)(wpb + 8);
  __syncthreads();
  f32x4 acc1[4][2];
#pragma unroll
  for (int m = 0; m < 4; ++m)
#pragma unroll
    for (int n = 0; n < 2; ++n) acc1[m][n] = (f32x4){0.f, 0.f, 0.f, 0.f};
  const int wc1 = wv << 5;
  {
    short8 a0[4], a1[4], b0[2], b1[2];
#pragma unroll
    for (int m = 0; m < 4; ++m) {
      a0[m] = *(const short8*)&Mt[(m * 16 + lrow) * 72 + lhi * 8];
      a1[m] = *(const short8*)&Mt[(m * 16 + lrow) * 72 + 32 + lhi * 8];
    }
#pragma unroll
    for (int n = 0; n < 2; ++n) {
      b0[n] = *(const short8*)&Bt1[(wc1 + n * 16 + lrow) * 72 + lhi * 8];
      b1[n] = *(const short8*)&Bt1[(wc1 + n * 16 + lrow) * 72 + 32 + lhi * 8];
    }
#pragma unroll
    for (int m = 0; m < 4; ++m)
#pragma unroll
      for (int n = 0; n < 2; ++n) {
        acc1[m][n] = __builtin_amdgcn_mfma_f32_16x16x32_bf16(a0[m], b0[n], acc1[m][n], 0, 0, 0);
        acc1[m][n] = __builtin_amdgcn_mfma_f32_16x16x32_bf16(a1[m], b1[n], acc1[m][n], 0, 0, 0);
      }
  }
  __syncthreads();
  {
    int tc = wc1 + (lrow << 1);
    float bdv0 = bd1[tc], bdv1 = bd1[tc + 1];
#pragma unroll
    for (int m = 0; m < 4; ++m)
#pragma unroll
      for (int r = 0; r < 4; ++r) {
        int row = m * 16 + lhi * 4 + r;
        float v0 = fmaxf(acc1[m][0][r] + bdv0, 0.f);
        float v1 = fmaxf(acc1[m][1][r] + bdv1, 0.f);
        *(unsigned*)&X1[row * 264 + tc] = pack2bf(v0, v1);
      }
  }

  f32x4 acc2[2][2];
#pragma unroll
  for (int m = 0; m < 2; ++m)
#pragma unroll
    for (int n = 0; n < 2; ++n) acc2[m][n] = (f32x4){0.f, 0.f, 0.f, 0.f};
  const int wr2 = (wv >> 2) << 5, wc2 = (wv & 3) << 5;
  for (int k0 = 0; k0 < 256; k0 += 64) {
    __syncthreads();
    *(int4*)&Bt2[r2 * 72 + base2] = pw0;
    *(int4*)&Bt2[r2 * 72 + base2 + 8] = pw1;
    if (k0 < 192) {
      pw0 = *(const int4*)(wpb + k0 + 64);
      pw1 = *(const int4*)(wpb + k0 + 64 + 8);
    }
    __syncthreads();
    short8 c0[2], c1[2], d0[2], d1[2];
#pragma unroll
    for (int m = 0; m < 2; ++m) {
      c0[m] = *(const short8*)&X1[(wr2 + m * 16 + lrow) * 264 + k0 + lhi * 8];
      c1[m] = *(const short8*)&X1[(wr2 + m * 16 + lrow) * 264 + k0 + 32 + lhi * 8];
    }
#pragma unroll
    for (int n = 0; n < 2; ++n) {
      d0[n] = *(const short8*)&Bt2[(wc2 + n * 16 + lrow) * 72 + lhi * 8];
      d1[n] = *(const short8*)&Bt2[(wc2 + n * 16 + lrow) * 72 + 32 + lhi * 8];
    }
#pragma unroll
    for (int m = 0; m < 2; ++m)
#pragma unroll
      for (int n = 0; n < 2; ++n) {
        acc2[m][n] = __builtin_amdgcn_mfma_f32_16x16x32_bf16(c0[m], d0[n], acc2[m][n], 0, 0, 0);
        acc2[m][n] = __builtin_amdgcn_mfma_f32_16x16x32_bf16(c1[m], d1[n], acc2[m][n], 0, 0, 0);
      }
  }
  {
    int tc2 = wc2 + (lrow << 1);
    float bx0 = bdX[tc2], bx1 = bdX[tc2 + 1];
#pragma unroll
    for (int m = 0; m < 2; ++m)
#pragma unroll
      for (int r = 0; r < 4; ++r) {
        int row = wr2 + m * 16 + lhi * 4 + r;
        float v0 = fmaxf(acc2[m][0][r] + bx0, 0.f);
        float v1 = fmaxf(acc2[m][1][r] + bx1, 0.f);
        __builtin_nontemporal_store((f32x2){v0, v1},
                                    (f32x2*)(Xo + (((size_t)(e0 + row)) << 7) + tc2));
      }
  }
}

extern "C" void kernel_launch(void* const* d_in, const int* in_sizes, int n_in,
                              void* d_out, int out_size, void* d_ws, size_t ws_size,
                              hipStream_t stream) {
  const float* x = (const float*)d_in[0];
  const int* src = (const int*)d_in[1];
  const int* dst = (const int*)d_in[2];
  const int* pos_src = (const int*)d_in[3];
  const int* pos_dst = (const int*)d_in[4];
  const int* neg_src = (const int*)d_in[5];
  const int* neg_dst = (const int*)d_in[6];
  const float* gauss_pos = (const float*)d_in[7];
  const float* gauss_neg = (const float*)d_in[8];
  const float* unif_pos = (const float*)d_in[9];
  const float* unif_neg = (const float*)d_in[10];
  const void* temp_p = d_in[11];
  const float* W1 = (const float*)d_in[12];
  const float* b1 = (const float*)d_in[13];
  const float* W2 = (const float*)d_in[14];
  const float* b2 = (const float*)d_in[15];
  const float* Wm = (const float*)d_in[16];
  const float* bm = (const float*)d_in[17];
  const float* Wl = (const float*)d_in[18];
  const float* bl = (const float*)d_in[19];
  const float* Wq = (const float*)d_in[20];
  const float* bq = (const float*)d_in[21];
  const float* Wd1 = (const float*)d_in[22];
  const float* bd1 = (const float*)d_in[23];
  const float* WdX = (const float*)d_in[24];
  const float* bdX = (const float*)d_in[25];
  const float* Wc = (const float*)d_in[26];
  const float* bc = (const float*)d_in[27];

  char* w = (char*)d_ws;
  int* degO = (int*)w;
  int* degI = (int*)(w + 401408);
  int* rowptr = (int*)(w + 802816);
  int* cursor = (int*)(w + 1204224);
  float* normO = (float*)(w + 1605632);
  float* normI = (float*)(w + 2007040);
  int* csr = (int*)(w + 2408448);
  unsigned short* W1T = (unsigned short*)(w + 5609472);
  unsigned short* W2T = (unsigned short*)(w + 5675008);
  unsigned short* WmT = (unsigned short*)(w + 5806080);
  unsigned short* WlT = (unsigned short*)(w + 5937152);
  unsigned short* Wd1T = (unsigned short*)(w + 6068224);
  unsigned short* WdXT = (unsigned short*)(w + 6100992);
  unsigned short* WqT = (unsigned short*)(w + 6166528);
  int* bsum = (int*)(w + 6174720);
  unsigned short* agg1 = (unsigned short*)(w + 6175232);
  unsigned short* h1s = (unsigned short*)(w + 31775232);
  unsigned short* agg2 = (unsigned short*)(w + 82975232);
  unsigned short* h = (unsigned short*)(w + 134175232);
  unsigned short* Mws = (unsigned short*)(w + 185375232);

  float* out = (float*)d_out;
  float* posA = out;
  float* negA = out + 1048576ull;
  float* posX = out + 2097152ull;
  float* negX = out + 35651584ull;
  float* pos_mean = out + 69206016ull;
  float* neg_mean = out + 136314880ull;
  float* pos_logstd = out + 203423744ull;
  float* neg_logstd = out + 270532608ull;
  float* posq = out + 337641472ull;
  float* negq = out + 338690048ull;

  hipMemsetAsync(d_ws, 0, 802816, stream);

  k_deg<<<1024, 256, 0, stream>>>(src, dst, degO, degI);
  k_scan1<<<NB, 1024, 0, stream>>>(degI, rowptr, bsum);
  k_scan2<<<1, 128, 0, stream>>>(bsum);
  k_scan3<<<NB, 1024, 0, stream>>>(degI, degO, rowptr, cursor, bsum, normO, normI);
  k_fill<<<2048, 256, 0, stream>>>(src, dst, cursor, csr);
  k_transpose_all<<<1104, 256, 0, stream>>>(W1, W2, Wm, Wl, Wd1, WdX, Wq,
                                            W1T, W2T, WmT, WlT, Wd1T, WdXT, WqT);

  k_gather1<<<2048, 256, 0, stream>>>(x, rowptr, csr, normO, normI, agg1);
  k_gemm<128, true, true><<<782, 256, 0, stream>>>(agg1, normO, W1T, b1, h1s, NN);
  k_gather2<<<2048, 256, 0, stream>>>(h1s, rowptr, csr, normI, agg2);
  k_gemm<256, false, false><<<782, 256, 0, stream>>>(agg2, nullptr, W2T, b2, h, NN);

  for (int b = 0; b < 2; ++b) {
    const int* es = b ? neg_src : pos_src;
    const int* ed = b ? neg_dst : pos_dst;
    const float* gs = b ? gauss_neg : gauss_pos;
    const float* uf = b ? unif_neg : unif_pos;
    float* o_mean = b ? neg_mean : pos_mean;
    float* o_ls = b ? neg_logstd : pos_logstd;
    float* o_q = b ? negq : posq;
    float* o_A = b ? negA : posA;
    float* o_X = b ? negX : posX;

    k_branch2<<<2048, 512, 0, stream>>>(h, es, ed, gs, uf, temp_p,
                                        WmT, bm, WlT, bl, WqT, bq, Wc, bc,
                                        o_mean, o_ls, o_q, o_A, (unsigned*)Mws);
    k_dec2<<<4096, 512, 0, stream>>>(Mws, Wd1T, bd1, WdXT, bdX, o_X);
  }
}